// Round 12
// baseline (2003.096 us; speedup 1.0000x reference)
//
#include <hip/hip_runtime.h>
#include <hip/hip_bf16.h>
#include <hip/hip_cooperative_groups.h>
#include <string.h>

namespace cg = cooperative_groups;

#define BB 8
#define NC 4096
#define NTT 4096
#define NNODE 1024
#define NEDGE 16384

typedef __hip_bfloat16 bf16;
typedef unsigned short u16;
typedef __attribute__((ext_vector_type(8))) short short8;
typedef __attribute__((ext_vector_type(4))) float f32x4;

__device__ __forceinline__ float b2f(bf16 x) { return __bfloat162float(x); }
__device__ __forceinline__ float t2f(float v) { return v; }
__device__ __forceinline__ float t2f(bf16 v) { return __bfloat162float(v); }

template <typename T> struct Cvt;
template <> struct Cvt<float> { static __device__ __forceinline__ float to(float v) { return v; } };
template <> struct Cvt<bf16>  { static __device__ __forceinline__ bf16  to(float v) { return __float2bfloat16(v); } };

__device__ __forceinline__ unsigned short f2bs(float x) {
    unsigned u = __float_as_uint(x);
    return (unsigned short)((u + 0x7FFFu + ((u >> 16) & 1u)) >> 16);
}

__device__ __forceinline__ short8 ld_frag(const bf16* g) {
    union { uint4 u4; short8 s8; } cv;
    cv.u4 = *(const uint4*)g;
    return cv.s8;
}
__device__ __forceinline__ short8 ld_frag(const float* g) {
    float4 f0 = *(const float4*)g;
    float4 f1 = *(const float4*)(g + 4);
    short8 r;
    r[0] = (short)f2bs(f0.x); r[1] = (short)f2bs(f0.y);
    r[2] = (short)f2bs(f0.z); r[3] = (short)f2bs(f0.w);
    r[4] = (short)f2bs(f1.x); r[5] = (short)f2bs(f1.y);
    r[6] = (short)f2bs(f1.z); r[7] = (short)f2bs(f1.w);
    return r;
}

// ---------------------------------------------------------------------------
__global__ void detect_k(const u16* __restrict__ posu, int* __restrict__ flag) {
    __shared__ int cnt;
    if (threadIdx.x == 0) cnt = 0;
    __syncthreads();
    int wild = 0;
    for (int i = threadIdx.x; i < 1024; i += 256) {
        u16 u = posu[2 * i];
        int ex = (u >> 7) & 0xFF;
        if (ex == 0 || ex == 0xFF || ex > 137 || ex < 107) wild++;
    }
    atomicAdd(&cnt, wild);
    __syncthreads();
    if (threadIdx.x == 0) *flag = (cnt > 50) ? 1 : 0;
}

// ---------------------------------------------------------------------------
struct Tab { const void* src[30]; int pref[31]; };

__global__ __launch_bounds__(256) void ingest_k(Tab tab, const int* __restrict__ flag,
                                                bf16* __restrict__ dst) {
    int idx = blockIdx.x * 256 + threadIdx.x;
    if (idx >= tab.pref[30]) return;
    int t = 0;
    while (tab.pref[t + 1] <= idx) t++;
    int e = idx - tab.pref[t];
    float v;
    if (*flag) v = ((const float*)tab.src[t])[e];
    else       v = b2f(((const bf16*)tab.src[t])[e]);
    dst[idx] = __float2bfloat16(v);
}

// ---------------------------------------------------------------------------
struct TT { const bf16* src[9]; bf16* dst[9]; int Ks[9]; int Ns[9]; int pref[10]; };

__global__ __launch_bounds__(256) void prep_trans_k(
    TT tt,
    const bf16* __restrict__ xc, const bf16* __restrict__ yc,
    const bf16* __restrict__ pos,
    bf16* __restrict__ xin5, float2* __restrict__ posf2) {
    if (blockIdx.x < 128) {
        int row = blockIdx.x * 256 + threadIdx.x;
        bf16 z = __float2bfloat16(0.f);
        xin5[row * 8 + 0] = xc[row * 2 + 0];
        xin5[row * 8 + 1] = xc[row * 2 + 1];
        xin5[row * 8 + 2] = yc[row * 3 + 0];
        xin5[row * 8 + 3] = yc[row * 3 + 1];
        xin5[row * 8 + 4] = yc[row * 3 + 2];
        xin5[row * 8 + 5] = z;
        xin5[row * 8 + 6] = z;
        xin5[row * 8 + 7] = z;
        if (row < NNODE) posf2[row] = make_float2(b2f(pos[2 * row]), b2f(pos[2 * row + 1]));
        return;
    }
    int idx = (blockIdx.x - 128) * 256 + threadIdx.x;
    if (idx >= tt.pref[9]) return;
    int t = 0;
    while (tt.pref[t + 1] <= idx) t++;
    int e = idx - tt.pref[t];
    int N = tt.Ns[t];
    int k = e / N, n = e - k * N;
    tt.dst[t][n * tt.Ks[t] + k] = tt.src[t][e];
}

// ---------------------------------------------------------------------------
__global__ __launch_bounds__(1024) void build_csr_k(const int* __restrict__ recv,
                                                    const int* __restrict__ send,
                                                    int* __restrict__ rowptr,
                                                    int* __restrict__ csr_send) {
    __shared__ int cnt[1024];
    __shared__ int wt[16], wt2[16];
    __shared__ int cur[1024];
    int t = threadIdx.x;
    cnt[t] = 0;
    __syncthreads();
    for (int e = t; e < NEDGE; e += 1024) atomicAdd(&cnt[recv[e]], 1);
    __syncthreads();
    int v = cnt[t];
    int lane = t & 63, w = t >> 6;
#pragma unroll
    for (int off = 1; off < 64; off <<= 1) {
        int u = __shfl_up(v, off);
        if (lane >= off) v += u;
    }
    if (lane == 63) wt[w] = v;
    __syncthreads();
    if (t < 16) {
        int x = wt[t];
#pragma unroll
        for (int off = 1; off < 16; off <<= 1) {
            int u = __shfl_up(x, off);
            if (t >= off) x += u;
        }
        wt2[t] = x;
    }
    __syncthreads();
    int excl = v - cnt[t] + (w ? wt2[w - 1] : 0);
    rowptr[t] = excl;
    cur[t] = excl;
    if (t == 0) rowptr[1024] = NEDGE;
    __syncthreads();
    for (int e = t; e < NEDGE; e += 1024) {
        int pos = atomicAdd(&cur[recv[e]], 1);
        csr_send[pos] = send[e];
    }
}

// ---------------------------------------------------------------------------
// standalone MFMA GEMM
// ---------------------------------------------------------------------------
template <int KSTEPS, int EPI, int RELU, int TRANS, int NSPLIT, typename TIN, typename TOUT>
__global__ __launch_bounds__(256) void mfma_gemm_k(
    const TIN* __restrict__ Xa, const TIN* __restrict__ Xb, int ldx,
    const bf16* __restrict__ Wt,
    const bf16* __restrict__ bias,
    const bf16* __restrict__ lng, const bf16* __restrict__ lnb,
    TOUT* __restrict__ Y, int ldy, int tshift)
{
    constexpr int K = KSTEPS * 32;
    __shared__ __align__(16) short As[4][64][8];
    __shared__ __align__(16) short Bs[8][64][8];
    int tid = threadIdx.x;
    int w = tid >> 6, l = tid & 63;
    int lm = l & 15, lq = l >> 4;
    int blk = blockIdx.x;
    int half = 0;
    if (NSPLIT == 2) { half = blk & 1; blk >>= 1; }
    const bf16* Wtl = Wt + (size_t)half * 128 * K;
    int colbase = half * 128;
    size_t row0 = (size_t)blk * 64;

    f32x4 acc[8];
#pragma unroll
    for (int i = 0; i < 8; i++) acc[i] = (f32x4){0.f, 0.f, 0.f, 0.f};

    for (int s = 0; s < KSTEPS; ++s) {
        int k0 = s * 32;
        __syncthreads();
        {
            const TIN* src = Xa; int kk = k0; int ld = ldx;
            if (Xb != nullptr && k0 >= 128) { src = Xb; kk = k0 - 128; ld = 128; }
            *(short8*)&As[w][l][0] = ld_frag(src + (row0 + w * 16 + lm) * (size_t)ld + kk + lq * 8);
        }
#pragma unroll
        for (int rr = 0; rr < 2; ++rr) {
            int idx = rr * 256 + tid;
            int nt = idx >> 6, ll = idx & 63;
            *(short8*)&Bs[nt][ll][0] =
                ld_frag(Wtl + (size_t)(nt * 16 + (ll & 15)) * K + k0 + (ll >> 4) * 8);
        }
        __syncthreads();
        short8 a = *(const short8*)&As[w][l][0];
#pragma unroll
        for (int nt = 0; nt < 8; ++nt) {
            short8 b = *(const short8*)&Bs[nt][l][0];
            acc[nt] = __builtin_amdgcn_mfma_f32_16x16x32_bf16(a, b, acc[nt], 0, 0, 0);
        }
    }

    float v[8][4];
#pragma unroll
    for (int nt = 0; nt < 8; ++nt) {
        float bb = bias ? b2f(bias[colbase + nt * 16 + lm]) : 0.f;
#pragma unroll
        for (int r = 0; r < 4; ++r) v[nt][r] = acc[nt][r] + bb;
    }
    if constexpr (EPI == 1) {
#pragma unroll
        for (int r = 0; r < 4; ++r) {
            float s1 = 0.f, s2 = 0.f;
#pragma unroll
            for (int nt = 0; nt < 8; ++nt) { s1 += v[nt][r]; s2 += v[nt][r] * v[nt][r]; }
#pragma unroll
            for (int m = 1; m < 16; m <<= 1) { s1 += __shfl_xor(s1, m); s2 += __shfl_xor(s2, m); }
            float mu = s1 * (1.f / 128.f);
            float var = s2 * (1.f / 128.f) - mu * mu;
            float rs = rsqrtf(var + 1e-5f);
#pragma unroll
            for (int nt = 0; nt < 8; ++nt) {
                int n = nt * 16 + lm;
                v[nt][r] = (v[nt][r] - mu) * rs * b2f(lng[n]) + b2f(lnb[n]);
            }
        }
    }
    if constexpr (TRANS) {
        size_t grow = row0 + w * 16 + lq * 4;
        int bb2 = (int)(grow >> tshift);
        size_t rloc = grow & (((size_t)1 << tshift) - 1);
        bf16* YT = (bf16*)Y;
#pragma unroll
        for (int nt = 0; nt < 8; ++nt) {
            int col = colbase + nt * 16 + lm;
            ushort4 u;
            float x0 = v[nt][0], x1 = v[nt][1], x2 = v[nt][2], x3 = v[nt][3];
            if (RELU) { x0 = fmaxf(x0, 0.f); x1 = fmaxf(x1, 0.f); x2 = fmaxf(x2, 0.f); x3 = fmaxf(x3, 0.f); }
            u.x = f2bs(x0); u.y = f2bs(x1); u.z = f2bs(x2); u.w = f2bs(x3);
            *(ushort4*)(YT + (((size_t)bb2 * 128 + col) << tshift) + rloc) = u;
        }
    } else {
#pragma unroll
        for (int nt = 0; nt < 8; ++nt)
#pragma unroll
            for (int r = 0; r < 4; ++r) {
                float x = v[nt][r];
                if (RELU) x = fmaxf(x, 0.f);
                Y[(row0 + w * 16 + lq * 4 + r) * (size_t)ldy + colbase + nt * 16 + lm] = Cvt<TOUT>::to(x);
            }
    }
}

// ---------------------------------------------------------------------------
// legacy row GEMM (K=5 / K=2 input layers only)
// ---------------------------------------------------------------------------
template <int NOUT, typename TIN, typename TOUT>
__global__ __launch_bounds__(256) void gemm_k(
    const TIN* __restrict__ Xa, int ldxa,
    const TIN* __restrict__ Xb,
    const bf16* __restrict__ W, int wcat,
    const bf16* __restrict__ bias,
    TOUT* __restrict__ Y, int ldy,
    int K, int relu) {
    constexpr int R = (NOUT == 256) ? 8 : 16;
    __shared__ __align__(16) float Xs[16 * 256];
    int tid = threadIdx.x;
    int row0 = blockIdx.x * R;

    int tot = R * K;
    for (int t = tid; t < tot; t += 256) {
        int r = t / K, i = t - r * K;
        float v;
        if (Xb && i >= 128) v = t2f(Xb[(row0 + r) * 128 + (i - 128)]);
        else                v = t2f(Xa[(row0 + r) * ldxa + i]);
        Xs[r * K + i] = v;
    }
    __syncthreads();

    int j = tid & (NOUT - 1);
    int g = tid / NOUT;
    int rbase = g * 8;
    const bf16* wcol = W + ((wcat && j >= 128) ? (16256 + j) : j);
    int wstep = wcat ? 128 : NOUT;

    float acc[8];
#pragma unroll
    for (int r = 0; r < 8; r++) acc[r] = 0.f;

    for (int i = 0; i < K; ++i) {
        float w = b2f(wcol[i * wstep]);
#pragma unroll
        for (int r = 0; r < 8; r++) acc[r] += Xs[(rbase + r) * K + i] * w;
    }

    float bb = bias ? b2f(bias[j]) : 0.f;
#pragma unroll
    for (int r = 0; r < 8; r++) {
        float v = acc[r] + bb;
        if (relu) v = fmaxf(v, 0.f);
        Y[(row0 + rbase + r) * ldy + j] = Cvt<TOUT>::to(v);
    }
}

// ---------------------------------------------------------------------------
__global__ __launch_bounds__(256) void stats2_k(const bf16* __restrict__ xcp,
                                                const bf16* __restrict__ xtp,
                                                const bf16* __restrict__ pos,
                                                float4* __restrict__ cstC4,
                                                float4* __restrict__ cstT4) {
    __shared__ float px[NNODE], py[NNODE];
    int tid = threadIdx.x;
    for (int t = tid; t < NNODE; t += 256) {
        px[t] = b2f(pos[2 * t]);
        py[t] = b2f(pos[2 * t + 1]);
    }
    __syncthreads();
    const bf16* xp = (blockIdx.x < 8192) ? xcp : xtp;
    float4* st4 = (blockIdx.x < 8192) ? cstC4 : cstT4;
    int pb = blockIdx.x & 8191;
    int w = tid >> 6, l = tid & 63;
    int p = pb * 4 + w;
    float x = b2f(xp[2 * p]), y = b2f(xp[2 * p + 1]);
    float vals[16];
    float m = -3.4e38f;
#pragma unroll
    for (int k = 0; k < 16; k++) {
        int n = k * 64 + l;
        float dx = x - px[n], dy = y - py[n];
        float v = -(dx * dx + dy * dy);
        vals[k] = v;
        m = fmaxf(m, v);
    }
#pragma unroll
    for (int off = 32; off; off >>= 1) m = fmaxf(m, __shfl_xor(m, off));
    float s = 0.f;
#pragma unroll
    for (int k = 0; k < 16; k++) s += __expf(vals[k] - m);
#pragma unroll
    for (int off = 32; off; off >>= 1) s += __shfl_xor(s, off);
    if (l == 0) st4[p] = make_float4(x, y, m, 1.f / s);
}

struct P8 { float* p[8]; };

// ---------------------------------------------------------------------------
// lat partials via MFMA, XCD-affine, K-split across wave halves.
// ---------------------------------------------------------------------------
__global__ __launch_bounds__(512, 4) void lat_mfma_k(const bf16* __restrict__ embT,
                                                     const float2* __restrict__ posf2,
                                                     const float4* __restrict__ cstC4,
                                                     P8 parts) {
    int i = blockIdx.x;
    int b = i & 7, r = i >> 3;
    int cs = r >> 4, nt = r & 15;
    int n0 = nt * 64;
    __shared__ __align__(16) float4 csh[512];
    __shared__ __align__(16) float4 red[4][64][8];
    int tid = threadIdx.x;
    int w = tid >> 6, l = tid & 63;
    int wl = w & 3, up = w >> 2;
    int lm = l & 15, lq = l >> 4;
    int node = n0 + wl * 16 + lm;
    float2 pn = posf2[node];
    const bf16* ebase = embT + ((size_t)b << 19) + cs * 512;
    const float4* cbase = cstC4 + b * NC + cs * 512;
    for (int t = tid; t < 512; t += 512) csh[t] = cbase[t];
    __syncthreads();

    f32x4 acc[8];
#pragma unroll
    for (int q = 0; q < 8; q++) acc[q] = (f32x4){0.f, 0.f, 0.f, 0.f};

    union AF { short8 s; u16 u[8]; };
    AF cw, nw;
    short8 bc[8], bn[8];
    int chb = up * 8;
    int c00 = chb * 32;
#pragma unroll
    for (int j = 0; j < 8; ++j) {
        float4 cc = csh[c00 + lq * 8 + j];
        float dx = cc.x - pn.x, dy = cc.y - pn.y;
        cw.u[j] = f2bs(__expf(-(dx * dx + dy * dy) - cc.z) * cc.w);
    }
#pragma unroll
    for (int t2 = 0; t2 < 8; ++t2)
        bc[t2] = ld_frag(ebase + ((size_t)(t2 * 16 + lm) << 12) + c00 + lq * 8);

    for (int ch = 0; ch < 8; ++ch) {
        int c0n = (chb + ((ch + 1) & 7)) * 32;
#pragma unroll
        for (int t2 = 0; t2 < 8; ++t2)
            bn[t2] = ld_frag(ebase + ((size_t)(t2 * 16 + lm) << 12) + c0n + lq * 8);
#pragma unroll
        for (int j = 0; j < 8; ++j) {
            float4 cc = csh[c0n + lq * 8 + j];
            float dx = cc.x - pn.x, dy = cc.y - pn.y;
            nw.u[j] = f2bs(__expf(-(dx * dx + dy * dy) - cc.z) * cc.w);
        }
#pragma unroll
        for (int t2 = 0; t2 < 8; ++t2)
            acc[t2] = __builtin_amdgcn_mfma_f32_16x16x32_bf16(cw.s, bc[t2], acc[t2], 0, 0, 0);
        cw = nw;
#pragma unroll
        for (int t2 = 0; t2 < 8; ++t2) bc[t2] = bn[t2];
    }
    if (up) {
#pragma unroll
        for (int t2 = 0; t2 < 8; ++t2)
            red[wl][l][t2] = make_float4(acc[t2][0], acc[t2][1], acc[t2][2], acc[t2][3]);
    }
    __syncthreads();
    if (!up) {
        float* part = parts.p[cs] + (((size_t)(b * NNODE + n0 + wl * 16 + lq * 4)) << 7) + lm;
#pragma unroll
        for (int t2 = 0; t2 < 8; ++t2) {
            float4 o = red[wl][l][t2];
#pragma unroll
            for (int r2 = 0; r2 < 4; ++r2)
                part[(r2 << 7) + t2 * 16] = acc[t2][r2] + ((const float*)&o)[r2];
        }
    }
}

__global__ __launch_bounds__(256) void reduce8_k(float* __restrict__ dst, P8 parts) {
    int i = blockIdx.x * 256 + threadIdx.x;
    float4 s = ((const float4*)parts.p[0])[i];
#pragma unroll
    for (int k = 1; k < 8; ++k) {
        float4 v = ((const float4*)parts.p[k])[i];
        s.x += v.x; s.y += v.y; s.z += v.z; s.w += v.w;
    }
    ((float4*)dst)[i] = s;
}

// ---------------------------------------------------------------------------
// z via MFMA, XCD-affine, K-split
// ---------------------------------------------------------------------------
__global__ __launch_bounds__(512, 4) void z_mfma_k(const bf16* __restrict__ latT,
                                                   const float2* __restrict__ posf2,
                                                   const float4* __restrict__ cstT4,
                                                   bf16* __restrict__ z) {
    int i = blockIdx.x;
    int b = i & 7, tt = i >> 3;
    int t0 = tt * 64;
    __shared__ __align__(8) float2 posh[1024];
    __shared__ __align__(16) float4 red[4][64][8];
    int tid = threadIdx.x;
    int w = tid >> 6, l = tid & 63;
    int wl = w & 3, up = w >> 2;
    int lm = l & 15, lq = l >> 4;
    int t = t0 + wl * 16 + lm;
    float4 qs = cstT4[b * NTT + t];
    const bf16* lbase = latT + ((size_t)b << 17);
    for (int k = tid; k < 1024; k += 512) posh[k] = posf2[k];
    __syncthreads();

    f32x4 acc[8];
#pragma unroll
    for (int q = 0; q < 8; q++) acc[q] = (f32x4){0.f, 0.f, 0.f, 0.f};

    union AF { short8 s; u16 u[8]; };
    AF cw, nw;
    short8 bc[8], bn[8];
    int chb = up * 16;
    int nb0 = chb * 32;
#pragma unroll
    for (int j = 0; j < 8; ++j) {
        float2 pn = posh[nb0 + lq * 8 + j];
        float dx = qs.x - pn.x, dy = qs.y - pn.y;
        cw.u[j] = f2bs(__expf(-(dx * dx + dy * dy) - qs.z) * qs.w);
    }
#pragma unroll
    for (int t2 = 0; t2 < 8; ++t2)
        bc[t2] = ld_frag(lbase + ((size_t)(t2 * 16 + lm) << 10) + nb0 + lq * 8);

    for (int ch = 0; ch < 16; ++ch) {
        int nbn = (chb + ((ch + 1) & 15)) * 32;
#pragma unroll
        for (int t2 = 0; t2 < 8; ++t2)
            bn[t2] = ld_frag(lbase + ((size_t)(t2 * 16 + lm) << 10) + nbn + lq * 8);
#pragma unroll
        for (int j = 0; j < 8; ++j) {
            float2 pn = posh[nbn + lq * 8 + j];
            float dx = qs.x - pn.x, dy = qs.y - pn.y;
            nw.u[j] = f2bs(__expf(-(dx * dx + dy * dy) - qs.z) * qs.w);
        }
#pragma unroll
        for (int t2 = 0; t2 < 8; ++t2)
            acc[t2] = __builtin_amdgcn_mfma_f32_16x16x32_bf16(cw.s, bc[t2], acc[t2], 0, 0, 0);
        cw = nw;
#pragma unroll
        for (int t2 = 0; t2 < 8; ++t2) bc[t2] = bn[t2];
    }
    if (up) {
#pragma unroll
        for (int t2 = 0; t2 < 8; ++t2)
            red[wl][l][t2] = make_float4(acc[t2][0], acc[t2][1], acc[t2][2], acc[t2][3]);
    }
    __syncthreads();
    if (!up) {
        bf16* zp = z + (((size_t)(b * NTT + t0 + wl * 16 + lq * 4)) << 7) + lm;
#pragma unroll
        for (int t2 = 0; t2 < 8; ++t2) {
            float4 o = red[wl][l][t2];
#pragma unroll
            for (int r2 = 0; r2 < 4; ++r2)
                zp[(r2 << 7) + t2 * 16] = __float2bfloat16(acc[t2][r2] + ((const float*)&o)[r2]);
        }
    }
}

// ---------------------------------------------------------------------------
// edge gather standalone (fallback path)
// ---------------------------------------------------------------------------
__global__ __launch_bounds__(256) void edge_gather_k(const float* __restrict__ PQ,
                                                     const int* __restrict__ rowptr,
                                                     const int* __restrict__ csr_send,
                                                     const bf16* __restrict__ mb,
                                                     const bf16* __restrict__ g1,
                                                     const bf16* __restrict__ b1,
                                                     float* __restrict__ inbox) {
    int tid = threadIdx.x;
    int w = tid >> 6, l = tid & 63;
    int gw = blockIdx.x * 4 + w;
    int b = gw >> 10, n = gw & 1023;
    const float* pqb = PQ + ((size_t)b << 18);
    float p0 = pqb[(n << 8) + l];
    float p1 = pqb[(n << 8) + l + 64];
    float mb0 = b2f(mb[l]), mb1 = b2f(mb[l + 64]);
    float g0 = b2f(g1[l]), g1v = b2f(g1[l + 64]);
    float bb0 = b2f(b1[l]), bb1 = b2f(b1[l + 64]);
    int beg = rowptr[n], end = rowptr[n + 1];
    float a0 = 0.f, a1 = 0.f;
    for (int i = beg; i < end; ++i) {
        int s = csr_send[i];
        const float* q = pqb + (s << 8) + 128;
        float m0 = p0 + q[l] + mb0;
        float m1 = p1 + q[l + 64] + mb1;
        float s1 = m0 + m1, s2 = m0 * m0 + m1 * m1;
#pragma unroll
        for (int off = 32; off; off >>= 1) {
            s1 += __shfl_xor(s1, off);
            s2 += __shfl_xor(s2, off);
        }
        float mu = s1 * (1.f / 128.f);
        float var = s2 * (1.f / 128.f) - mu * mu;
        float rs = rsqrtf(var + 1e-5f);
        a0 += (m0 - mu) * rs * g0 + bb0;
        a1 += (m1 - mu) * rs * g1v + bb1;
    }
    float* inb = inbox + ((size_t)b << 17) + (n << 7);
    inb[l] = a0;
    inb[l + 64] = a1;
}

// ---------------------------------------------------------------------------
// FUSED 4-step recurrence (cooperative): grid 512 x 256 (2 blocks/CU).
// ---------------------------------------------------------------------------
__global__ __launch_bounds__(256, 4) void steps_k(
    float* __restrict__ lat0, float* __restrict__ lat1,
    float* __restrict__ PQ, float* __restrict__ inbox,
    const bf16* __restrict__ WtMsg,
    const bf16* __restrict__ mbv, const bf16* __restrict__ g1v, const bf16* __restrict__ b1v,
    const int* __restrict__ rowptr, const int* __restrict__ csr_send,
    const bf16* __restrict__ WtNode, const bf16* __restrict__ node_b,
    const bf16* __restrict__ ln2_g, const bf16* __restrict__ ln2_b,
    bf16* __restrict__ latT)
{
    cg::grid_group grid = cg::this_grid();
    __shared__ __align__(16) short As[4][64][8];
    __shared__ __align__(16) short Bs[8][64][8];
    int tid = threadIdx.x;
    int w = tid >> 6, l = tid & 63;
    int lm = l & 15, lq = l >> 4;
    float mb0 = b2f(mbv[l]), mb1 = b2f(mbv[l + 64]);
    float g0 = b2f(g1v[l]), g1 = b2f(g1v[l + 64]);
    float bb0 = b2f(b1v[l]), bb1 = b2f(b1v[l + 64]);

    float* cur = lat0;
    float* nxt = lat1;
    for (int s = 0; s < 4; ++s) {
        // ---- phase 1: msg GEMM (8192 x 256, K=128) -> PQ; blocks 0..255
        if (blockIdx.x < 256) {
            int half = blockIdx.x & 1;
            size_t row0 = (size_t)(blockIdx.x >> 1) * 64;
            const bf16* Wtl = WtMsg + (size_t)half * 128 * 128;
            int colbase = half * 128;
            f32x4 acc[8];
#pragma unroll
            for (int i = 0; i < 8; i++) acc[i] = (f32x4){0.f, 0.f, 0.f, 0.f};
            for (int ks = 0; ks < 4; ++ks) {
                int k0 = ks * 32;
                __syncthreads();
                *(short8*)&As[w][l][0] = ld_frag(cur + (row0 + w * 16 + lm) * 128 + k0 + lq * 8);
#pragma unroll
                for (int rr = 0; rr < 2; ++rr) {
                    int idx = rr * 256 + tid;
                    int nt = idx >> 6, ll = idx & 63;
                    *(short8*)&Bs[nt][ll][0] =
                        ld_frag(Wtl + (size_t)(nt * 16 + (ll & 15)) * 128 + k0 + (ll >> 4) * 8);
                }
                __syncthreads();
                short8 a = *(const short8*)&As[w][l][0];
#pragma unroll
                for (int nt = 0; nt < 8; ++nt) {
                    short8 b = *(const short8*)&Bs[nt][l][0];
                    acc[nt] = __builtin_amdgcn_mfma_f32_16x16x32_bf16(a, b, acc[nt], 0, 0, 0);
                }
            }
#pragma unroll
            for (int nt = 0; nt < 8; ++nt)
#pragma unroll
                for (int r = 0; r < 4; ++r)
                    PQ[(row0 + w * 16 + lq * 4 + r) * 256 + colbase + nt * 16 + lm] = acc[nt][r];
        }
        __threadfence();
        grid.sync();
        // ---- phase 2: edge gather (512 blocks x 4 waves x 4 nodes)
        {
            int gw = blockIdx.x * 4 + w;
            for (int k = 0; k < 4; ++k) {
                int flat = gw * 4 + k;
                int b = flat >> 10, n = flat & 1023;
                const float* pqb = PQ + ((size_t)b << 18);
                float p0 = pqb[(n << 8) + l];
                float p1 = pqb[(n << 8) + l + 64];
                int beg = rowptr[n], end = rowptr[n + 1];
                float a0 = 0.f, a1 = 0.f;
                for (int i = beg; i < end; ++i) {
                    int sv = csr_send[i];
                    const float* q = pqb + (sv << 8) + 128;
                    float m0 = p0 + q[l] + mb0;
                    float m1 = p1 + q[l + 64] + mb1;
                    float s1 = m0 + m1, s2 = m0 * m0 + m1 * m1;
#pragma unroll
                    for (int off = 32; off; off >>= 1) {
                        s1 += __shfl_xor(s1, off);
                        s2 += __shfl_xor(s2, off);
                    }
                    float mu = s1 * (1.f / 128.f);
                    float var = s2 * (1.f / 128.f) - mu * mu;
                    float rs = rsqrtf(var + 1e-5f);
                    a0 += (m0 - mu) * rs * g0 + bb0;
                    a1 += (m1 - mu) * rs * g1 + bb1;
                }
                float* inb = inbox + ((size_t)b << 17) + (n << 7);
                inb[l] = a0;
                inb[l + 64] = a1;
            }
        }
        __threadfence();
        grid.sync();
        // ---- phase 3: node GEMM (8192 x 128, K=256) + LN; blocks 0..127
        if (blockIdx.x < 128) {
            size_t row0 = (size_t)blockIdx.x * 64;
            f32x4 acc[8];
#pragma unroll
            for (int i = 0; i < 8; i++) acc[i] = (f32x4){0.f, 0.f, 0.f, 0.f};
            for (int ks = 0; ks < 8; ++ks) {
                int k0 = ks * 32;
                __syncthreads();
                {
                    const float* src = (k0 < 128) ? cur : inbox;
                    int kk = (k0 < 128) ? k0 : (k0 - 128);
                    *(short8*)&As[w][l][0] = ld_frag(src + (row0 + w * 16 + lm) * 128 + kk + lq * 8);
                }
#pragma unroll
                for (int rr = 0; rr < 2; ++rr) {
                    int idx = rr * 256 + tid;
                    int nt = idx >> 6, ll = idx & 63;
                    *(short8*)&Bs[nt][ll][0] =
                        ld_frag(WtNode + (size_t)(nt * 16 + (ll & 15)) * 256 + k0 + (ll >> 4) * 8);
                }
                __syncthreads();
                short8 a = *(const short8*)&As[w][l][0];
#pragma unroll
                for (int nt = 0; nt < 8; ++nt) {
                    short8 b = *(const short8*)&Bs[nt][l][0];
                    acc[nt] = __builtin_amdgcn_mfma_f32_16x16x32_bf16(a, b, acc[nt], 0, 0, 0);
                }
            }
            float v[8][4];
#pragma unroll
            for (int nt = 0; nt < 8; ++nt) {
                float bb = b2f(node_b[nt * 16 + lm]);
#pragma unroll
                for (int r = 0; r < 4; ++r) v[nt][r] = acc[nt][r] + bb;
            }
#pragma unroll
            for (int r = 0; r < 4; ++r) {
                float s1 = 0.f, s2 = 0.f;
#pragma unroll
                for (int nt = 0; nt < 8; ++nt) { s1 += v[nt][r]; s2 += v[nt][r] * v[nt][r]; }
#pragma unroll
                for (int m = 1; m < 16; m <<= 1) { s1 += __shfl_xor(s1, m); s2 += __shfl_xor(s2, m); }
                float mu = s1 * (1.f / 128.f);
                float var = s2 * (1.f / 128.f) - mu * mu;
                float rs = rsqrtf(var + 1e-5f);
#pragma unroll
                for (int nt = 0; nt < 8; ++nt) {
                    int n = nt * 16 + lm;
                    v[nt][r] = (v[nt][r] - mu) * rs * b2f(ln2_g[n]) + b2f(ln2_b[n]);
                }
            }
            if (s < 3) {
#pragma unroll
                for (int nt = 0; nt < 8; ++nt)
#pragma unroll
                    for (int r = 0; r < 4; ++r)
                        nxt[(row0 + w * 16 + lq * 4 + r) * 128 + nt * 16 + lm] = v[nt][r];
            } else {
                size_t grow = row0 + w * 16 + lq * 4;
                int bb2 = (int)(grow >> 10);
                size_t rloc = grow & 1023;
#pragma unroll
                for (int nt = 0; nt < 8; ++nt) {
                    int col = nt * 16 + lm;
                    ushort4 u;
                    u.x = f2bs(v[nt][0]); u.y = f2bs(v[nt][1]);
                    u.z = f2bs(v[nt][2]); u.w = f2bs(v[nt][3]);
                    *(ushort4*)(latT + (((size_t)bb2 * 128 + col) << 10) + rloc) = u;
                }
            }
        }
        __threadfence();
        grid.sync();
        float* t = cur; cur = nxt; nxt = t;
    }
}

// ---------------------------------------------------------------------------
__global__ __launch_bounds__(256) void dec_final_k(const bf16* __restrict__ X,
                                                   const bf16* __restrict__ W2,
                                                   const bf16* __restrict__ b2v,
                                                   const int* __restrict__ flag,
                                                   void* __restrict__ out) {
    __shared__ float xs[8 * 128];
    int row0 = blockIdx.x * 8;
    int tid = threadIdx.x;
    for (int t = tid; t < 1024; t += 256) xs[t] = b2f(X[row0 * 128 + t]);
    __syncthreads();
    if (tid < 24) {
        int r = tid / 3, j = tid - r * 3;
        float acc = b2f(b2v[j]);
        for (int i = 0; i < 128; ++i) acc += xs[r * 128 + i] * b2f(W2[i * 3 + j]);
        int o = (row0 + r) * 3 + j;
        if (*flag) ((float*)out)[o] = acc;
        else       ((bf16*)out)[o] = __float2bfloat16(acc);
    }
}

// ---------------------------------------------------------------------------
extern "C" void kernel_launch(void* const* d_in, const int* in_sizes, int n_in,
                              void* d_out, int out_size, void* d_ws, size_t ws_size,
                              hipStream_t stream) {
    const int* senders = (const int*)d_in[30];
    const int* receivers = (const int*)d_in[31];

    char* base = (char*)d_ws;
    size_t off = 0;
    auto alloc = [&](size_t bytes) { char* p = base + off; off += (bytes + 255) & ~(size_t)255; return p; };

    int* flag = (int*)alloc(256);

    Tab tab;
    int pref = 0;
    for (int i = 0; i < 30; ++i) { tab.src[i] = d_in[i]; tab.pref[i] = pref; pref += in_sizes[i]; }
    tab.pref[30] = pref;
    bf16* arena = (bf16*)alloc((size_t)pref * 2);
    auto C = [&](int i) { return arena + tab.pref[i]; };

    float4* cstC4 = (float4*)alloc(32768 * sizeof(float4));
    float4* cstT4 = (float4*)alloc(32768 * sizeof(float4));
    float* lat0  = (float*)alloc(8192 * 128 * 4);
    float* lat1  = (float*)alloc(8192 * 128 * 4);
    float* inbox = (float*)alloc(8192 * 128 * 4);
    bf16* T1     = (bf16*)alloc((size_t)32768 * 128 * 2);
    bf16* T2     = (bf16*)alloc((size_t)32768 * 128 * 2);
    bf16* T3     = (bf16*)alloc((size_t)32768 * 128 * 2);
    bf16* embT   = (bf16*)alloc((size_t)8 * 128 * 4096 * 2);
    bf16* latT   = (bf16*)alloc((size_t)8 * 128 * 1024 * 2);
    bf16* xin5   = (bf16*)alloc((size_t)32768 * 8 * 2);
    float2* posf2 = (float2*)alloc(1024 * sizeof(float2));
    int* rowptr  = (int*)alloc(1025 * 4);
    int* csr_send = (int*)alloc(NEDGE * 4);
    bf16* WtEnc1 = (bf16*)alloc(16384 * 2);
    bf16* WtEnc2 = (bf16*)alloc(16384 * 2);
    bf16* WtQ1   = (bf16*)alloc(16384 * 2);
    bf16* WtQ2   = (bf16*)alloc(16384 * 2);
    bf16* WtDec0 = (bf16*)alloc(32768 * 2);
    bf16* WtDec1 = (bf16*)alloc(16384 * 2);
    bf16* WtMsg  = (bf16*)alloc(32768 * 2);
    bf16* WtNode = (bf16*)alloc(32768 * 2);
    float* PQ    = (float*)T3;
    (void)ws_size; (void)n_in; (void)out_size;

    detect_k<<<1, 256, 0, stream>>>((const u16*)d_in[3], flag);
    ingest_k<<<(pref + 255) / 256, 256, 0, stream>>>(tab, flag, arena);

    const bf16 *xc = C(0), *yc = C(1), *xt = C(2), *pos = C(3);
    const bf16 *enc_W0 = C(4), *enc_b0 = C(5), *enc_W1 = C(6), *enc_b1 = C(7), *enc_W2 = C(8), *enc_b2 = C(9);
    const bf16 *qenc_W0 = C(10), *qenc_b0 = C(11), *qenc_W1 = C(12), *qenc_b1 = C(13), *qenc_W2 = C(14), *qenc_b2 = C(15);
    const bf16 *dec_W0 = C(16), *dec_b0 = C(17), *dec_W1 = C(18), *dec_b1 = C(19), *dec_W2 = C(20), *dec_b2 = C(21);
    const bf16 *msg_W = C(22), *msg_b = C(23), *ln1_g = C(24), *ln1_b = C(25);
    const bf16 *node_W = C(26), *node_b = C(27), *ln2_g = C(28), *ln2_b = C(29);

    TT tt;
    const bf16* s9[9] = { enc_W1, enc_W2, qenc_W1, qenc_W2, dec_W1, dec_W0, msg_W, msg_W + 16384, node_W };
    bf16* dd9[9]      = { WtEnc1, WtEnc2, WtQ1,    WtQ2,    WtDec1, WtDec0, WtMsg, WtMsg + 16384, WtNode };
    int ks9[9] = { 128, 128, 128, 128, 128, 256, 128, 128, 256 };
    int tp = 0;
    for (int i = 0; i < 9; ++i) {
        tt.src[i] = s9[i]; tt.dst[i] = dd9[i]; tt.Ks[i] = ks9[i]; tt.Ns[i] = 128;
        tt.pref[i] = tp; tp += ks9[i] * 128;
    }
    tt.pref[9] = tp;

    prep_trans_k<<<128 + (tp + 255) / 256, 256, 0, stream>>>(tt, xc, yc, pos, xin5, posf2);
    build_csr_k<<<1, 1024, 0, stream>>>(receivers, senders, rowptr, csr_send);

    // encoder: xin5 -> T1 -> T2 -> embT (transposed)
    gemm_k<128, bf16, bf16><<<2048, 256, 0, stream>>>(xin5, 8, nullptr, enc_W0, 0, enc_b0, T1, 128, 5, 1);
    mfma_gemm_k<4, 0, 1, 0, 1, bf16, bf16><<<512, 256, 0, stream>>>(T1, nullptr, 128, WtEnc1, enc_b1, nullptr, nullptr, T2, 128, 0);
    mfma_gemm_k<4, 0, 0, 1, 1, bf16, bf16><<<512, 256, 0, stream>>>(T2, nullptr, 128, WtEnc2, enc_b2, nullptr, nullptr, embT, 128, 12);

    stats2_k<<<16384, 256, 0, stream>>>(xc, xt, pos, cstC4, cstT4);

    P8 parts;
    parts.p[0] = lat1;
    parts.p[1] = inbox;
    parts.p[2] = (float*)T1;
    parts.p[3] = (float*)T1 + 1048576;
    parts.p[4] = (float*)T2;
    parts.p[5] = (float*)T2 + 1048576;
    parts.p[6] = (float*)T3;
    parts.p[7] = (float*)T3 + 1048576;
    lat_mfma_k<<<1024, 512, 0, stream>>>(embT, posf2, cstC4, parts);
    reduce8_k<<<1024, 256, 0, stream>>>(lat0, parts);

    // fused 4-step recurrence (cooperative, 512 x 256); fallback on failure
    {
        void* p_lat0 = (void*)lat0;   void* p_lat1 = (void*)lat1;
        void* p_PQ = (void*)PQ;       void* p_inbox = (void*)inbox;
        void* p_WtMsg = (void*)WtMsg; void* p_mb = (void*)msg_b;
        void* p_g1 = (void*)ln1_g;    void* p_b1 = (void*)ln1_b;
        void* p_rp = (void*)rowptr;   void* p_cs = (void*)csr_send;
        void* p_WtN = (void*)WtNode;  void* p_nb = (void*)node_b;
        void* p_g2 = (void*)ln2_g;    void* p_b2 = (void*)ln2_b;
        void* p_latT = (void*)latT;
        void* args[15] = { &p_lat0, &p_lat1, &p_PQ, &p_inbox, &p_WtMsg, &p_mb, &p_g1, &p_b1,
                           &p_rp, &p_cs, &p_WtN, &p_nb, &p_g2, &p_b2, &p_latT };
        hipError_t rc = hipLaunchCooperativeKernel((void*)steps_k, dim3(512), dim3(256),
                                                   args, 0, stream);
        if (rc != hipSuccess) {
            (void)hipGetLastError();  // clear sticky error
            float* cur = lat0;
            float* nxt = lat1;
            for (int s = 0; s < 4; ++s) {
                mfma_gemm_k<4, 0, 0, 0, 2, float, float><<<256, 256, 0, stream>>>(cur, nullptr, 128, WtMsg, nullptr, nullptr, nullptr, PQ, 256, 0);
                edge_gather_k<<<2048, 256, 0, stream>>>(PQ, rowptr, csr_send, msg_b, ln1_g, ln1_b, inbox);
                if (s < 3) {
                    mfma_gemm_k<8, 1, 0, 0, 1, float, float><<<128, 256, 0, stream>>>(cur, inbox, 128, WtNode, node_b, ln2_g, ln2_b, nxt, 128, 0);
                    float* tmp = cur; cur = nxt; nxt = tmp;
                } else {
                    mfma_gemm_k<8, 1, 0, 1, 1, float, bf16><<<128, 256, 0, stream>>>(cur, inbox, 128, WtNode, node_b, ln2_g, ln2_b, latT, 128, 10);
                }
            }
        }
    }

    // query encoder: xt -> T2 -> T3 -> T1 (= q)
    gemm_k<128, bf16, bf16><<<2048, 256, 0, stream>>>(xt, 2, nullptr, qenc_W0, 0, qenc_b0, T2, 128, 2, 1);
    mfma_gemm_k<4, 0, 1, 0, 1, bf16, bf16><<<512, 256, 0, stream>>>(T2, nullptr, 128, WtQ1, qenc_b1, nullptr, nullptr, T3, 128, 0);
    mfma_gemm_k<4, 0, 0, 0, 1, bf16, bf16><<<512, 256, 0, stream>>>(T3, nullptr, 128, WtQ2, qenc_b2, nullptr, nullptr, T1, 128, 0);

    // z -> T2 (bf16)
    z_mfma_k<<<512, 512, 0, stream>>>(latT, posf2, cstT4, T2);

    // decoder: (z=T2 | q=T1) -> T3 -> T2 -> out
    mfma_gemm_k<8, 0, 1, 0, 1, bf16, bf16><<<512, 256, 0, stream>>>(T2, T1, 128, WtDec0, dec_b0, nullptr, nullptr, T3, 128, 0);
    mfma_gemm_k<4, 0, 1, 0, 1, bf16, bf16><<<512, 256, 0, stream>>>(T3, nullptr, 128, WtDec1, dec_b1, nullptr, nullptr, T2, 128, 0);
    dec_final_k<<<4096, 256, 0, stream>>>(T2, dec_W2, dec_b2, flag, d_out);
}

// Round 13
// 597.333 us; speedup vs baseline: 3.3534x; 3.3534x over previous
//
#include <hip/hip_runtime.h>
#include <hip/hip_bf16.h>
#include <string.h>

#define BB 8
#define NC 4096
#define NTT 4096
#define NNODE 1024
#define NEDGE 16384

typedef __hip_bfloat16 bf16;
typedef unsigned short u16;
typedef __attribute__((ext_vector_type(8))) short short8;
typedef __attribute__((ext_vector_type(4))) float f32x4;

__device__ __forceinline__ float b2f(bf16 x) { return __bfloat162float(x); }
__device__ __forceinline__ float t2f(float v) { return v; }
__device__ __forceinline__ float t2f(bf16 v) { return __bfloat162float(v); }

template <typename T> struct Cvt;
template <> struct Cvt<float> { static __device__ __forceinline__ float to(float v) { return v; } };
template <> struct Cvt<bf16>  { static __device__ __forceinline__ bf16  to(float v) { return __float2bfloat16(v); } };

__device__ __forceinline__ unsigned short f2bs(float x) {
    unsigned u = __float_as_uint(x);
    return (unsigned short)((u + 0x7FFFu + ((u >> 16) & 1u)) >> 16);
}

__device__ __forceinline__ short8 ld_frag(const bf16* g) {
    union { uint4 u4; short8 s8; } cv;
    cv.u4 = *(const uint4*)g;
    return cv.s8;
}
__device__ __forceinline__ short8 ld_frag(const float* g) {
    float4 f0 = *(const float4*)g;
    float4 f1 = *(const float4*)(g + 4);
    short8 r;
    r[0] = (short)f2bs(f0.x); r[1] = (short)f2bs(f0.y);
    r[2] = (short)f2bs(f0.z); r[3] = (short)f2bs(f0.w);
    r[4] = (short)f2bs(f1.x); r[5] = (short)f2bs(f1.y);
    r[6] = (short)f2bs(f1.z); r[7] = (short)f2bs(f1.w);
    return r;
}

// ---------------------------------------------------------------------------
__global__ void detect_k(const u16* __restrict__ posu, int* __restrict__ flag) {
    __shared__ int cnt;
    if (threadIdx.x == 0) cnt = 0;
    __syncthreads();
    int wild = 0;
    for (int i = threadIdx.x; i < 1024; i += 256) {
        u16 u = posu[2 * i];
        int ex = (u >> 7) & 0xFF;
        if (ex == 0 || ex == 0xFF || ex > 137 || ex < 107) wild++;
    }
    atomicAdd(&cnt, wild);
    __syncthreads();
    if (threadIdx.x == 0) *flag = (cnt > 50) ? 1 : 0;
}

// ---------------------------------------------------------------------------
struct Tab { const void* src[30]; int pref[31]; };

__global__ __launch_bounds__(256) void ingest_k(Tab tab, const int* __restrict__ flag,
                                                bf16* __restrict__ dst) {
    int idx = blockIdx.x * 256 + threadIdx.x;
    if (idx >= tab.pref[30]) return;
    int t = 0;
    while (tab.pref[t + 1] <= idx) t++;
    int e = idx - tab.pref[t];
    float v;
    if (*flag) v = ((const float*)tab.src[t])[e];
    else       v = b2f(((const bf16*)tab.src[t])[e]);
    dst[idx] = __float2bfloat16(v);
}

// ---------------------------------------------------------------------------
// fused prep (blocks 0..127) + weight transpose (blocks 128..)
// ---------------------------------------------------------------------------
struct TT { const bf16* src[9]; bf16* dst[9]; int Ks[9]; int Ns[9]; int pref[10]; };

__global__ __launch_bounds__(256) void prep_trans_k(
    TT tt,
    const bf16* __restrict__ xc, const bf16* __restrict__ yc,
    const bf16* __restrict__ pos,
    bf16* __restrict__ xin5, float2* __restrict__ posf2) {
    if (blockIdx.x < 128) {
        int row = blockIdx.x * 256 + threadIdx.x;
        bf16 z = __float2bfloat16(0.f);
        xin5[row * 8 + 0] = xc[row * 2 + 0];
        xin5[row * 8 + 1] = xc[row * 2 + 1];
        xin5[row * 8 + 2] = yc[row * 3 + 0];
        xin5[row * 8 + 3] = yc[row * 3 + 1];
        xin5[row * 8 + 4] = yc[row * 3 + 2];
        xin5[row * 8 + 5] = z;
        xin5[row * 8 + 6] = z;
        xin5[row * 8 + 7] = z;
        if (row < NNODE) posf2[row] = make_float2(b2f(pos[2 * row]), b2f(pos[2 * row + 1]));
        return;
    }
    int idx = (blockIdx.x - 128) * 256 + threadIdx.x;
    if (idx >= tt.pref[9]) return;
    int t = 0;
    while (tt.pref[t + 1] <= idx) t++;
    int e = idx - tt.pref[t];
    int N = tt.Ns[t];
    int k = e / N, n = e - k * N;
    tt.dst[t][n * tt.Ks[t] + k] = tt.src[t][e];
}

// ---------------------------------------------------------------------------
__global__ __launch_bounds__(1024) void build_csr_k(const int* __restrict__ recv,
                                                    const int* __restrict__ send,
                                                    int* __restrict__ rowptr,
                                                    int* __restrict__ csr_send) {
    __shared__ int cnt[1024];
    __shared__ int wt[16], wt2[16];
    __shared__ int cur[1024];
    int t = threadIdx.x;
    cnt[t] = 0;
    __syncthreads();
    for (int e = t; e < NEDGE; e += 1024) atomicAdd(&cnt[recv[e]], 1);
    __syncthreads();
    int v = cnt[t];
    int lane = t & 63, w = t >> 6;
#pragma unroll
    for (int off = 1; off < 64; off <<= 1) {
        int u = __shfl_up(v, off);
        if (lane >= off) v += u;
    }
    if (lane == 63) wt[w] = v;
    __syncthreads();
    if (t < 16) {
        int x = wt[t];
#pragma unroll
        for (int off = 1; off < 16; off <<= 1) {
            int u = __shfl_up(x, off);
            if (t >= off) x += u;
        }
        wt2[t] = x;
    }
    __syncthreads();
    int excl = v - cnt[t] + (w ? wt2[w - 1] : 0);
    rowptr[t] = excl;
    cur[t] = excl;
    if (t == 0) rowptr[1024] = NEDGE;
    __syncthreads();
    for (int e = t; e < NEDGE; e += 1024) {
        int pos = atomicAdd(&cur[recv[e]], 1);
        csr_send[pos] = send[e];
    }
}

// ---------------------------------------------------------------------------
// MFMA GEMM. TRANS=1: write bf16 transposed Y_T[b][col][rowlocal].
// NSPLIT=2: blockIdx.x&1 selects 128-col half.
// ---------------------------------------------------------------------------
template <int KSTEPS, int EPI, int RELU, int TRANS, int NSPLIT, typename TIN, typename TOUT>
__global__ __launch_bounds__(256) void mfma_gemm_k(
    const TIN* __restrict__ Xa, const TIN* __restrict__ Xb, int ldx,
    const bf16* __restrict__ Wt,
    const bf16* __restrict__ bias,
    const bf16* __restrict__ lng, const bf16* __restrict__ lnb,
    TOUT* __restrict__ Y, int ldy, int tshift)
{
    constexpr int K = KSTEPS * 32;
    __shared__ __align__(16) short As[4][64][8];
    __shared__ __align__(16) short Bs[8][64][8];
    int tid = threadIdx.x;
    int w = tid >> 6, l = tid & 63;
    int lm = l & 15, lq = l >> 4;
    int blk = blockIdx.x;
    int half = 0;
    if (NSPLIT == 2) { half = blk & 1; blk >>= 1; }
    const bf16* Wtl = Wt + (size_t)half * 128 * K;
    int colbase = half * 128;
    size_t row0 = (size_t)blk * 64;

    f32x4 acc[8];
#pragma unroll
    for (int i = 0; i < 8; i++) acc[i] = (f32x4){0.f, 0.f, 0.f, 0.f};

    for (int s = 0; s < KSTEPS; ++s) {
        int k0 = s * 32;
        __syncthreads();
        {
            const TIN* src = Xa; int kk = k0; int ld = ldx;
            if (Xb != nullptr && k0 >= 128) { src = Xb; kk = k0 - 128; ld = 128; }
            *(short8*)&As[w][l][0] = ld_frag(src + (row0 + w * 16 + lm) * (size_t)ld + kk + lq * 8);
        }
#pragma unroll
        for (int rr = 0; rr < 2; ++rr) {
            int idx = rr * 256 + tid;
            int nt = idx >> 6, ll = idx & 63;
            *(short8*)&Bs[nt][ll][0] =
                ld_frag(Wtl + (size_t)(nt * 16 + (ll & 15)) * K + k0 + (ll >> 4) * 8);
        }
        __syncthreads();
        short8 a = *(const short8*)&As[w][l][0];
#pragma unroll
        for (int nt = 0; nt < 8; ++nt) {
            short8 b = *(const short8*)&Bs[nt][l][0];
            acc[nt] = __builtin_amdgcn_mfma_f32_16x16x32_bf16(a, b, acc[nt], 0, 0, 0);
        }
    }

    float v[8][4];
#pragma unroll
    for (int nt = 0; nt < 8; ++nt) {
        float bb = bias ? b2f(bias[colbase + nt * 16 + lm]) : 0.f;
#pragma unroll
        for (int r = 0; r < 4; ++r) v[nt][r] = acc[nt][r] + bb;
    }
    if constexpr (EPI == 1) {
#pragma unroll
        for (int r = 0; r < 4; ++r) {
            float s1 = 0.f, s2 = 0.f;
#pragma unroll
            for (int nt = 0; nt < 8; ++nt) { s1 += v[nt][r]; s2 += v[nt][r] * v[nt][r]; }
#pragma unroll
            for (int m = 1; m < 16; m <<= 1) { s1 += __shfl_xor(s1, m); s2 += __shfl_xor(s2, m); }
            float mu = s1 * (1.f / 128.f);
            float var = s2 * (1.f / 128.f) - mu * mu;
            float rs = rsqrtf(var + 1e-5f);
#pragma unroll
            for (int nt = 0; nt < 8; ++nt) {
                int n = nt * 16 + lm;
                v[nt][r] = (v[nt][r] - mu) * rs * b2f(lng[n]) + b2f(lnb[n]);
            }
        }
    }
    if constexpr (TRANS) {
        size_t grow = row0 + w * 16 + lq * 4;
        int bb2 = (int)(grow >> tshift);
        size_t rloc = grow & (((size_t)1 << tshift) - 1);
        bf16* YT = (bf16*)Y;
#pragma unroll
        for (int nt = 0; nt < 8; ++nt) {
            int col = colbase + nt * 16 + lm;
            ushort4 u;
            float x0 = v[nt][0], x1 = v[nt][1], x2 = v[nt][2], x3 = v[nt][3];
            if (RELU) { x0 = fmaxf(x0, 0.f); x1 = fmaxf(x1, 0.f); x2 = fmaxf(x2, 0.f); x3 = fmaxf(x3, 0.f); }
            u.x = f2bs(x0); u.y = f2bs(x1); u.z = f2bs(x2); u.w = f2bs(x3);
            *(ushort4*)(YT + (((size_t)bb2 * 128 + col) << tshift) + rloc) = u;
        }
    } else {
#pragma unroll
        for (int nt = 0; nt < 8; ++nt)
#pragma unroll
            for (int r = 0; r < 4; ++r) {
                float x = v[nt][r];
                if (RELU) x = fmaxf(x, 0.f);
                Y[(row0 + w * 16 + lq * 4 + r) * (size_t)ldy + colbase + nt * 16 + lm] = Cvt<TOUT>::to(x);
            }
    }
}

// ---------------------------------------------------------------------------
// legacy row GEMM (K=5 / K=2 input layers only)
// ---------------------------------------------------------------------------
template <int NOUT, typename TIN, typename TOUT>
__global__ __launch_bounds__(256) void gemm_k(
    const TIN* __restrict__ Xa, int ldxa,
    const TIN* __restrict__ Xb,
    const bf16* __restrict__ W, int wcat,
    const bf16* __restrict__ bias,
    TOUT* __restrict__ Y, int ldy,
    int K, int relu) {
    constexpr int R = (NOUT == 256) ? 8 : 16;
    __shared__ __align__(16) float Xs[16 * 256];
    int tid = threadIdx.x;
    int row0 = blockIdx.x * R;

    int tot = R * K;
    for (int t = tid; t < tot; t += 256) {
        int r = t / K, i = t - r * K;
        float v;
        if (Xb && i >= 128) v = t2f(Xb[(row0 + r) * 128 + (i - 128)]);
        else                v = t2f(Xa[(row0 + r) * ldxa + i]);
        Xs[r * K + i] = v;
    }
    __syncthreads();

    int j = tid & (NOUT - 1);
    int g = tid / NOUT;
    int rbase = g * 8;
    const bf16* wcol = W + ((wcat && j >= 128) ? (16256 + j) : j);
    int wstep = wcat ? 128 : NOUT;

    float acc[8];
#pragma unroll
    for (int r = 0; r < 8; r++) acc[r] = 0.f;

    for (int i = 0; i < K; ++i) {
        float w = b2f(wcol[i * wstep]);
#pragma unroll
        for (int r = 0; r < 8; r++) acc[r] += Xs[(rbase + r) * K + i] * w;
    }

    float bb = bias ? b2f(bias[j]) : 0.f;
#pragma unroll
    for (int r = 0; r < 8; r++) {
        float v = acc[r] + bb;
        if (relu) v = fmaxf(v, 0.f);
        Y[(row0 + rbase + r) * ldy + j] = Cvt<TOUT>::to(v);
    }
}

// ---------------------------------------------------------------------------
// fused softmax stats for xc (blocks <8192) and xt
// ---------------------------------------------------------------------------
__global__ __launch_bounds__(256) void stats2_k(const bf16* __restrict__ xcp,
                                                const bf16* __restrict__ xtp,
                                                const bf16* __restrict__ pos,
                                                float4* __restrict__ cstC4,
                                                float4* __restrict__ cstT4) {
    __shared__ float px[NNODE], py[NNODE];
    int tid = threadIdx.x;
    for (int t = tid; t < NNODE; t += 256) {
        px[t] = b2f(pos[2 * t]);
        py[t] = b2f(pos[2 * t + 1]);
    }
    __syncthreads();
    const bf16* xp = (blockIdx.x < 8192) ? xcp : xtp;
    float4* st4 = (blockIdx.x < 8192) ? cstC4 : cstT4;
    int pb = blockIdx.x & 8191;
    int w = tid >> 6, l = tid & 63;
    int p = pb * 4 + w;
    float x = b2f(xp[2 * p]), y = b2f(xp[2 * p + 1]);
    float vals[16];
    float m = -3.4e38f;
#pragma unroll
    for (int k = 0; k < 16; k++) {
        int n = k * 64 + l;
        float dx = x - px[n], dy = y - py[n];
        float v = -(dx * dx + dy * dy);
        vals[k] = v;
        m = fmaxf(m, v);
    }
#pragma unroll
    for (int off = 32; off; off >>= 1) m = fmaxf(m, __shfl_xor(m, off));
    float s = 0.f;
#pragma unroll
    for (int k = 0; k < 16; k++) s += __expf(vals[k] - m);
#pragma unroll
    for (int off = 32; off; off >>= 1) s += __shfl_xor(s, off);
    if (l == 0) st4[p] = make_float4(x, y, m, 1.f / s);
}

struct P8 { float* p[8]; };

// ---------------------------------------------------------------------------
// lat partials via MFMA, XCD-affine, K-split across wave halves.
// ---------------------------------------------------------------------------
__global__ __launch_bounds__(512, 4) void lat_mfma_k(const bf16* __restrict__ embT,
                                                     const float2* __restrict__ posf2,
                                                     const float4* __restrict__ cstC4,
                                                     P8 parts) {
    int i = blockIdx.x;
    int b = i & 7, r = i >> 3;
    int cs = r >> 4, nt = r & 15;
    int n0 = nt * 64;
    __shared__ __align__(16) float4 csh[512];
    __shared__ __align__(16) float4 red[4][64][8];
    int tid = threadIdx.x;
    int w = tid >> 6, l = tid & 63;
    int wl = w & 3, up = w >> 2;
    int lm = l & 15, lq = l >> 4;
    int node = n0 + wl * 16 + lm;
    float2 pn = posf2[node];
    const bf16* ebase = embT + ((size_t)b << 19) + cs * 512;
    const float4* cbase = cstC4 + b * NC + cs * 512;
    for (int t = tid; t < 512; t += 512) csh[t] = cbase[t];
    __syncthreads();

    f32x4 acc[8];
#pragma unroll
    for (int q = 0; q < 8; q++) acc[q] = (f32x4){0.f, 0.f, 0.f, 0.f};

    union AF { short8 s; u16 u[8]; };
    AF cw, nw;
    short8 bc[8], bn[8];
    int chb = up * 8;
    int c00 = chb * 32;
#pragma unroll
    for (int j = 0; j < 8; ++j) {
        float4 cc = csh[c00 + lq * 8 + j];
        float dx = cc.x - pn.x, dy = cc.y - pn.y;
        cw.u[j] = f2bs(__expf(-(dx * dx + dy * dy) - cc.z) * cc.w);
    }
#pragma unroll
    for (int t2 = 0; t2 < 8; ++t2)
        bc[t2] = ld_frag(ebase + ((size_t)(t2 * 16 + lm) << 12) + c00 + lq * 8);

    for (int ch = 0; ch < 8; ++ch) {
        int c0n = (chb + ((ch + 1) & 7)) * 32;
#pragma unroll
        for (int t2 = 0; t2 < 8; ++t2)
            bn[t2] = ld_frag(ebase + ((size_t)(t2 * 16 + lm) << 12) + c0n + lq * 8);
#pragma unroll
        for (int j = 0; j < 8; ++j) {
            float4 cc = csh[c0n + lq * 8 + j];
            float dx = cc.x - pn.x, dy = cc.y - pn.y;
            nw.u[j] = f2bs(__expf(-(dx * dx + dy * dy) - cc.z) * cc.w);
        }
#pragma unroll
        for (int t2 = 0; t2 < 8; ++t2)
            acc[t2] = __builtin_amdgcn_mfma_f32_16x16x32_bf16(cw.s, bc[t2], acc[t2], 0, 0, 0);
        cw = nw;
#pragma unroll
        for (int t2 = 0; t2 < 8; ++t2) bc[t2] = bn[t2];
    }
    if (up) {
#pragma unroll
        for (int t2 = 0; t2 < 8; ++t2)
            red[wl][l][t2] = make_float4(acc[t2][0], acc[t2][1], acc[t2][2], acc[t2][3]);
    }
    __syncthreads();
    if (!up) {
        float* part = parts.p[cs] + (((size_t)(b * NNODE + n0 + wl * 16 + lq * 4)) << 7) + lm;
#pragma unroll
        for (int t2 = 0; t2 < 8; ++t2) {
            float4 o = red[wl][l][t2];
#pragma unroll
            for (int r2 = 0; r2 < 4; ++r2)
                part[(r2 << 7) + t2 * 16] = acc[t2][r2] + ((const float*)&o)[r2];
        }
    }
}

__global__ __launch_bounds__(256) void reduce8_k(float* __restrict__ dst, P8 parts) {
    int i = blockIdx.x * 256 + threadIdx.x;
    float4 s = ((const float4*)parts.p[0])[i];
#pragma unroll
    for (int k = 1; k < 8; ++k) {
        float4 v = ((const float4*)parts.p[k])[i];
        s.x += v.x; s.y += v.y; s.z += v.z; s.w += v.w;
    }
    ((float4*)dst)[i] = s;
}

// ---------------------------------------------------------------------------
// z via MFMA, XCD-affine, K-split
// ---------------------------------------------------------------------------
__global__ __launch_bounds__(512, 4) void z_mfma_k(const bf16* __restrict__ latT,
                                                   const float2* __restrict__ posf2,
                                                   const float4* __restrict__ cstT4,
                                                   bf16* __restrict__ z) {
    int i = blockIdx.x;
    int b = i & 7, tt = i >> 3;
    int t0 = tt * 64;
    __shared__ __align__(8) float2 posh[1024];
    __shared__ __align__(16) float4 red[4][64][8];
    int tid = threadIdx.x;
    int w = tid >> 6, l = tid & 63;
    int wl = w & 3, up = w >> 2;
    int lm = l & 15, lq = l >> 4;
    int t = t0 + wl * 16 + lm;
    float4 qs = cstT4[b * NTT + t];
    const bf16* lbase = latT + ((size_t)b << 17);
    for (int k = tid; k < 1024; k += 512) posh[k] = posf2[k];
    __syncthreads();

    f32x4 acc[8];
#pragma unroll
    for (int q = 0; q < 8; q++) acc[q] = (f32x4){0.f, 0.f, 0.f, 0.f};

    union AF { short8 s; u16 u[8]; };
    AF cw, nw;
    short8 bc[8], bn[8];
    int chb = up * 16;
    int nb0 = chb * 32;
#pragma unroll
    for (int j = 0; j < 8; ++j) {
        float2 pn = posh[nb0 + lq * 8 + j];
        float dx = qs.x - pn.x, dy = qs.y - pn.y;
        cw.u[j] = f2bs(__expf(-(dx * dx + dy * dy) - qs.z) * qs.w);
    }
#pragma unroll
    for (int t2 = 0; t2 < 8; ++t2)
        bc[t2] = ld_frag(lbase + ((size_t)(t2 * 16 + lm) << 10) + nb0 + lq * 8);

    for (int ch = 0; ch < 16; ++ch) {
        int nbn = (chb + ((ch + 1) & 15)) * 32;
#pragma unroll
        for (int t2 = 0; t2 < 8; ++t2)
            bn[t2] = ld_frag(lbase + ((size_t)(t2 * 16 + lm) << 10) + nbn + lq * 8);
#pragma unroll
        for (int j = 0; j < 8; ++j) {
            float2 pn = posh[nbn + lq * 8 + j];
            float dx = qs.x - pn.x, dy = qs.y - pn.y;
            nw.u[j] = f2bs(__expf(-(dx * dx + dy * dy) - qs.z) * qs.w);
        }
#pragma unroll
        for (int t2 = 0; t2 < 8; ++t2)
            acc[t2] = __builtin_amdgcn_mfma_f32_16x16x32_bf16(cw.s, bc[t2], acc[t2], 0, 0, 0);
        cw = nw;
#pragma unroll
        for (int t2 = 0; t2 < 8; ++t2) bc[t2] = bn[t2];
    }
    if (up) {
#pragma unroll
        for (int t2 = 0; t2 < 8; ++t2)
            red[wl][l][t2] = make_float4(acc[t2][0], acc[t2][1], acc[t2][2], acc[t2][3]);
    }
    __syncthreads();
    if (!up) {
        bf16* zp = z + (((size_t)(b * NTT + t0 + wl * 16 + lq * 4)) << 7) + lm;
#pragma unroll
        for (int t2 = 0; t2 < 8; ++t2) {
            float4 o = red[wl][l][t2];
#pragma unroll
            for (int r2 = 0; r2 < 4; ++r2)
                zp[(r2 << 7) + t2 * 16] = __float2bfloat16(acc[t2][r2] + ((const float*)&o)[r2]);
        }
    }
}

// ---------------------------------------------------------------------------
// edge gather: one wave per (b, node). No atomics.
// ---------------------------------------------------------------------------
__global__ __launch_bounds__(256) void edge_gather_k(const float* __restrict__ PQ,
                                                     const int* __restrict__ rowptr,
                                                     const int* __restrict__ csr_send,
                                                     const bf16* __restrict__ mb,
                                                     const bf16* __restrict__ g1,
                                                     const bf16* __restrict__ b1,
                                                     float* __restrict__ inbox) {
    int tid = threadIdx.x;
    int w = tid >> 6, l = tid & 63;
    int gw = blockIdx.x * 4 + w;
    int b = gw >> 10, n = gw & 1023;
    const float* pqb = PQ + ((size_t)b << 18);
    float p0 = pqb[(n << 8) + l];
    float p1 = pqb[(n << 8) + l + 64];
    float mb0 = b2f(mb[l]), mb1 = b2f(mb[l + 64]);
    float g0 = b2f(g1[l]), g1v = b2f(g1[l + 64]);
    float bb0 = b2f(b1[l]), bb1 = b2f(b1[l + 64]);
    int beg = rowptr[n], end = rowptr[n + 1];
    float a0 = 0.f, a1 = 0.f;
    for (int i = beg; i < end; ++i) {
        int s = csr_send[i];
        const float* q = pqb + (s << 8) + 128;
        float m0 = p0 + q[l] + mb0;
        float m1 = p1 + q[l + 64] + mb1;
        float s1 = m0 + m1, s2 = m0 * m0 + m1 * m1;
#pragma unroll
        for (int off = 32; off; off >>= 1) {
            s1 += __shfl_xor(s1, off);
            s2 += __shfl_xor(s2, off);
        }
        float mu = s1 * (1.f / 128.f);
        float var = s2 * (1.f / 128.f) - mu * mu;
        float rs = rsqrtf(var + 1e-5f);
        a0 += (m0 - mu) * rs * g0 + bb0;
        a1 += (m1 - mu) * rs * g1v + bb1;
    }
    float* inb = inbox + ((size_t)b << 17) + (n << 7);
    inb[l] = a0;
    inb[l + 64] = a1;
}

// ---------------------------------------------------------------------------
__global__ __launch_bounds__(256) void dec_final_k(const bf16* __restrict__ X,
                                                   const bf16* __restrict__ W2,
                                                   const bf16* __restrict__ b2v,
                                                   const int* __restrict__ flag,
                                                   void* __restrict__ out) {
    __shared__ float xs[8 * 128];
    int row0 = blockIdx.x * 8;
    int tid = threadIdx.x;
    for (int t = tid; t < 1024; t += 256) xs[t] = b2f(X[row0 * 128 + t]);
    __syncthreads();
    if (tid < 24) {
        int r = tid / 3, j = tid - r * 3;
        float acc = b2f(b2v[j]);
        for (int i = 0; i < 128; ++i) acc += xs[r * 128 + i] * b2f(W2[i * 3 + j]);
        int o = (row0 + r) * 3 + j;
        if (*flag) ((float*)out)[o] = acc;
        else       ((bf16*)out)[o] = __float2bfloat16(acc);
    }
}

// ---------------------------------------------------------------------------
extern "C" void kernel_launch(void* const* d_in, const int* in_sizes, int n_in,
                              void* d_out, int out_size, void* d_ws, size_t ws_size,
                              hipStream_t stream) {
    const int* senders = (const int*)d_in[30];
    const int* receivers = (const int*)d_in[31];

    char* base = (char*)d_ws;
    size_t off = 0;
    auto alloc = [&](size_t bytes) { char* p = base + off; off += (bytes + 255) & ~(size_t)255; return p; };

    int* flag = (int*)alloc(256);

    Tab tab;
    int pref = 0;
    for (int i = 0; i < 30; ++i) { tab.src[i] = d_in[i]; tab.pref[i] = pref; pref += in_sizes[i]; }
    tab.pref[30] = pref;
    bf16* arena = (bf16*)alloc((size_t)pref * 2);
    auto C = [&](int i) { return arena + tab.pref[i]; };

    float4* cstC4 = (float4*)alloc(32768 * sizeof(float4));
    float4* cstT4 = (float4*)alloc(32768 * sizeof(float4));
    float* lat0  = (float*)alloc(8192 * 128 * 4);
    float* lat1  = (float*)alloc(8192 * 128 * 4);
    float* inbox = (float*)alloc(8192 * 128 * 4);
    bf16* T1     = (bf16*)alloc((size_t)32768 * 128 * 2);
    bf16* T2     = (bf16*)alloc((size_t)32768 * 128 * 2);
    bf16* T3     = (bf16*)alloc((size_t)32768 * 128 * 2);
    bf16* embT   = (bf16*)alloc((size_t)8 * 128 * 4096 * 2);
    bf16* latT   = (bf16*)alloc((size_t)8 * 128 * 1024 * 2);
    bf16* xin5   = (bf16*)alloc((size_t)32768 * 8 * 2);
    float2* posf2 = (float2*)alloc(1024 * sizeof(float2));
    int* rowptr  = (int*)alloc(1025 * 4);
    int* csr_send = (int*)alloc(NEDGE * 4);
    bf16* WtEnc1 = (bf16*)alloc(16384 * 2);
    bf16* WtEnc2 = (bf16*)alloc(16384 * 2);
    bf16* WtQ1   = (bf16*)alloc(16384 * 2);
    bf16* WtQ2   = (bf16*)alloc(16384 * 2);
    bf16* WtDec0 = (bf16*)alloc(32768 * 2);
    bf16* WtDec1 = (bf16*)alloc(16384 * 2);
    bf16* WtMsg  = (bf16*)alloc(32768 * 2);
    bf16* WtNode = (bf16*)alloc(32768 * 2);
    float* PQ    = (float*)T3;
    (void)ws_size; (void)n_in; (void)out_size;

    detect_k<<<1, 256, 0, stream>>>((const u16*)d_in[3], flag);
    ingest_k<<<(pref + 255) / 256, 256, 0, stream>>>(tab, flag, arena);

    const bf16 *xc = C(0), *yc = C(1), *xt = C(2), *pos = C(3);
    const bf16 *enc_W0 = C(4), *enc_b0 = C(5), *enc_W1 = C(6), *enc_b1 = C(7), *enc_W2 = C(8), *enc_b2 = C(9);
    const bf16 *qenc_W0 = C(10), *qenc_b0 = C(11), *qenc_W1 = C(12), *qenc_b1 = C(13), *qenc_W2 = C(14), *qenc_b2 = C(15);
    const bf16 *dec_W0 = C(16), *dec_b0 = C(17), *dec_W1 = C(18), *dec_b1 = C(19), *dec_W2 = C(20), *dec_b2 = C(21);
    const bf16 *msg_W = C(22), *msg_b = C(23), *ln1_g = C(24), *ln1_b = C(25);
    const bf16 *node_W = C(26), *node_b = C(27), *ln2_g = C(28), *ln2_b = C(29);

    TT tt;
    const bf16* s9[9] = { enc_W1, enc_W2, qenc_W1, qenc_W2, dec_W1, dec_W0, msg_W, msg_W + 16384, node_W };
    bf16* dd9[9]      = { WtEnc1, WtEnc2, WtQ1,    WtQ2,    WtDec1, WtDec0, WtMsg, WtMsg + 16384, WtNode };
    int ks9[9] = { 128, 128, 128, 128, 128, 256, 128, 128, 256 };
    int tp = 0;
    for (int i = 0; i < 9; ++i) {
        tt.src[i] = s9[i]; tt.dst[i] = dd9[i]; tt.Ks[i] = ks9[i]; tt.Ns[i] = 128;
        tt.pref[i] = tp; tp += ks9[i] * 128;
    }
    tt.pref[9] = tp;

    prep_trans_k<<<128 + (tp + 255) / 256, 256, 0, stream>>>(tt, xc, yc, pos, xin5, posf2);
    build_csr_k<<<1, 1024, 0, stream>>>(receivers, senders, rowptr, csr_send);

    // encoder: xin5 -> T1 -> T2 -> embT (transposed)
    gemm_k<128, bf16, bf16><<<2048, 256, 0, stream>>>(xin5, 8, nullptr, enc_W0, 0, enc_b0, T1, 128, 5, 1);
    mfma_gemm_k<4, 0, 1, 0, 1, bf16, bf16><<<512, 256, 0, stream>>>(T1, nullptr, 128, WtEnc1, enc_b1, nullptr, nullptr, T2, 128, 0);
    mfma_gemm_k<4, 0, 0, 1, 1, bf16, bf16><<<512, 256, 0, stream>>>(T2, nullptr, 128, WtEnc2, enc_b2, nullptr, nullptr, embT, 128, 12);

    stats2_k<<<16384, 256, 0, stream>>>(xc, xt, pos, cstC4, cstT4);

    P8 parts;
    parts.p[0] = lat1;
    parts.p[1] = inbox;
    parts.p[2] = (float*)T1;
    parts.p[3] = (float*)T1 + 1048576;
    parts.p[4] = (float*)T2;
    parts.p[5] = (float*)T2 + 1048576;
    parts.p[6] = (float*)T3;
    parts.p[7] = (float*)T3 + 1048576;
    lat_mfma_k<<<1024, 512, 0, stream>>>(embT, posf2, cstC4, parts);
    reduce8_k<<<1024, 256, 0, stream>>>(lat0, parts);

    // 4-step recurrence: multi-launch (stream-ordered launches are the cheap
    // grid barrier on MI355X — cooperative grid.sync measured ~135 µs/sync)
    float* cur = lat0;
    float* nxt = lat1;
    for (int s = 0; s < 4; ++s) {
        mfma_gemm_k<4, 0, 0, 0, 2, float, float><<<256, 256, 0, stream>>>(cur, nullptr, 128, WtMsg, nullptr, nullptr, nullptr, PQ, 256, 0);
        edge_gather_k<<<2048, 256, 0, stream>>>(PQ, rowptr, csr_send, msg_b, ln1_g, ln1_b, inbox);
        if (s < 3) {
            mfma_gemm_k<8, 1, 0, 0, 1, float, float><<<128, 256, 0, stream>>>(cur, inbox, 128, WtNode, node_b, ln2_g, ln2_b, nxt, 128, 0);
            float* tmp = cur; cur = nxt; nxt = tmp;
        } else {
            mfma_gemm_k<8, 1, 0, 1, 1, float, bf16><<<128, 256, 0, stream>>>(cur, inbox, 128, WtNode, node_b, ln2_g, ln2_b, latT, 128, 10);
        }
    }

    // query encoder: xt -> T2 -> T3 -> T1 (= q)
    gemm_k<128, bf16, bf16><<<2048, 256, 0, stream>>>(xt, 2, nullptr, qenc_W0, 0, qenc_b0, T2, 128, 2, 1);
    mfma_gemm_k<4, 0, 1, 0, 1, bf16, bf16><<<512, 256, 0, stream>>>(T2, nullptr, 128, WtQ1, qenc_b1, nullptr, nullptr, T3, 128, 0);
    mfma_gemm_k<4, 0, 0, 0, 1, bf16, bf16><<<512, 256, 0, stream>>>(T3, nullptr, 128, WtQ2, qenc_b2, nullptr, nullptr, T1, 128, 0);

    // z -> T2 (bf16)
    z_mfma_k<<<512, 512, 0, stream>>>(latT, posf2, cstT4, T2);

    // decoder: (z=T2 | q=T1) -> T3 -> T2 -> out
    mfma_gemm_k<8, 0, 1, 0, 1, bf16, bf16><<<512, 256, 0, stream>>>(T2, T1, 128, WtDec0, dec_b0, nullptr, nullptr, T3, 128, 0);
    mfma_gemm_k<4, 0, 1, 0, 1, bf16, bf16><<<512, 256, 0, stream>>>(T3, nullptr, 128, WtDec1, dec_b1, nullptr, nullptr, T2, 128, 0);
    dec_final_k<<<4096, 256, 0, stream>>>(T2, dec_W2, dec_b2, flag, d_out);
}

// Round 14
// 594.224 us; speedup vs baseline: 3.3709x; 1.0052x over previous
//
#include <hip/hip_runtime.h>
#include <hip/hip_bf16.h>
#include <string.h>

#define BB 8
#define NC 4096
#define NTT 4096
#define NNODE 1024
#define NEDGE 16384

typedef __hip_bfloat16 bf16;
typedef unsigned short u16;
typedef __attribute__((ext_vector_type(8))) short short8;
typedef __attribute__((ext_vector_type(4))) float f32x4;

__device__ __forceinline__ float b2f(bf16 x) { return __bfloat162float(x); }
__device__ __forceinline__ float t2f(float v) { return v; }
__device__ __forceinline__ float t2f(bf16 v) { return __bfloat162float(v); }

template <typename T> struct Cvt;
template <> struct Cvt<float> { static __device__ __forceinline__ float to(float v) { return v; } };
template <> struct Cvt<bf16>  { static __device__ __forceinline__ bf16  to(float v) { return __float2bfloat16(v); } };

__device__ __forceinline__ unsigned short f2bs(float x) {
    unsigned u = __float_as_uint(x);
    return (unsigned short)((u + 0x7FFFu + ((u >> 16) & 1u)) >> 16);
}

__device__ __forceinline__ short8 ld_frag(const bf16* g) {
    union { uint4 u4; short8 s8; } cv;
    cv.u4 = *(const uint4*)g;
    return cv.s8;
}
__device__ __forceinline__ short8 ld_frag(const float* g) {
    float4 f0 = *(const float4*)g;
    float4 f1 = *(const float4*)(g + 4);
    short8 r;
    r[0] = (short)f2bs(f0.x); r[1] = (short)f2bs(f0.y);
    r[2] = (short)f2bs(f0.z); r[3] = (short)f2bs(f0.w);
    r[4] = (short)f2bs(f1.x); r[5] = (short)f2bs(f1.y);
    r[6] = (short)f2bs(f1.z); r[7] = (short)f2bs(f1.w);
    return r;
}

// ---------------------------------------------------------------------------
__global__ void detect_k(const u16* __restrict__ posu, int* __restrict__ flag) {
    __shared__ int cnt;
    if (threadIdx.x == 0) cnt = 0;
    __syncthreads();
    int wild = 0;
    for (int i = threadIdx.x; i < 1024; i += 256) {
        u16 u = posu[2 * i];
        int ex = (u >> 7) & 0xFF;
        if (ex == 0 || ex == 0xFF || ex > 137 || ex < 107) wild++;
    }
    atomicAdd(&cnt, wild);
    __syncthreads();
    if (threadIdx.x == 0) *flag = (cnt > 50) ? 1 : 0;
}

// ---------------------------------------------------------------------------
struct Tab { const void* src[30]; int pref[31]; };

__global__ __launch_bounds__(256) void ingest_k(Tab tab, const int* __restrict__ flag,
                                                bf16* __restrict__ dst) {
    int idx = blockIdx.x * 256 + threadIdx.x;
    if (idx >= tab.pref[30]) return;
    int t = 0;
    while (tab.pref[t + 1] <= idx) t++;
    int e = idx - tab.pref[t];
    float v;
    if (*flag) v = ((const float*)tab.src[t])[e];
    else       v = b2f(((const bf16*)tab.src[t])[e]);
    dst[idx] = __float2bfloat16(v);
}

// ---------------------------------------------------------------------------
// fused prep (blocks 0..127) + zero-padding weight transpose (blocks 128..)
//   dst[n*dK + k] = (k < srcK) ? src[k*N + n] : 0
// ---------------------------------------------------------------------------
struct TT { const bf16* src[11]; bf16* dst[11]; int srcK[11]; int dK[11]; int pref[12]; };

__global__ __launch_bounds__(256) void prep_trans_k(
    TT tt,
    const bf16* __restrict__ xc, const bf16* __restrict__ yc,
    const bf16* __restrict__ xt,
    const bf16* __restrict__ pos,
    bf16* __restrict__ xin32, bf16* __restrict__ xt32,
    float2* __restrict__ posf2) {
    if (blockIdx.x < 128) {
        int row = blockIdx.x * 256 + threadIdx.x;
        bf16 z = __float2bfloat16(0.f);
        bf16* xr = xin32 + row * 32;
        xr[0] = xc[row * 2 + 0];
        xr[1] = xc[row * 2 + 1];
        xr[2] = yc[row * 3 + 0];
        xr[3] = yc[row * 3 + 1];
        xr[4] = yc[row * 3 + 2];
#pragma unroll
        for (int k = 5; k < 32; ++k) xr[k] = z;
        bf16* tr = xt32 + row * 32;
        tr[0] = xt[row * 2 + 0];
        tr[1] = xt[row * 2 + 1];
#pragma unroll
        for (int k = 2; k < 32; ++k) tr[k] = z;
        if (row < NNODE) posf2[row] = make_float2(b2f(pos[2 * row]), b2f(pos[2 * row + 1]));
        return;
    }
    int idx = (blockIdx.x - 128) * 256 + threadIdx.x;
    if (idx >= tt.pref[11]) return;
    int t = 0;
    while (tt.pref[t + 1] <= idx) t++;
    int e = idx - tt.pref[t];
    int k = e >> 7, n = e & 127;   // N is always 128
    bf16 v = (k < tt.srcK[t]) ? tt.src[t][k * 128 + n] : __float2bfloat16(0.f);
    tt.dst[t][n * tt.dK[t] + k] = v;
}

// ---------------------------------------------------------------------------
__global__ __launch_bounds__(1024) void build_csr_k(const int* __restrict__ recv,
                                                    const int* __restrict__ send,
                                                    int* __restrict__ rowptr,
                                                    int* __restrict__ csr_send) {
    __shared__ int cnt[1024];
    __shared__ int wt[16], wt2[16];
    __shared__ int cur[1024];
    int t = threadIdx.x;
    cnt[t] = 0;
    __syncthreads();
    for (int e = t; e < NEDGE; e += 1024) atomicAdd(&cnt[recv[e]], 1);
    __syncthreads();
    int v = cnt[t];
    int lane = t & 63, w = t >> 6;
#pragma unroll
    for (int off = 1; off < 64; off <<= 1) {
        int u = __shfl_up(v, off);
        if (lane >= off) v += u;
    }
    if (lane == 63) wt[w] = v;
    __syncthreads();
    if (t < 16) {
        int x = wt[t];
#pragma unroll
        for (int off = 1; off < 16; off <<= 1) {
            int u = __shfl_up(x, off);
            if (t >= off) x += u;
        }
        wt2[t] = x;
    }
    __syncthreads();
    int excl = v - cnt[t] + (w ? wt2[w - 1] : 0);
    rowptr[t] = excl;
    cur[t] = excl;
    if (t == 0) rowptr[1024] = NEDGE;
    __syncthreads();
    for (int e = t; e < NEDGE; e += 1024) {
        int pos = atomicAdd(&cur[recv[e]], 1);
        csr_send[pos] = send[e];
    }
}

// ---------------------------------------------------------------------------
// MFMA GEMM. TRANS=1: write bf16 transposed Y_T[b][col][rowlocal].
// NSPLIT=2: blockIdx.x&1 selects 128-col half.
// ---------------------------------------------------------------------------
template <int KSTEPS, int EPI, int RELU, int TRANS, int NSPLIT, typename TIN, typename TOUT>
__global__ __launch_bounds__(256) void mfma_gemm_k(
    const TIN* __restrict__ Xa, const TIN* __restrict__ Xb, int ldx,
    const bf16* __restrict__ Wt,
    const bf16* __restrict__ bias,
    const bf16* __restrict__ lng, const bf16* __restrict__ lnb,
    TOUT* __restrict__ Y, int ldy, int tshift)
{
    constexpr int K = KSTEPS * 32;
    __shared__ __align__(16) short As[4][64][8];
    __shared__ __align__(16) short Bs[8][64][8];
    int tid = threadIdx.x;
    int w = tid >> 6, l = tid & 63;
    int lm = l & 15, lq = l >> 4;
    int blk = blockIdx.x;
    int half = 0;
    if (NSPLIT == 2) { half = blk & 1; blk >>= 1; }
    const bf16* Wtl = Wt + (size_t)half * 128 * K;
    int colbase = half * 128;
    size_t row0 = (size_t)blk * 64;

    f32x4 acc[8];
#pragma unroll
    for (int i = 0; i < 8; i++) acc[i] = (f32x4){0.f, 0.f, 0.f, 0.f};

    for (int s = 0; s < KSTEPS; ++s) {
        int k0 = s * 32;
        __syncthreads();
        {
            const TIN* src = Xa; int kk = k0; int ld = ldx;
            if (Xb != nullptr && k0 >= 128) { src = Xb; kk = k0 - 128; ld = 128; }
            *(short8*)&As[w][l][0] = ld_frag(src + (row0 + w * 16 + lm) * (size_t)ld + kk + lq * 8);
        }
#pragma unroll
        for (int rr = 0; rr < 2; ++rr) {
            int idx = rr * 256 + tid;
            int nt = idx >> 6, ll = idx & 63;
            *(short8*)&Bs[nt][ll][0] =
                ld_frag(Wtl + (size_t)(nt * 16 + (ll & 15)) * K + k0 + (ll >> 4) * 8);
        }
        __syncthreads();
        short8 a = *(const short8*)&As[w][l][0];
#pragma unroll
        for (int nt = 0; nt < 8; ++nt) {
            short8 b = *(const short8*)&Bs[nt][l][0];
            acc[nt] = __builtin_amdgcn_mfma_f32_16x16x32_bf16(a, b, acc[nt], 0, 0, 0);
        }
    }

    float v[8][4];
#pragma unroll
    for (int nt = 0; nt < 8; ++nt) {
        float bb = bias ? b2f(bias[colbase + nt * 16 + lm]) : 0.f;
#pragma unroll
        for (int r = 0; r < 4; ++r) v[nt][r] = acc[nt][r] + bb;
    }
    if constexpr (EPI == 1) {
#pragma unroll
        for (int r = 0; r < 4; ++r) {
            float s1 = 0.f, s2 = 0.f;
#pragma unroll
            for (int nt = 0; nt < 8; ++nt) { s1 += v[nt][r]; s2 += v[nt][r] * v[nt][r]; }
#pragma unroll
            for (int m = 1; m < 16; m <<= 1) { s1 += __shfl_xor(s1, m); s2 += __shfl_xor(s2, m); }
            float mu = s1 * (1.f / 128.f);
            float var = s2 * (1.f / 128.f) - mu * mu;
            float rs = rsqrtf(var + 1e-5f);
#pragma unroll
            for (int nt = 0; nt < 8; ++nt) {
                int n = nt * 16 + lm;
                v[nt][r] = (v[nt][r] - mu) * rs * b2f(lng[n]) + b2f(lnb[n]);
            }
        }
    }
    if constexpr (TRANS) {
        size_t grow = row0 + w * 16 + lq * 4;
        int bb2 = (int)(grow >> tshift);
        size_t rloc = grow & (((size_t)1 << tshift) - 1);
        bf16* YT = (bf16*)Y;
#pragma unroll
        for (int nt = 0; nt < 8; ++nt) {
            int col = colbase + nt * 16 + lm;
            ushort4 u;
            float x0 = v[nt][0], x1 = v[nt][1], x2 = v[nt][2], x3 = v[nt][3];
            if (RELU) { x0 = fmaxf(x0, 0.f); x1 = fmaxf(x1, 0.f); x2 = fmaxf(x2, 0.f); x3 = fmaxf(x3, 0.f); }
            u.x = f2bs(x0); u.y = f2bs(x1); u.z = f2bs(x2); u.w = f2bs(x3);
            *(ushort4*)(YT + (((size_t)bb2 * 128 + col) << tshift) + rloc) = u;
        }
    } else {
#pragma unroll
        for (int nt = 0; nt < 8; ++nt)
#pragma unroll
            for (int r = 0; r < 4; ++r) {
                float x = v[nt][r];
                if (RELU) x = fmaxf(x, 0.f);
                Y[(row0 + w * 16 + lq * 4 + r) * (size_t)ldy + colbase + nt * 16 + lm] = Cvt<TOUT>::to(x);
            }
    }
}

// ---------------------------------------------------------------------------
// fused softmax stats for xc (blocks <8192) and xt
// ---------------------------------------------------------------------------
__global__ __launch_bounds__(256) void stats2_k(const bf16* __restrict__ xcp,
                                                const bf16* __restrict__ xtp,
                                                const bf16* __restrict__ pos,
                                                float4* __restrict__ cstC4,
                                                float4* __restrict__ cstT4) {
    __shared__ float px[NNODE], py[NNODE];
    int tid = threadIdx.x;
    for (int t = tid; t < NNODE; t += 256) {
        px[t] = b2f(pos[2 * t]);
        py[t] = b2f(pos[2 * t + 1]);
    }
    __syncthreads();
    const bf16* xp = (blockIdx.x < 8192) ? xcp : xtp;
    float4* st4 = (blockIdx.x < 8192) ? cstC4 : cstT4;
    int pb = blockIdx.x & 8191;
    int w = tid >> 6, l = tid & 63;
    int p = pb * 4 + w;
    float x = b2f(xp[2 * p]), y = b2f(xp[2 * p + 1]);
    float vals[16];
    float m = -3.4e38f;
#pragma unroll
    for (int k = 0; k < 16; k++) {
        int n = k * 64 + l;
        float dx = x - px[n], dy = y - py[n];
        float v = -(dx * dx + dy * dy);
        vals[k] = v;
        m = fmaxf(m, v);
    }
#pragma unroll
    for (int off = 32; off; off >>= 1) m = fmaxf(m, __shfl_xor(m, off));
    float s = 0.f;
#pragma unroll
    for (int k = 0; k < 16; k++) s += __expf(vals[k] - m);
#pragma unroll
    for (int off = 32; off; off >>= 1) s += __shfl_xor(s, off);
    if (l == 0) st4[p] = make_float4(x, y, m, 1.f / s);
}

struct P8 { float* p[8]; };

// ---------------------------------------------------------------------------
// lat partials via MFMA, XCD-affine, K-split across wave halves.
// red[wl][t2][l]: lane-contiguous float4 -> conflict-free LDS reduction.
// ---------------------------------------------------------------------------
__global__ __launch_bounds__(512, 4) void lat_mfma_k(const bf16* __restrict__ embT,
                                                     const float2* __restrict__ posf2,
                                                     const float4* __restrict__ cstC4,
                                                     P8 parts) {
    int i = blockIdx.x;
    int b = i & 7, r = i >> 3;
    int cs = r >> 4, nt = r & 15;
    int n0 = nt * 64;
    __shared__ __align__(16) float4 csh[512];
    __shared__ __align__(16) float4 red[4][8][64];
    int tid = threadIdx.x;
    int w = tid >> 6, l = tid & 63;
    int wl = w & 3, up = w >> 2;
    int lm = l & 15, lq = l >> 4;
    int node = n0 + wl * 16 + lm;
    float2 pn = posf2[node];
    const bf16* ebase = embT + ((size_t)b << 19) + cs * 512;
    const float4* cbase = cstC4 + b * NC + cs * 512;
    for (int t = tid; t < 512; t += 512) csh[t] = cbase[t];
    __syncthreads();

    f32x4 acc[8];
#pragma unroll
    for (int q = 0; q < 8; q++) acc[q] = (f32x4){0.f, 0.f, 0.f, 0.f};

    union AF { short8 s; u16 u[8]; };
    AF cw, nw;
    short8 bc[8], bn[8];
    int chb = up * 8;
    int c00 = chb * 32;
#pragma unroll
    for (int j = 0; j < 8; ++j) {
        float4 cc = csh[c00 + lq * 8 + j];
        float dx = cc.x - pn.x, dy = cc.y - pn.y;
        cw.u[j] = f2bs(__expf(-(dx * dx + dy * dy) - cc.z) * cc.w);
    }
#pragma unroll
    for (int t2 = 0; t2 < 8; ++t2)
        bc[t2] = ld_frag(ebase + ((size_t)(t2 * 16 + lm) << 12) + c00 + lq * 8);

    for (int ch = 0; ch < 8; ++ch) {
        int c0n = (chb + ((ch + 1) & 7)) * 32;
#pragma unroll
        for (int t2 = 0; t2 < 8; ++t2)
            bn[t2] = ld_frag(ebase + ((size_t)(t2 * 16 + lm) << 12) + c0n + lq * 8);
#pragma unroll
        for (int j = 0; j < 8; ++j) {
            float4 cc = csh[c0n + lq * 8 + j];
            float dx = cc.x - pn.x, dy = cc.y - pn.y;
            nw.u[j] = f2bs(__expf(-(dx * dx + dy * dy) - cc.z) * cc.w);
        }
#pragma unroll
        for (int t2 = 0; t2 < 8; ++t2)
            acc[t2] = __builtin_amdgcn_mfma_f32_16x16x32_bf16(cw.s, bc[t2], acc[t2], 0, 0, 0);
        cw = nw;
#pragma unroll
        for (int t2 = 0; t2 < 8; ++t2) bc[t2] = bn[t2];
    }
    if (up) {
#pragma unroll
        for (int t2 = 0; t2 < 8; ++t2)
            red[wl][t2][l] = make_float4(acc[t2][0], acc[t2][1], acc[t2][2], acc[t2][3]);
    }
    __syncthreads();
    if (!up) {
        float* part = parts.p[cs] + (((size_t)(b * NNODE + n0 + wl * 16 + lq * 4)) << 7) + lm;
#pragma unroll
        for (int t2 = 0; t2 < 8; ++t2) {
            float4 o = red[wl][t2][l];
#pragma unroll
            for (int r2 = 0; r2 < 4; ++r2)
                part[(r2 << 7) + t2 * 16] = acc[t2][r2] + ((const float*)&o)[r2];
        }
    }
}

__global__ __launch_bounds__(256) void reduce8_k(float* __restrict__ dst, P8 parts) {
    int i = blockIdx.x * 256 + threadIdx.x;
    float4 s = ((const float4*)parts.p[0])[i];
#pragma unroll
    for (int k = 1; k < 8; ++k) {
        float4 v = ((const float4*)parts.p[k])[i];
        s.x += v.x; s.y += v.y; s.z += v.z; s.w += v.w;
    }
    ((float4*)dst)[i] = s;
}

// ---------------------------------------------------------------------------
// z via MFMA, XCD-affine, K-split; conflict-free red layout.
// ---------------------------------------------------------------------------
__global__ __launch_bounds__(512, 4) void z_mfma_k(const bf16* __restrict__ latT,
                                                   const float2* __restrict__ posf2,
                                                   const float4* __restrict__ cstT4,
                                                   bf16* __restrict__ z) {
    int i = blockIdx.x;
    int b = i & 7, tt = i >> 3;
    int t0 = tt * 64;
    __shared__ __align__(8) float2 posh[1024];
    __shared__ __align__(16) float4 red[4][8][64];
    int tid = threadIdx.x;
    int w = tid >> 6, l = tid & 63;
    int wl = w & 3, up = w >> 2;
    int lm = l & 15, lq = l >> 4;
    int t = t0 + wl * 16 + lm;
    float4 qs = cstT4[b * NTT + t];
    const bf16* lbase = latT + ((size_t)b << 17);
    for (int k = tid; k < 1024; k += 512) posh[k] = posf2[k];
    __syncthreads();

    f32x4 acc[8];
#pragma unroll
    for (int q = 0; q < 8; q++) acc[q] = (f32x4){0.f, 0.f, 0.f, 0.f};

    union AF { short8 s; u16 u[8]; };
    AF cw, nw;
    short8 bc[8], bn[8];
    int chb = up * 16;
    int nb0 = chb * 32;
#pragma unroll
    for (int j = 0; j < 8; ++j) {
        float2 pn = posh[nb0 + lq * 8 + j];
        float dx = qs.x - pn.x, dy = qs.y - pn.y;
        cw.u[j] = f2bs(__expf(-(dx * dx + dy * dy) - qs.z) * qs.w);
    }
#pragma unroll
    for (int t2 = 0; t2 < 8; ++t2)
        bc[t2] = ld_frag(lbase + ((size_t)(t2 * 16 + lm) << 10) + nb0 + lq * 8);

    for (int ch = 0; ch < 16; ++ch) {
        int nbn = (chb + ((ch + 1) & 15)) * 32;
#pragma unroll
        for (int t2 = 0; t2 < 8; ++t2)
            bn[t2] = ld_frag(lbase + ((size_t)(t2 * 16 + lm) << 10) + nbn + lq * 8);
#pragma unroll
        for (int j = 0; j < 8; ++j) {
            float2 pn = posh[nbn + lq * 8 + j];
            float dx = qs.x - pn.x, dy = qs.y - pn.y;
            nw.u[j] = f2bs(__expf(-(dx * dx + dy * dy) - qs.z) * qs.w);
        }
#pragma unroll
        for (int t2 = 0; t2 < 8; ++t2)
            acc[t2] = __builtin_amdgcn_mfma_f32_16x16x32_bf16(cw.s, bc[t2], acc[t2], 0, 0, 0);
        cw = nw;
#pragma unroll
        for (int t2 = 0; t2 < 8; ++t2) bc[t2] = bn[t2];
    }
    if (up) {
#pragma unroll
        for (int t2 = 0; t2 < 8; ++t2)
            red[wl][t2][l] = make_float4(acc[t2][0], acc[t2][1], acc[t2][2], acc[t2][3]);
    }
    __syncthreads();
    if (!up) {
        bf16* zp = z + (((size_t)(b * NTT + t0 + wl * 16 + lq * 4)) << 7) + lm;
#pragma unroll
        for (int t2 = 0; t2 < 8; ++t2) {
            float4 o = red[wl][t2][l];
#pragma unroll
            for (int r2 = 0; r2 < 4; ++r2)
                zp[(r2 << 7) + t2 * 16] = __float2bfloat16(acc[t2][r2] + ((const float*)&o)[r2]);
        }
    }
}

// ---------------------------------------------------------------------------
// edge gather: one wave per (b, node). No atomics.
// ---------------------------------------------------------------------------
__global__ __launch_bounds__(256) void edge_gather_k(const float* __restrict__ PQ,
                                                     const int* __restrict__ rowptr,
                                                     const int* __restrict__ csr_send,
                                                     const bf16* __restrict__ mb,
                                                     const bf16* __restrict__ g1,
                                                     const bf16* __restrict__ b1,
                                                     float* __restrict__ inbox) {
    int tid = threadIdx.x;
    int w = tid >> 6, l = tid & 63;
    int gw = blockIdx.x * 4 + w;
    int b = gw >> 10, n = gw & 1023;
    const float* pqb = PQ + ((size_t)b << 18);
    float p0 = pqb[(n << 8) + l];
    float p1 = pqb[(n << 8) + l + 64];
    float mb0 = b2f(mb[l]), mb1 = b2f(mb[l + 64]);
    float g0 = b2f(g1[l]), g1v = b2f(g1[l + 64]);
    float bb0 = b2f(b1[l]), bb1 = b2f(b1[l + 64]);
    int beg = rowptr[n], end = rowptr[n + 1];
    float a0 = 0.f, a1 = 0.f;
    for (int i = beg; i < end; ++i) {
        int s = csr_send[i];
        const float* q = pqb + (s << 8) + 128;
        float m0 = p0 + q[l] + mb0;
        float m1 = p1 + q[l + 64] + mb1;
        float s1 = m0 + m1, s2 = m0 * m0 + m1 * m1;
#pragma unroll
        for (int off = 32; off; off >>= 1) {
            s1 += __shfl_xor(s1, off);
            s2 += __shfl_xor(s2, off);
        }
        float mu = s1 * (1.f / 128.f);
        float var = s2 * (1.f / 128.f) - mu * mu;
        float rs = rsqrtf(var + 1e-5f);
        a0 += (m0 - mu) * rs * g0 + bb0;
        a1 += (m1 - mu) * rs * g1v + bb1;
    }
    float* inb = inbox + ((size_t)b << 17) + (n << 7);
    inb[l] = a0;
    inb[l + 64] = a1;
}

// ---------------------------------------------------------------------------
__global__ __launch_bounds__(256) void dec_final_k(const bf16* __restrict__ X,
                                                   const bf16* __restrict__ W2,
                                                   const bf16* __restrict__ b2v,
                                                   const int* __restrict__ flag,
                                                   void* __restrict__ out) {
    __shared__ float xs[8 * 128];
    int row0 = blockIdx.x * 8;
    int tid = threadIdx.x;
    for (int t = tid; t < 1024; t += 256) xs[t] = b2f(X[row0 * 128 + t]);
    __syncthreads();
    if (tid < 24) {
        int r = tid / 3, j = tid - r * 3;
        float acc = b2f(b2v[j]);
        for (int i = 0; i < 128; ++i) acc += xs[r * 128 + i] * b2f(W2[i * 3 + j]);
        int o = (row0 + r) * 3 + j;
        if (*flag) ((float*)out)[o] = acc;
        else       ((bf16*)out)[o] = __float2bfloat16(acc);
    }
}

// ---------------------------------------------------------------------------
extern "C" void kernel_launch(void* const* d_in, const int* in_sizes, int n_in,
                              void* d_out, int out_size, void* d_ws, size_t ws_size,
                              hipStream_t stream) {
    const int* senders = (const int*)d_in[30];
    const int* receivers = (const int*)d_in[31];

    char* base = (char*)d_ws;
    size_t off = 0;
    auto alloc = [&](size_t bytes) { char* p = base + off; off += (bytes + 255) & ~(size_t)255; return p; };

    int* flag = (int*)alloc(256);

    Tab tab;
    int pref = 0;
    for (int i = 0; i < 30; ++i) { tab.src[i] = d_in[i]; tab.pref[i] = pref; pref += in_sizes[i]; }
    tab.pref[30] = pref;
    bf16* arena = (bf16*)alloc((size_t)pref * 2);
    auto C = [&](int i) { return arena + tab.pref[i]; };

    float4* cstC4 = (float4*)alloc(32768 * sizeof(float4));
    float4* cstT4 = (float4*)alloc(32768 * sizeof(float4));
    float* lat0  = (float*)alloc(8192 * 128 * 4);
    float* lat1  = (float*)alloc(8192 * 128 * 4);
    float* inbox = (float*)alloc(8192 * 128 * 4);
    bf16* T1     = (bf16*)alloc((size_t)32768 * 128 * 2);
    bf16* T2     = (bf16*)alloc((size_t)32768 * 128 * 2);
    bf16* T3     = (bf16*)alloc((size_t)32768 * 128 * 2);
    bf16* embT   = (bf16*)alloc((size_t)8 * 128 * 4096 * 2);
    bf16* latT   = (bf16*)alloc((size_t)8 * 128 * 1024 * 2);
    bf16* xin32  = (bf16*)alloc((size_t)32768 * 32 * 2);
    bf16* xt32   = (bf16*)alloc((size_t)32768 * 32 * 2);
    float2* posf2 = (float2*)alloc(1024 * sizeof(float2));
    int* rowptr  = (int*)alloc(1025 * 4);
    int* csr_send = (int*)alloc(NEDGE * 4);
    bf16* WtEnc0 = (bf16*)alloc(128 * 32 * 2);
    bf16* WtQ0   = (bf16*)alloc(128 * 32 * 2);
    bf16* WtEnc1 = (bf16*)alloc(16384 * 2);
    bf16* WtEnc2 = (bf16*)alloc(16384 * 2);
    bf16* WtQ1   = (bf16*)alloc(16384 * 2);
    bf16* WtQ2   = (bf16*)alloc(16384 * 2);
    bf16* WtDec0 = (bf16*)alloc(32768 * 2);
    bf16* WtDec1 = (bf16*)alloc(16384 * 2);
    bf16* WtMsg  = (bf16*)alloc(32768 * 2);
    bf16* WtNode = (bf16*)alloc(32768 * 2);
    float* PQ    = (float*)T3;
    (void)ws_size; (void)n_in; (void)out_size;

    detect_k<<<1, 256, 0, stream>>>((const u16*)d_in[3], flag);
    ingest_k<<<(pref + 255) / 256, 256, 0, stream>>>(tab, flag, arena);

    const bf16 *xc = C(0), *yc = C(1), *xt = C(2), *pos = C(3);
    const bf16 *enc_W0 = C(4), *enc_b0 = C(5), *enc_W1 = C(6), *enc_b1 = C(7), *enc_W2 = C(8), *enc_b2 = C(9);
    const bf16 *qenc_W0 = C(10), *qenc_b0 = C(11), *qenc_W1 = C(12), *qenc_b1 = C(13), *qenc_W2 = C(14), *qenc_b2 = C(15);
    const bf16 *dec_W0 = C(16), *dec_b0 = C(17), *dec_W1 = C(18), *dec_b1 = C(19), *dec_W2 = C(20), *dec_b2 = C(21);
    const bf16 *msg_W = C(22), *msg_b = C(23), *ln1_g = C(24), *ln1_b = C(25);
    const bf16 *node_W = C(26), *node_b = C(27), *ln2_g = C(28), *ln2_b = C(29);

    // 11 transposes (zero-padding where dK > srcK): dst[n][k]
    TT tt;
    const bf16* s11[11] = { enc_W1, enc_W2, qenc_W1, qenc_W2, dec_W1, dec_W0, msg_W, msg_W + 16384, node_W, enc_W0, qenc_W0 };
    bf16* d11[11]       = { WtEnc1, WtEnc2, WtQ1,    WtQ2,    WtDec1, WtDec0, WtMsg, WtMsg + 16384, WtNode, WtEnc0, WtQ0   };
    int sk11[11] = { 128, 128, 128, 128, 128, 256, 128, 128, 256, 5, 2 };
    int dk11[11] = { 128, 128, 128, 128, 128, 256, 128, 128, 256, 32, 32 };
    int tp = 0;
    for (int i = 0; i < 11; ++i) {
        tt.src[i] = s11[i]; tt.dst[i] = d11[i]; tt.srcK[i] = sk11[i]; tt.dK[i] = dk11[i];
        tt.pref[i] = tp; tp += dk11[i] * 128;
    }
    tt.pref[11] = tp;

    prep_trans_k<<<128 + (tp + 255) / 256, 256, 0, stream>>>(tt, xc, yc, xt, pos, xin32, xt32, posf2);
    build_csr_k<<<1, 1024, 0, stream>>>(receivers, senders, rowptr, csr_send);

    // encoder: xin32 -> T1 -> T2 -> embT (transposed)
    mfma_gemm_k<1, 0, 1, 0, 1, bf16, bf16><<<512, 256, 0, stream>>>(xin32, nullptr, 32, WtEnc0, enc_b0, nullptr, nullptr, T1, 128, 0);
    mfma_gemm_k<4, 0, 1, 0, 1, bf16, bf16><<<512, 256, 0, stream>>>(T1, nullptr, 128, WtEnc1, enc_b1, nullptr, nullptr, T2, 128, 0);
    mfma_gemm_k<4, 0, 0, 1, 1, bf16, bf16><<<512, 256, 0, stream>>>(T2, nullptr, 128, WtEnc2, enc_b2, nullptr, nullptr, embT, 128, 12);

    stats2_k<<<16384, 256, 0, stream>>>(xc, xt, pos, cstC4, cstT4);

    P8 parts;
    parts.p[0] = lat1;
    parts.p[1] = inbox;
    parts.p[2] = (float*)T1;
    parts.p[3] = (float*)T1 + 1048576;
    parts.p[4] = (float*)T2;
    parts.p[5] = (float*)T2 + 1048576;
    parts.p[6] = (float*)T3;
    parts.p[7] = (float*)T3 + 1048576;
    lat_mfma_k<<<1024, 512, 0, stream>>>(embT, posf2, cstC4, parts);
    reduce8_k<<<1024, 256, 0, stream>>>(lat0, parts);

    // 4-step recurrence: multi-launch (stream-ordered launches are the cheap
    // grid barrier on MI355X — cooperative grid.sync measured ~135 µs/sync)
    float* cur = lat0;
    float* nxt = lat1;
    for (int s = 0; s < 4; ++s) {
        mfma_gemm_k<4, 0, 0, 0, 2, float, float><<<256, 256, 0, stream>>>(cur, nullptr, 128, WtMsg, nullptr, nullptr, nullptr, PQ, 256, 0);
        edge_gather_k<<<2048, 256, 0, stream>>>(PQ, rowptr, csr_send, msg_b, ln1_g, ln1_b, inbox);
        if (s < 3) {
            mfma_gemm_k<8, 1, 0, 0, 1, float, float><<<128, 256, 0, stream>>>(cur, inbox, 128, WtNode, node_b, ln2_g, ln2_b, nxt, 128, 0);
            float* tmp = cur; cur = nxt; nxt = tmp;
        } else {
            mfma_gemm_k<8, 1, 0, 1, 1, float, bf16><<<128, 256, 0, stream>>>(cur, inbox, 128, WtNode, node_b, ln2_g, ln2_b, latT, 128, 10);
        }
    }

    // query encoder: xt32 -> T2 -> T3 -> T1 (= q)
    mfma_gemm_k<1, 0, 1, 0, 1, bf16, bf16><<<512, 256, 0, stream>>>(xt32, nullptr, 32, WtQ0, qenc_b0, nullptr, nullptr, T2, 128, 0);
    mfma_gemm_k<4, 0, 1, 0, 1, bf16, bf16><<<512, 256, 0, stream>>>(T2, nullptr, 128, WtQ1, qenc_b1, nullptr, nullptr, T3, 128, 0);
    mfma_gemm_k<4, 0, 0, 0, 1, bf16, bf16><<<512, 256, 0, stream>>>(T3, nullptr, 128, WtQ2, qenc_b2, nullptr, nullptr, T1, 128, 0);

    // z -> T2 (bf16)
    z_mfma_k<<<512, 512, 0, stream>>>(latT, posf2, cstT4, T2);

    // decoder: (z=T2 | q=T1) -> T3 -> T2 -> out
    mfma_gemm_k<8, 0, 1, 0, 1, bf16, bf16><<<512, 256, 0, stream>>>(T2, T1, 128, WtDec0, dec_b0, nullptr, nullptr, T3, 128, 0);
    mfma_gemm_k<4, 0, 1, 0, 1, bf16, bf16><<<512, 256, 0, stream>>>(T3, nullptr, 128, WtDec1, dec_b1, nullptr, nullptr, T2, 128, 0);
    dec_final_k<<<4096, 256, 0, stream>>>(T2, dec_W2, dec_b2, flag, d_out);
}

// Round 15
// 564.262 us; speedup vs baseline: 3.5499x; 1.0531x over previous
//
#include <hip/hip_runtime.h>
#include <hip/hip_bf16.h>
#include <string.h>

#define BB 8
#define NC 4096
#define NTT 4096
#define NNODE 1024
#define NEDGE 16384

typedef __hip_bfloat16 bf16;
typedef unsigned short u16;
typedef __attribute__((ext_vector_type(8))) short short8;
typedef __attribute__((ext_vector_type(4))) float f32x4;

__device__ __forceinline__ float b2f(bf16 x) { return __bfloat162float(x); }
__device__ __forceinline__ float t2f(float v) { return v; }
__device__ __forceinline__ float t2f(bf16 v) { return __bfloat162float(v); }

template <typename T> struct Cvt;
template <> struct Cvt<float> { static __device__ __forceinline__ float to(float v) { return v; } };
template <> struct Cvt<bf16>  { static __device__ __forceinline__ bf16  to(float v) { return __float2bfloat16(v); } };

__device__ __forceinline__ unsigned short f2bs(float x) {
    unsigned u = __float_as_uint(x);
    return (unsigned short)((u + 0x7FFFu + ((u >> 16) & 1u)) >> 16);
}

__device__ __forceinline__ short8 ld_frag(const bf16* g) {
    union { uint4 u4; short8 s8; } cv;
    cv.u4 = *(const uint4*)g;
    return cv.s8;
}
__device__ __forceinline__ short8 ld_frag(const float* g) {
    float4 f0 = *(const float4*)g;
    float4 f1 = *(const float4*)(g + 4);
    short8 r;
    r[0] = (short)f2bs(f0.x); r[1] = (short)f2bs(f0.y);
    r[2] = (short)f2bs(f0.z); r[3] = (short)f2bs(f0.w);
    r[4] = (short)f2bs(f1.x); r[5] = (short)f2bs(f1.y);
    r[6] = (short)f2bs(f1.z); r[7] = (short)f2bs(f1.w);
    return r;
}

// ---------------------------------------------------------------------------
__global__ void detect_k(const u16* __restrict__ posu, int* __restrict__ flag) {
    __shared__ int cnt;
    if (threadIdx.x == 0) cnt = 0;
    __syncthreads();
    int wild = 0;
    for (int i = threadIdx.x; i < 1024; i += 256) {
        u16 u = posu[2 * i];
        int ex = (u >> 7) & 0xFF;
        if (ex == 0 || ex == 0xFF || ex > 137 || ex < 107) wild++;
    }
    atomicAdd(&cnt, wild);
    __syncthreads();
    if (threadIdx.x == 0) *flag = (cnt > 50) ? 1 : 0;
}

// ---------------------------------------------------------------------------
struct Tab { const void* src[30]; int pref[31]; };

__global__ __launch_bounds__(256) void ingest_k(Tab tab, const int* __restrict__ flag,
                                                bf16* __restrict__ dst) {
    int idx = blockIdx.x * 256 + threadIdx.x;
    if (idx >= tab.pref[30]) return;
    int t = 0;
    while (tab.pref[t + 1] <= idx) t++;
    int e = idx - tab.pref[t];
    float v;
    if (*flag) v = ((const float*)tab.src[t])[e];
    else       v = b2f(((const bf16*)tab.src[t])[e]);
    dst[idx] = __float2bfloat16(v);
}

// ---------------------------------------------------------------------------
// fused prep (blocks 0..127) + zero-padding weight transpose (blocks 128..)
// ---------------------------------------------------------------------------
struct TT { const bf16* src[11]; bf16* dst[11]; int srcK[11]; int dK[11]; int pref[12]; };

__global__ __launch_bounds__(256) void prep_trans_k(
    TT tt,
    const bf16* __restrict__ xc, const bf16* __restrict__ yc,
    const bf16* __restrict__ xt,
    const bf16* __restrict__ pos,
    bf16* __restrict__ xin32, bf16* __restrict__ xt32,
    float2* __restrict__ posf2) {
    if (blockIdx.x < 128) {
        int row = blockIdx.x * 256 + threadIdx.x;
        bf16 z = __float2bfloat16(0.f);
        bf16* xr = xin32 + row * 32;
        xr[0] = xc[row * 2 + 0];
        xr[1] = xc[row * 2 + 1];
        xr[2] = yc[row * 3 + 0];
        xr[3] = yc[row * 3 + 1];
        xr[4] = yc[row * 3 + 2];
#pragma unroll
        for (int k = 5; k < 32; ++k) xr[k] = z;
        bf16* tr = xt32 + row * 32;
        tr[0] = xt[row * 2 + 0];
        tr[1] = xt[row * 2 + 1];
#pragma unroll
        for (int k = 2; k < 32; ++k) tr[k] = z;
        if (row < NNODE) posf2[row] = make_float2(b2f(pos[2 * row]), b2f(pos[2 * row + 1]));
        return;
    }
    int idx = (blockIdx.x - 128) * 256 + threadIdx.x;
    if (idx >= tt.pref[11]) return;
    int t = 0;
    while (tt.pref[t + 1] <= idx) t++;
    int e = idx - tt.pref[t];
    int k = e >> 7, n = e & 127;
    bf16 v = (k < tt.srcK[t]) ? tt.src[t][k * 128 + n] : __float2bfloat16(0.f);
    tt.dst[t][n * tt.dK[t] + k] = v;
}

// ---------------------------------------------------------------------------
__global__ __launch_bounds__(1024) void build_csr_k(const int* __restrict__ recv,
                                                    const int* __restrict__ send,
                                                    int* __restrict__ rowptr,
                                                    int* __restrict__ csr_send) {
    __shared__ int cnt[1024];
    __shared__ int wt[16], wt2[16];
    __shared__ int cur[1024];
    int t = threadIdx.x;
    cnt[t] = 0;
    __syncthreads();
    for (int e = t; e < NEDGE; e += 1024) atomicAdd(&cnt[recv[e]], 1);
    __syncthreads();
    int v = cnt[t];
    int lane = t & 63, w = t >> 6;
#pragma unroll
    for (int off = 1; off < 64; off <<= 1) {
        int u = __shfl_up(v, off);
        if (lane >= off) v += u;
    }
    if (lane == 63) wt[w] = v;
    __syncthreads();
    if (t < 16) {
        int x = wt[t];
#pragma unroll
        for (int off = 1; off < 16; off <<= 1) {
            int u = __shfl_up(x, off);
            if (t >= off) x += u;
        }
        wt2[t] = x;
    }
    __syncthreads();
    int excl = v - cnt[t] + (w ? wt2[w - 1] : 0);
    rowptr[t] = excl;
    cur[t] = excl;
    if (t == 0) rowptr[1024] = NEDGE;
    __syncthreads();
    for (int e = t; e < NEDGE; e += 1024) {
        int pos = atomicAdd(&cur[recv[e]], 1);
        csr_send[pos] = send[e];
    }
}

// ---------------------------------------------------------------------------
// MFMA GEMM (steps loop). TRANS=1: bf16 transposed write. NSPLIT=2: col halves.
// A-frags read directly from global (no LDS round trip).
// ---------------------------------------------------------------------------
template <int KSTEPS, int EPI, int RELU, int TRANS, int NSPLIT, typename TIN, typename TOUT>
__global__ __launch_bounds__(256) void mfma_gemm_k(
    const TIN* __restrict__ Xa, const TIN* __restrict__ Xb, int ldx,
    const bf16* __restrict__ Wt,
    const bf16* __restrict__ bias,
    const bf16* __restrict__ lng, const bf16* __restrict__ lnb,
    TOUT* __restrict__ Y, int ldy, int tshift)
{
    constexpr int K = KSTEPS * 32;
    __shared__ __align__(16) short Bs[8][64][8];
    int tid = threadIdx.x;
    int w = tid >> 6, l = tid & 63;
    int lm = l & 15, lq = l >> 4;
    int blk = blockIdx.x;
    int half = 0;
    if (NSPLIT == 2) { half = blk & 1; blk >>= 1; }
    const bf16* Wtl = Wt + (size_t)half * 128 * K;
    int colbase = half * 128;
    size_t row0 = (size_t)blk * 64;

    f32x4 acc[8];
#pragma unroll
    for (int i = 0; i < 8; i++) acc[i] = (f32x4){0.f, 0.f, 0.f, 0.f};

    for (int s = 0; s < KSTEPS; ++s) {
        int k0 = s * 32;
        __syncthreads();
        short8 a;
        {
            const TIN* src = Xa; int kk = k0; int ld = ldx;
            if (Xb != nullptr && k0 >= 128) { src = Xb; kk = k0 - 128; ld = 128; }
            a = ld_frag(src + (row0 + w * 16 + lm) * (size_t)ld + kk + lq * 8);
        }
#pragma unroll
        for (int rr = 0; rr < 2; ++rr) {
            int idx = rr * 256 + tid;
            int nt = idx >> 6, ll = idx & 63;
            *(short8*)&Bs[nt][ll][0] =
                ld_frag(Wtl + (size_t)(nt * 16 + (ll & 15)) * K + k0 + (ll >> 4) * 8);
        }
        __syncthreads();
#pragma unroll
        for (int nt = 0; nt < 8; ++nt) {
            short8 b = *(const short8*)&Bs[nt][l][0];
            acc[nt] = __builtin_amdgcn_mfma_f32_16x16x32_bf16(a, b, acc[nt], 0, 0, 0);
        }
    }

    float v[8][4];
#pragma unroll
    for (int nt = 0; nt < 8; ++nt) {
        float bb = bias ? b2f(bias[colbase + nt * 16 + lm]) : 0.f;
#pragma unroll
        for (int r = 0; r < 4; ++r) v[nt][r] = acc[nt][r] + bb;
    }
    if constexpr (EPI == 1) {
#pragma unroll
        for (int r = 0; r < 4; ++r) {
            float s1 = 0.f, s2 = 0.f;
#pragma unroll
            for (int nt = 0; nt < 8; ++nt) { s1 += v[nt][r]; s2 += v[nt][r] * v[nt][r]; }
#pragma unroll
            for (int m = 1; m < 16; m <<= 1) { s1 += __shfl_xor(s1, m); s2 += __shfl_xor(s2, m); }
            float mu = s1 * (1.f / 128.f);
            float var = s2 * (1.f / 128.f) - mu * mu;
            float rs = rsqrtf(var + 1e-5f);
#pragma unroll
            for (int nt = 0; nt < 8; ++nt) {
                int n = nt * 16 + lm;
                v[nt][r] = (v[nt][r] - mu) * rs * b2f(lng[n]) + b2f(lnb[n]);
            }
        }
    }
    if constexpr (TRANS) {
        size_t grow = row0 + w * 16 + lq * 4;
        int bb2 = (int)(grow >> tshift);
        size_t rloc = grow & (((size_t)1 << tshift) - 1);
        bf16* YT = (bf16*)Y;
#pragma unroll
        for (int nt = 0; nt < 8; ++nt) {
            int col = colbase + nt * 16 + lm;
            ushort4 u;
            float x0 = v[nt][0], x1 = v[nt][1], x2 = v[nt][2], x3 = v[nt][3];
            if (RELU) { x0 = fmaxf(x0, 0.f); x1 = fmaxf(x1, 0.f); x2 = fmaxf(x2, 0.f); x3 = fmaxf(x3, 0.f); }
            u.x = f2bs(x0); u.y = f2bs(x1); u.z = f2bs(x2); u.w = f2bs(x3);
            *(ushort4*)(YT + (((size_t)bb2 * 128 + col) << tshift) + rloc) = u;
        }
    } else {
#pragma unroll
        for (int nt = 0; nt < 8; ++nt)
#pragma unroll
            for (int r = 0; r < 4; ++r) {
                float x = v[nt][r];
                if (RELU) x = fmaxf(x, 0.f);
                Y[(row0 + w * 16 + lq * 4 + r) * (size_t)ldy + colbase + nt * 16 + lm] = Cvt<TOUT>::to(x);
            }
    }
}

// ---------------------------------------------------------------------------
// FUSED per-row MLP (2 or 3 layers), one block = 64 rows, no grid sync.
// Layer 0: A from global (K = K0STEPS*32, optional Xb split at k>=128), relu.
// Layers 1..: K=128, A from LDS Act tile (C-layout -> A-layout transform).
// Last layer: RELU_LAST, TRANS or row-major write.
// ---------------------------------------------------------------------------
template <int K0STEPS, int LAYERS, int RELU_LAST, int TRANS, typename TIN, typename TOUT>
__global__ __launch_bounds__(256) void mlp_k(
    const TIN* __restrict__ Xa, const TIN* __restrict__ Xb, int ldx,
    const bf16* __restrict__ Wt0, const bf16* __restrict__ b0,
    const bf16* __restrict__ Wt1, const bf16* __restrict__ b1,
    const bf16* __restrict__ Wt2, const bf16* __restrict__ b2,
    TOUT* __restrict__ Y, int ldy, int tshift)
{
    constexpr int K0 = K0STEPS * 32;
    __shared__ __align__(16) short Bs[8][64][8];
    __shared__ __align__(16) short Act[64][136];   // 272 B row stride: 16B-aligned frags
    int tid = threadIdx.x;
    int w = tid >> 6, l = tid & 63;
    int lm = l & 15, lq = l >> 4;
    size_t row0 = (size_t)blockIdx.x * 64;

    f32x4 acc[8];
#pragma unroll
    for (int i = 0; i < 8; i++) acc[i] = (f32x4){0.f, 0.f, 0.f, 0.f};

    // ---- layer 0: A from global
    for (int s = 0; s < K0STEPS; ++s) {
        int k0 = s * 32;
        __syncthreads();
        short8 a;
        {
            const TIN* src = Xa; int kk = k0; int ld = ldx;
            if (Xb != nullptr && k0 >= 128) { src = Xb; kk = k0 - 128; ld = 128; }
            a = ld_frag(src + (row0 + w * 16 + lm) * (size_t)ld + kk + lq * 8);
        }
#pragma unroll
        for (int rr = 0; rr < 2; ++rr) {
            int idx = rr * 256 + tid;
            int nt = idx >> 6, ll = idx & 63;
            *(short8*)&Bs[nt][ll][0] =
                ld_frag(Wt0 + (size_t)(nt * 16 + (ll & 15)) * K0 + k0 + (ll >> 4) * 8);
        }
        __syncthreads();
#pragma unroll
        for (int nt = 0; nt < 8; ++nt) {
            short8 b = *(const short8*)&Bs[nt][l][0];
            acc[nt] = __builtin_amdgcn_mfma_f32_16x16x32_bf16(a, b, acc[nt], 0, 0, 0);
        }
    }
    // epilogue L0: relu -> Act (each wave writes its own 16-row slice)
#pragma unroll
    for (int nt = 0; nt < 8; ++nt) {
        float bb = b2f(b0[nt * 16 + lm]);
#pragma unroll
        for (int r = 0; r < 4; ++r) {
            float x = fmaxf(acc[nt][r] + bb, 0.f);
            Act[w * 16 + lq * 4 + r][nt * 16 + lm] = (short)f2bs(x);
        }
    }

    // ---- layers 1..LAYERS-1: A from Act (K=128)
    for (int L = 1; L < LAYERS; ++L) {
        const bf16* Wt = (L == 1) ? Wt1 : Wt2;
        const bf16* bias = (L == 1) ? b1 : b2;
        bool last = (L == LAYERS - 1);
#pragma unroll
        for (int i = 0; i < 8; i++) acc[i] = (f32x4){0.f, 0.f, 0.f, 0.f};
        for (int s = 0; s < 4; ++s) {
            int k0 = s * 32;
            __syncthreads();   // Act writes & prior Bs reads drained
#pragma unroll
            for (int rr = 0; rr < 2; ++rr) {
                int idx = rr * 256 + tid;
                int nt = idx >> 6, ll = idx & 63;
                *(short8*)&Bs[nt][ll][0] =
                    ld_frag(Wt + (size_t)(nt * 16 + (ll & 15)) * 128 + k0 + (ll >> 4) * 8);
            }
            __syncthreads();
            short8 a = *(const short8*)&Act[w * 16 + lm][k0 + lq * 8];
#pragma unroll
            for (int nt = 0; nt < 8; ++nt) {
                short8 b = *(const short8*)&Bs[nt][l][0];
                acc[nt] = __builtin_amdgcn_mfma_f32_16x16x32_bf16(a, b, acc[nt], 0, 0, 0);
            }
        }
        if (!last) {
            __syncthreads();   // all Act reads for this layer done before overwrite
#pragma unroll
            for (int nt = 0; nt < 8; ++nt) {
                float bb = b2f(bias[nt * 16 + lm]);
#pragma unroll
                for (int r = 0; r < 4; ++r) {
                    float x = fmaxf(acc[nt][r] + bb, 0.f);
                    Act[w * 16 + lq * 4 + r][nt * 16 + lm] = (short)f2bs(x);
                }
            }
        } else {
            float v[8][4];
#pragma unroll
            for (int nt = 0; nt < 8; ++nt) {
                float bb = b2f(bias[nt * 16 + lm]);
#pragma unroll
                for (int r = 0; r < 4; ++r) {
                    float x = acc[nt][r] + bb;
                    if (RELU_LAST) x = fmaxf(x, 0.f);
                    v[nt][r] = x;
                }
            }
            if constexpr (TRANS) {
                size_t grow = row0 + w * 16 + lq * 4;
                int bb2 = (int)(grow >> tshift);
                size_t rloc = grow & (((size_t)1 << tshift) - 1);
                bf16* YT = (bf16*)Y;
#pragma unroll
                for (int nt = 0; nt < 8; ++nt) {
                    int col = nt * 16 + lm;
                    ushort4 u;
                    u.x = f2bs(v[nt][0]); u.y = f2bs(v[nt][1]);
                    u.z = f2bs(v[nt][2]); u.w = f2bs(v[nt][3]);
                    *(ushort4*)(YT + (((size_t)bb2 * 128 + col) << tshift) + rloc) = u;
                }
            } else {
#pragma unroll
                for (int nt = 0; nt < 8; ++nt)
#pragma unroll
                    for (int r = 0; r < 4; ++r)
                        Y[(row0 + w * 16 + lq * 4 + r) * (size_t)ldy + nt * 16 + lm] =
                            Cvt<TOUT>::to(v[nt][r]);
            }
        }
    }
}

// ---------------------------------------------------------------------------
// fused softmax stats for xc (blocks <8192) and xt
// ---------------------------------------------------------------------------
__global__ __launch_bounds__(256) void stats2_k(const bf16* __restrict__ xcp,
                                                const bf16* __restrict__ xtp,
                                                const bf16* __restrict__ pos,
                                                float4* __restrict__ cstC4,
                                                float4* __restrict__ cstT4) {
    __shared__ float px[NNODE], py[NNODE];
    int tid = threadIdx.x;
    for (int t = tid; t < NNODE; t += 256) {
        px[t] = b2f(pos[2 * t]);
        py[t] = b2f(pos[2 * t + 1]);
    }
    __syncthreads();
    const bf16* xp = (blockIdx.x < 8192) ? xcp : xtp;
    float4* st4 = (blockIdx.x < 8192) ? cstC4 : cstT4;
    int pb = blockIdx.x & 8191;
    int w = tid >> 6, l = tid & 63;
    int p = pb * 4 + w;
    float x = b2f(xp[2 * p]), y = b2f(xp[2 * p + 1]);
    float vals[16];
    float m = -3.4e38f;
#pragma unroll
    for (int k = 0; k < 16; k++) {
        int n = k * 64 + l;
        float dx = x - px[n], dy = y - py[n];
        float v = -(dx * dx + dy * dy);
        vals[k] = v;
        m = fmaxf(m, v);
    }
#pragma unroll
    for (int off = 32; off; off >>= 1) m = fmaxf(m, __shfl_xor(m, off));
    float s = 0.f;
#pragma unroll
    for (int k = 0; k < 16; k++) s += __expf(vals[k] - m);
#pragma unroll
    for (int off = 32; off; off >>= 1) s += __shfl_xor(s, off);
    if (l == 0) st4[p] = make_float4(x, y, m, 1.f / s);
}

struct P8 { float* p[8]; };

// ---------------------------------------------------------------------------
// lat partials via MFMA, XCD-affine, K-split; conflict-free red layout.
// ---------------------------------------------------------------------------
__global__ __launch_bounds__(512, 4) void lat_mfma_k(const bf16* __restrict__ embT,
                                                     const float2* __restrict__ posf2,
                                                     const float4* __restrict__ cstC4,
                                                     P8 parts) {
    int i = blockIdx.x;
    int b = i & 7, r = i >> 3;
    int cs = r >> 4, nt = r & 15;
    int n0 = nt * 64;
    __shared__ __align__(16) float4 csh[512];
    __shared__ __align__(16) float4 red[4][8][64];
    int tid = threadIdx.x;
    int w = tid >> 6, l = tid & 63;
    int wl = w & 3, up = w >> 2;
    int lm = l & 15, lq = l >> 4;
    int node = n0 + wl * 16 + lm;
    float2 pn = posf2[node];
    const bf16* ebase = embT + ((size_t)b << 19) + cs * 512;
    const float4* cbase = cstC4 + b * NC + cs * 512;
    for (int t = tid; t < 512; t += 512) csh[t] = cbase[t];
    __syncthreads();

    f32x4 acc[8];
#pragma unroll
    for (int q = 0; q < 8; q++) acc[q] = (f32x4){0.f, 0.f, 0.f, 0.f};

    union AF { short8 s; u16 u[8]; };
    AF cw, nw;
    short8 bc[8], bn[8];
    int chb = up * 8;
    int c00 = chb * 32;
#pragma unroll
    for (int j = 0; j < 8; ++j) {
        float4 cc = csh[c00 + lq * 8 + j];
        float dx = cc.x - pn.x, dy = cc.y - pn.y;
        cw.u[j] = f2bs(__expf(-(dx * dx + dy * dy) - cc.z) * cc.w);
    }
#pragma unroll
    for (int t2 = 0; t2 < 8; ++t2)
        bc[t2] = ld_frag(ebase + ((size_t)(t2 * 16 + lm) << 12) + c00 + lq * 8);

    for (int ch = 0; ch < 8; ++ch) {
        int c0n = (chb + ((ch + 1) & 7)) * 32;
#pragma unroll
        for (int t2 = 0; t2 < 8; ++t2)
            bn[t2] = ld_frag(ebase + ((size_t)(t2 * 16 + lm) << 12) + c0n + lq * 8);
#pragma unroll
        for (int j = 0; j < 8; ++j) {
            float4 cc = csh[c0n + lq * 8 + j];
            float dx = cc.x - pn.x, dy = cc.y - pn.y;
            nw.u[j] = f2bs(__expf(-(dx * dx + dy * dy) - cc.z) * cc.w);
        }
#pragma unroll
        for (int t2 = 0; t2 < 8; ++t2)
            acc[t2] = __builtin_amdgcn_mfma_f32_16x16x32_bf16(cw.s, bc[t2], acc[t2], 0, 0, 0);
        cw = nw;
#pragma unroll
        for (int t2 = 0; t2 < 8; ++t2) bc[t2] = bn[t2];
    }
    if (up) {
#pragma unroll
        for (int t2 = 0; t2 < 8; ++t2)
            red[wl][t2][l] = make_float4(acc[t2][0], acc[t2][1], acc[t2][2], acc[t2][3]);
    }
    __syncthreads();
    if (!up) {
        float* part = parts.p[cs] + (((size_t)(b * NNODE + n0 + wl * 16 + lq * 4)) << 7) + lm;
#pragma unroll
        for (int t2 = 0; t2 < 8; ++t2) {
            float4 o = red[wl][t2][l];
#pragma unroll
            for (int r2 = 0; r2 < 4; ++r2)
                part[(r2 << 7) + t2 * 16] = acc[t2][r2] + ((const float*)&o)[r2];
        }
    }
}

__global__ __launch_bounds__(256) void reduce8_k(float* __restrict__ dst, P8 parts) {
    int i = blockIdx.x * 256 + threadIdx.x;
    float4 s = ((const float4*)parts.p[0])[i];
#pragma unroll
    for (int k = 1; k < 8; ++k) {
        float4 v = ((const float4*)parts.p[k])[i];
        s.x += v.x; s.y += v.y; s.z += v.z; s.w += v.w;
    }
    ((float4*)dst)[i] = s;
}

// ---------------------------------------------------------------------------
// z via MFMA, XCD-affine, K-split; conflict-free red layout.
// ---------------------------------------------------------------------------
__global__ __launch_bounds__(512, 4) void z_mfma_k(const bf16* __restrict__ latT,
                                                   const float2* __restrict__ posf2,
                                                   const float4* __restrict__ cstT4,
                                                   bf16* __restrict__ z) {
    int i = blockIdx.x;
    int b = i & 7, tt = i >> 3;
    int t0 = tt * 64;
    __shared__ __align__(8) float2 posh[1024];
    __shared__ __align__(16) float4 red[4][8][64];
    int tid = threadIdx.x;
    int w = tid >> 6, l = tid & 63;
    int wl = w & 3, up = w >> 2;
    int lm = l & 15, lq = l >> 4;
    int t = t0 + wl * 16 + lm;
    float4 qs = cstT4[b * NTT + t];
    const bf16* lbase = latT + ((size_t)b << 17);
    for (int k = tid; k < 1024; k += 512) posh[k] = posf2[k];
    __syncthreads();

    f32x4 acc[8];
#pragma unroll
    for (int q = 0; q < 8; q++) acc[q] = (f32x4){0.f, 0.f, 0.f, 0.f};

    union AF { short8 s; u16 u[8]; };
    AF cw, nw;
    short8 bc[8], bn[8];
    int chb = up * 16;
    int nb0 = chb * 32;
#pragma unroll
    for (int j = 0; j < 8; ++j) {
        float2 pn = posh[nb0 + lq * 8 + j];
        float dx = qs.x - pn.x, dy = qs.y - pn.y;
        cw.u[j] = f2bs(__expf(-(dx * dx + dy * dy) - qs.z) * qs.w);
    }
#pragma unroll
    for (int t2 = 0; t2 < 8; ++t2)
        bc[t2] = ld_frag(lbase + ((size_t)(t2 * 16 + lm) << 10) + nb0 + lq * 8);

    for (int ch = 0; ch < 16; ++ch) {
        int nbn = (chb + ((ch + 1) & 15)) * 32;
#pragma unroll
        for (int t2 = 0; t2 < 8; ++t2)
            bn[t2] = ld_frag(lbase + ((size_t)(t2 * 16 + lm) << 10) + nbn + lq * 8);
#pragma unroll
        for (int j = 0; j < 8; ++j) {
            float2 pn = posh[nbn + lq * 8 + j];
            float dx = qs.x - pn.x, dy = qs.y - pn.y;
            nw.u[j] = f2bs(__expf(-(dx * dx + dy * dy) - qs.z) * qs.w);
        }
#pragma unroll
        for (int t2 = 0; t2 < 8; ++t2)
            acc[t2] = __builtin_amdgcn_mfma_f32_16x16x32_bf16(cw.s, bc[t2], acc[t2], 0, 0, 0);
        cw = nw;
#pragma unroll
        for (int t2 = 0; t2 < 8; ++t2) bc[t2] = bn[t2];
    }
    if (up) {
#pragma unroll
        for (int t2 = 0; t2 < 8; ++t2)
            red[wl][t2][l] = make_float4(acc[t2][0], acc[t2][1], acc[t2][2], acc[t2][3]);
    }
    __syncthreads();
    if (!up) {
        bf16* zp = z + (((size_t)(b * NTT + t0 + wl * 16 + lq * 4)) << 7) + lm;
#pragma unroll
        for (int t2 = 0; t2 < 8; ++t2) {
            float4 o = red[wl][t2][l];
#pragma unroll
            for (int r2 = 0; r2 < 4; ++r2)
                zp[(r2 << 7) + t2 * 16] = __float2bfloat16(acc[t2][r2] + ((const float*)&o)[r2]);
        }
    }
}

// ---------------------------------------------------------------------------
// edge gather: one wave per (b, node). No atomics.
// ---------------------------------------------------------------------------
__global__ __launch_bounds__(256) void edge_gather_k(const float* __restrict__ PQ,
                                                     const int* __restrict__ rowptr,
                                                     const int* __restrict__ csr_send,
                                                     const bf16* __restrict__ mb,
                                                     const bf16* __restrict__ g1,
                                                     const bf16* __restrict__ b1,
                                                     float* __restrict__ inbox) {
    int tid = threadIdx.x;
    int w = tid >> 6, l = tid & 63;
    int gw = blockIdx.x * 4 + w;
    int b = gw >> 10, n = gw & 1023;
    const float* pqb = PQ + ((size_t)b << 18);
    float p0 = pqb[(n << 8) + l];
    float p1 = pqb[(n << 8) + l + 64];
    float mb0 = b2f(mb[l]), mb1 = b2f(mb[l + 64]);
    float g0 = b2f(g1[l]), g1v = b2f(g1[l + 64]);
    float bb0 = b2f(b1[l]), bb1 = b2f(b1[l + 64]);
    int beg = rowptr[n], end = rowptr[n + 1];
    float a0 = 0.f, a1 = 0.f;
    for (int i = beg; i < end; ++i) {
        int s = csr_send[i];
        const float* q = pqb + (s << 8) + 128;
        float m0 = p0 + q[l] + mb0;
        float m1 = p1 + q[l + 64] + mb1;
        float s1 = m0 + m1, s2 = m0 * m0 + m1 * m1;
#pragma unroll
        for (int off = 32; off; off >>= 1) {
            s1 += __shfl_xor(s1, off);
            s2 += __shfl_xor(s2, off);
        }
        float mu = s1 * (1.f / 128.f);
        float var = s2 * (1.f / 128.f) - mu * mu;
        float rs = rsqrtf(var + 1e-5f);
        a0 += (m0 - mu) * rs * g0 + bb0;
        a1 += (m1 - mu) * rs * g1v + bb1;
    }
    float* inb = inbox + ((size_t)b << 17) + (n << 7);
    inb[l] = a0;
    inb[l + 64] = a1;
}

// ---------------------------------------------------------------------------
__global__ __launch_bounds__(256) void dec_final_k(const bf16* __restrict__ X,
                                                   const bf16* __restrict__ W2,
                                                   const bf16* __restrict__ b2v,
                                                   const int* __restrict__ flag,
                                                   void* __restrict__ out) {
    __shared__ float xs[8 * 128];
    int row0 = blockIdx.x * 8;
    int tid = threadIdx.x;
    for (int t = tid; t < 1024; t += 256) xs[t] = b2f(X[row0 * 128 + t]);
    __syncthreads();
    if (tid < 24) {
        int r = tid / 3, j = tid - r * 3;
        float acc = b2f(b2v[j]);
        for (int i = 0; i < 128; ++i) acc += xs[r * 128 + i] * b2f(W2[i * 3 + j]);
        int o = (row0 + r) * 3 + j;
        if (*flag) ((float*)out)[o] = acc;
        else       ((bf16*)out)[o] = __float2bfloat16(acc);
    }
}

// ---------------------------------------------------------------------------
extern "C" void kernel_launch(void* const* d_in, const int* in_sizes, int n_in,
                              void* d_out, int out_size, void* d_ws, size_t ws_size,
                              hipStream_t stream) {
    const int* senders = (const int*)d_in[30];
    const int* receivers = (const int*)d_in[31];

    char* base = (char*)d_ws;
    size_t off = 0;
    auto alloc = [&](size_t bytes) { char* p = base + off; off += (bytes + 255) & ~(size_t)255; return p; };

    int* flag = (int*)alloc(256);

    Tab tab;
    int pref = 0;
    for (int i = 0; i < 30; ++i) { tab.src[i] = d_in[i]; tab.pref[i] = pref; pref += in_sizes[i]; }
    tab.pref[30] = pref;
    bf16* arena = (bf16*)alloc((size_t)pref * 2);
    auto C = [&](int i) { return arena + tab.pref[i]; };

    float4* cstC4 = (float4*)alloc(32768 * sizeof(float4));
    float4* cstT4 = (float4*)alloc(32768 * sizeof(float4));
    float* lat0  = (float*)alloc(8192 * 128 * 4);
    float* lat1  = (float*)alloc(8192 * 128 * 4);
    float* inbox = (float*)alloc(8192 * 128 * 4);
    bf16* T1     = (bf16*)alloc((size_t)32768 * 128 * 2);
    bf16* T2     = (bf16*)alloc((size_t)32768 * 128 * 2);
    bf16* T3     = (bf16*)alloc((size_t)32768 * 128 * 2);
    bf16* embT   = (bf16*)alloc((size_t)8 * 128 * 4096 * 2);
    bf16* latT   = (bf16*)alloc((size_t)8 * 128 * 1024 * 2);
    bf16* xin32  = (bf16*)alloc((size_t)32768 * 32 * 2);
    bf16* xt32   = (bf16*)alloc((size_t)32768 * 32 * 2);
    float2* posf2 = (float2*)alloc(1024 * sizeof(float2));
    int* rowptr  = (int*)alloc(1025 * 4);
    int* csr_send = (int*)alloc(NEDGE * 4);
    bf16* WtEnc0 = (bf16*)alloc(128 * 32 * 2);
    bf16* WtQ0   = (bf16*)alloc(128 * 32 * 2);
    bf16* WtEnc1 = (bf16*)alloc(16384 * 2);
    bf16* WtEnc2 = (bf16*)alloc(16384 * 2);
    bf16* WtQ1   = (bf16*)alloc(16384 * 2);
    bf16* WtQ2   = (bf16*)alloc(16384 * 2);
    bf16* WtDec0 = (bf16*)alloc(32768 * 2);
    bf16* WtDec1 = (bf16*)alloc(16384 * 2);
    bf16* WtMsg  = (bf16*)alloc(32768 * 2);
    bf16* WtNode = (bf16*)alloc(32768 * 2);
    float* PQ    = (float*)T3;
    (void)ws_size; (void)n_in; (void)out_size;

    detect_k<<<1, 256, 0, stream>>>((const u16*)d_in[3], flag);
    ingest_k<<<(pref + 255) / 256, 256, 0, stream>>>(tab, flag, arena);

    const bf16 *xc = C(0), *yc = C(1), *xt = C(2), *pos = C(3);
    const bf16 *enc_W0 = C(4), *enc_b0 = C(5), *enc_W1 = C(6), *enc_b1 = C(7), *enc_W2 = C(8), *enc_b2 = C(9);
    const bf16 *qenc_W0 = C(10), *qenc_b0 = C(11), *qenc_W1 = C(12), *qenc_b1 = C(13), *qenc_W2 = C(14), *qenc_b2 = C(15);
    const bf16 *dec_W0 = C(16), *dec_b0 = C(17), *dec_W1 = C(18), *dec_b1 = C(19), *dec_W2 = C(20), *dec_b2 = C(21);
    const bf16 *msg_W = C(22), *msg_b = C(23), *ln1_g = C(24), *ln1_b = C(25);
    const bf16 *node_W = C(26), *node_b = C(27), *ln2_g = C(28), *ln2_b = C(29);

    TT tt;
    const bf16* s11[11] = { enc_W1, enc_W2, qenc_W1, qenc_W2, dec_W1, dec_W0, msg_W, msg_W + 16384, node_W, enc_W0, qenc_W0 };
    bf16* d11[11]       = { WtEnc1, WtEnc2, WtQ1,    WtQ2,    WtDec1, WtDec0, WtMsg, WtMsg + 16384, WtNode, WtEnc0, WtQ0   };
    int sk11[11] = { 128, 128, 128, 128, 128, 256, 128, 128, 256, 5, 2 };
    int dk11[11] = { 128, 128, 128, 128, 128, 256, 128, 128, 256, 32, 32 };
    int tp = 0;
    for (int i = 0; i < 11; ++i) {
        tt.src[i] = s11[i]; tt.dst[i] = d11[i]; tt.srcK[i] = sk11[i]; tt.dK[i] = dk11[i];
        tt.pref[i] = tp; tp += dk11[i] * 128;
    }
    tt.pref[11] = tp;

    prep_trans_k<<<128 + (tp + 255) / 256, 256, 0, stream>>>(tt, xc, yc, xt, pos, xin32, xt32, posf2);
    build_csr_k<<<1, 1024, 0, stream>>>(receivers, senders, rowptr, csr_send);

    // encoder (fused 3-layer MLP): xin32 -> embT (transposed)
    mlp_k<1, 3, 0, 1, bf16, bf16><<<512, 256, 0, stream>>>(
        xin32, nullptr, 32, WtEnc0, enc_b0, WtEnc1, enc_b1, WtEnc2, enc_b2, embT, 128, 12);

    stats2_k<<<16384, 256, 0, stream>>>(xc, xt, pos, cstC4, cstT4);

    P8 parts;
    parts.p[0] = lat1;
    parts.p[1] = inbox;
    parts.p[2] = (float*)T1;
    parts.p[3] = (float*)T1 + 1048576;
    parts.p[4] = (float*)T2;
    parts.p[5] = (float*)T2 + 1048576;
    parts.p[6] = (float*)T3;
    parts.p[7] = (float*)T3 + 1048576;
    lat_mfma_k<<<1024, 512, 0, stream>>>(embT, posf2, cstC4, parts);
    reduce8_k<<<1024, 256, 0, stream>>>(lat0, parts);

    // 4-step recurrence: multi-launch (stream-ordered launches are the cheap
    // grid barrier on MI355X — cooperative grid.sync measured ~135 µs/sync)
    float* cur = lat0;
    float* nxt = lat1;
    for (int s = 0; s < 4; ++s) {
        mfma_gemm_k<4, 0, 0, 0, 2, float, float><<<256, 256, 0, stream>>>(cur, nullptr, 128, WtMsg, nullptr, nullptr, nullptr, PQ, 256, 0);
        edge_gather_k<<<2048, 256, 0, stream>>>(PQ, rowptr, csr_send, msg_b, ln1_g, ln1_b, inbox);
        if (s < 3) {
            mfma_gemm_k<8, 1, 0, 0, 1, float, float><<<128, 256, 0, stream>>>(cur, inbox, 128, WtNode, node_b, ln2_g, ln2_b, nxt, 128, 0);
            float* tmp = cur; cur = nxt; nxt = tmp;
        } else {
            mfma_gemm_k<8, 1, 0, 1, 1, float, bf16><<<128, 256, 0, stream>>>(cur, inbox, 128, WtNode, node_b, ln2_g, ln2_b, latT, 128, 10);
        }
    }

    // query encoder (fused 3-layer MLP): xt32 -> T1 (= q)
    mlp_k<1, 3, 0, 0, bf16, bf16><<<512, 256, 0, stream>>>(
        xt32, nullptr, 32, WtQ0, qenc_b0, WtQ1, qenc_b1, WtQ2, qenc_b2, T1, 128, 0);

    // z -> T2 (bf16)
    z_mfma_k<<<512, 512, 0, stream>>>(latT, posf2, cstT4, T2);

    // decoder (fused 2-layer MLP): (z=T2 | q=T1) -> T3, then final 128->3
    mlp_k<8, 2, 1, 0, bf16, bf16><<<512, 256, 0, stream>>>(
        T2, T1, 128, WtDec0, dec_b0, WtDec1, dec_b1, nullptr, nullptr, T3, 128, 0);
    dec_final_k<<<4096, 256, 0, stream>>>(T3, dec_W2, dec_b2, flag, d_out);
}

// Round 17
// 540.458 us; speedup vs baseline: 3.7063x; 1.0440x over previous
//
#include <hip/hip_runtime.h>
#include <hip/hip_bf16.h>
#include <string.h>

#define BB 8
#define NC 4096
#define NTT 4096
#define NNODE 1024
#define NEDGE 16384

typedef __hip_bfloat16 bf16;
typedef unsigned short u16;
typedef __attribute__((ext_vector_type(8))) short short8;
typedef __attribute__((ext_vector_type(4))) float f32x4;

__device__ __forceinline__ float b2f(bf16 x) { return __bfloat162float(x); }
__device__ __forceinline__ float t2f(float v) { return v; }
__device__ __forceinline__ float t2f(bf16 v) { return __bfloat162float(v); }
__device__ __forceinline__ float bs2f(short s) { return __uint_as_float(((unsigned)(unsigned short)s) << 16); }

template <typename T> struct Cvt;
template <> struct Cvt<float> { static __device__ __forceinline__ float to(float v) { return v; } };
template <> struct Cvt<bf16>  { static __device__ __forceinline__ bf16  to(float v) { return __float2bfloat16(v); } };

__device__ __forceinline__ unsigned short f2bs(float x) {
    unsigned u = __float_as_uint(x);
    return (unsigned short)((u + 0x7FFFu + ((u >> 16) & 1u)) >> 16);
}

__device__ __forceinline__ short8 ld_frag(const bf16* g) {
    union { uint4 u4; short8 s8; } cv;
    cv.u4 = *(const uint4*)g;
    return cv.s8;
}
__device__ __forceinline__ short8 ld_frag(const float* g) {
    float4 f0 = *(const float4*)g;
    float4 f1 = *(const float4*)(g + 4);
    short8 r;
    r[0] = (short)f2bs(f0.x); r[1] = (short)f2bs(f0.y);
    r[2] = (short)f2bs(f0.z); r[3] = (short)f2bs(f0.w);
    r[4] = (short)f2bs(f1.x); r[5] = (short)f2bs(f1.y);
    r[6] = (short)f2bs(f1.z); r[7] = (short)f2bs(f1.w);
    return r;
}

// ---------------------------------------------------------------------------
__global__ void detect_k(const u16* __restrict__ posu, int* __restrict__ flag) {
    __shared__ int cnt;
    if (threadIdx.x == 0) cnt = 0;
    __syncthreads();
    int wild = 0;
    for (int i = threadIdx.x; i < 1024; i += 256) {
        u16 u = posu[2 * i];
        int ex = (u >> 7) & 0xFF;
        if (ex == 0 || ex == 0xFF || ex > 137 || ex < 107) wild++;
    }
    atomicAdd(&cnt, wild);
    __syncthreads();
    if (threadIdx.x == 0) *flag = (cnt > 50) ? 1 : 0;
}

// ---------------------------------------------------------------------------
struct Tab { const void* src[30]; int pref[31]; };

__global__ __launch_bounds__(256) void ingest_k(Tab tab, const int* __restrict__ flag,
                                                bf16* __restrict__ dst) {
    int idx = blockIdx.x * 256 + threadIdx.x;
    if (idx >= tab.pref[30]) return;
    int t = 0;
    while (tab.pref[t + 1] <= idx) t++;
    int e = idx - tab.pref[t];
    float v;
    if (*flag) v = ((const float*)tab.src[t])[e];
    else       v = b2f(((const bf16*)tab.src[t])[e]);
    dst[idx] = __float2bfloat16(v);
}

// ---------------------------------------------------------------------------
// fused prep (blocks 0..127) + zero-padding weight transpose (blocks 128..)
// ---------------------------------------------------------------------------
struct TT { const bf16* src[11]; bf16* dst[11]; int srcK[11]; int dK[11]; int pref[12]; };

__global__ __launch_bounds__(256) void prep_trans_k(
    TT tt,
    const bf16* __restrict__ xc, const bf16* __restrict__ yc,
    const bf16* __restrict__ xt,
    const bf16* __restrict__ pos,
    bf16* __restrict__ xin32, bf16* __restrict__ xt32,
    float2* __restrict__ posf2) {
    if (blockIdx.x < 128) {
        int row = blockIdx.x * 256 + threadIdx.x;
        bf16 z = __float2bfloat16(0.f);
        bf16* xr = xin32 + row * 32;
        xr[0] = xc[row * 2 + 0];
        xr[1] = xc[row * 2 + 1];
        xr[2] = yc[row * 3 + 0];
        xr[3] = yc[row * 3 + 1];
        xr[4] = yc[row * 3 + 2];
#pragma unroll
        for (int k = 5; k < 32; ++k) xr[k] = z;
        bf16* tr = xt32 + row * 32;
        tr[0] = xt[row * 2 + 0];
        tr[1] = xt[row * 2 + 1];
#pragma unroll
        for (int k = 2; k < 32; ++k) tr[k] = z;
        if (row < NNODE) posf2[row] = make_float2(b2f(pos[2 * row]), b2f(pos[2 * row + 1]));
        return;
    }
    int idx = (blockIdx.x - 128) * 256 + threadIdx.x;
    if (idx >= tt.pref[11]) return;
    int t = 0;
    while (tt.pref[t + 1] <= idx) t++;
    int e = idx - tt.pref[t];
    int k = e >> 7, n = e & 127;
    bf16 v = (k < tt.srcK[t]) ? tt.src[t][k * 128 + n] : __float2bfloat16(0.f);
    tt.dst[t][n * tt.dK[t] + k] = v;
}

// ---------------------------------------------------------------------------
__global__ __launch_bounds__(1024) void build_csr_k(const int* __restrict__ recv,
                                                    const int* __restrict__ send,
                                                    int* __restrict__ rowptr,
                                                    int* __restrict__ csr_send) {
    __shared__ int cnt[1024];
    __shared__ int wt[16], wt2[16];
    __shared__ int cur[1024];
    int t = threadIdx.x;
    cnt[t] = 0;
    __syncthreads();
    for (int e = t; e < NEDGE; e += 1024) atomicAdd(&cnt[recv[e]], 1);
    __syncthreads();
    int v = cnt[t];
    int lane = t & 63, w = t >> 6;
#pragma unroll
    for (int off = 1; off < 64; off <<= 1) {
        int u = __shfl_up(v, off);
        if (lane >= off) v += u;
    }
    if (lane == 63) wt[w] = v;
    __syncthreads();
    if (t < 16) {
        int x = wt[t];
#pragma unroll
        for (int off = 1; off < 16; off <<= 1) {
            int u = __shfl_up(x, off);
            if (t >= off) x += u;
        }
        wt2[t] = x;
    }
    __syncthreads();
    int excl = v - cnt[t] + (w ? wt2[w - 1] : 0);
    rowptr[t] = excl;
    cur[t] = excl;
    if (t == 0) rowptr[1024] = NEDGE;
    __syncthreads();
    for (int e = t; e < NEDGE; e += 1024) {
        int pos = atomicAdd(&cur[recv[e]], 1);
        csr_send[pos] = send[e];
    }
}

// ---------------------------------------------------------------------------
// MFMA GEMM (steps: s=0 msg + s=3 node). A-frags direct from global.
// ---------------------------------------------------------------------------
template <int KSTEPS, int EPI, int RELU, int TRANS, int NSPLIT, typename TIN, typename TOUT>
__global__ __launch_bounds__(256) void mfma_gemm_k(
    const TIN* __restrict__ Xa, const TIN* __restrict__ Xb, int ldx,
    const bf16* __restrict__ Wt,
    const bf16* __restrict__ bias,
    const bf16* __restrict__ lng, const bf16* __restrict__ lnb,
    TOUT* __restrict__ Y, int ldy, int tshift)
{
    constexpr int K = KSTEPS * 32;
    __shared__ __align__(16) short Bs[8][64][8];
    int tid = threadIdx.x;
    int w = tid >> 6, l = tid & 63;
    int lm = l & 15, lq = l >> 4;
    int blk = blockIdx.x;
    int half = 0;
    if (NSPLIT == 2) { half = blk & 1; blk >>= 1; }
    const bf16* Wtl = Wt + (size_t)half * 128 * K;
    int colbase = half * 128;
    size_t row0 = (size_t)blk * 64;

    f32x4 acc[8];
#pragma unroll
    for (int i = 0; i < 8; i++) acc[i] = (f32x4){0.f, 0.f, 0.f, 0.f};

    for (int s = 0; s < KSTEPS; ++s) {
        int k0 = s * 32;
        __syncthreads();
        short8 a;
        {
            const TIN* src = Xa; int kk = k0; int ld = ldx;
            if (Xb != nullptr && k0 >= 128) { src = Xb; kk = k0 - 128; ld = 128; }
            a = ld_frag(src + (row0 + w * 16 + lm) * (size_t)ld + kk + lq * 8);
        }
#pragma unroll
        for (int rr = 0; rr < 2; ++rr) {
            int idx = rr * 256 + tid;
            int nt = idx >> 6, ll = idx & 63;
            *(short8*)&Bs[nt][ll][0] =
                ld_frag(Wtl + (size_t)(nt * 16 + (ll & 15)) * K + k0 + (ll >> 4) * 8);
        }
        __syncthreads();
#pragma unroll
        for (int nt = 0; nt < 8; ++nt) {
            short8 b = *(const short8*)&Bs[nt][l][0];
            acc[nt] = __builtin_amdgcn_mfma_f32_16x16x32_bf16(a, b, acc[nt], 0, 0, 0);
        }
    }

    float v[8][4];
#pragma unroll
    for (int nt = 0; nt < 8; ++nt) {
        float bb = bias ? b2f(bias[colbase + nt * 16 + lm]) : 0.f;
#pragma unroll
        for (int r = 0; r < 4; ++r) v[nt][r] = acc[nt][r] + bb;
    }
    if constexpr (EPI == 1) {
#pragma unroll
        for (int r = 0; r < 4; ++r) {
            float s1 = 0.f, s2 = 0.f;
#pragma unroll
            for (int nt = 0; nt < 8; ++nt) { s1 += v[nt][r]; s2 += v[nt][r] * v[nt][r]; }
#pragma unroll
            for (int m = 1; m < 16; m <<= 1) { s1 += __shfl_xor(s1, m); s2 += __shfl_xor(s2, m); }
            float mu = s1 * (1.f / 128.f);
            float var = s2 * (1.f / 128.f) - mu * mu;
            float rs = rsqrtf(var + 1e-5f);
#pragma unroll
            for (int nt = 0; nt < 8; ++nt) {
                int n = nt * 16 + lm;
                v[nt][r] = (v[nt][r] - mu) * rs * b2f(lng[n]) + b2f(lnb[n]);
            }
        }
    }
    if constexpr (TRANS) {
        size_t grow = row0 + w * 16 + lq * 4;
        int bb2 = (int)(grow >> tshift);
        size_t rloc = grow & (((size_t)1 << tshift) - 1);
        bf16* YT = (bf16*)Y;
#pragma unroll
        for (int nt = 0; nt < 8; ++nt) {
            int col = colbase + nt * 16 + lm;
            ushort4 u;
            float x0 = v[nt][0], x1 = v[nt][1], x2 = v[nt][2], x3 = v[nt][3];
            if (RELU) { x0 = fmaxf(x0, 0.f); x1 = fmaxf(x1, 0.f); x2 = fmaxf(x2, 0.f); x3 = fmaxf(x3, 0.f); }
            u.x = f2bs(x0); u.y = f2bs(x1); u.z = f2bs(x2); u.w = f2bs(x3);
            *(ushort4*)(YT + (((size_t)bb2 * 128 + col) << tshift) + rloc) = u;
        }
    } else {
#pragma unroll
        for (int nt = 0; nt < 8; ++nt)
#pragma unroll
            for (int r = 0; r < 4; ++r) {
                float x = v[nt][r];
                if (RELU) x = fmaxf(x, 0.f);
                Y[(row0 + w * 16 + lq * 4 + r) * (size_t)ldy + colbase + nt * 16 + lm] = Cvt<TOUT>::to(x);
            }
    }
}

// ---------------------------------------------------------------------------
// FUSED node-GEMM+LN then msg-GEMM for the NEXT step (row-local chain).
// ---------------------------------------------------------------------------
__global__ __launch_bounds__(256) void node_msg_k(
    const float* __restrict__ cur, const float* __restrict__ inbox,
    const bf16* __restrict__ WtNode, const bf16* __restrict__ node_b,
    const bf16* __restrict__ ln2_g, const bf16* __restrict__ ln2_b,
    const bf16* __restrict__ WtMsg,
    float* __restrict__ nxt, float* __restrict__ PQ)
{
    __shared__ __align__(16) short Bs[8][64][8];
    __shared__ __align__(16) short Act[64][136];
    int tid = threadIdx.x;
    int w = tid >> 6, l = tid & 63;
    int lm = l & 15, lq = l >> 4;
    size_t row0 = (size_t)blockIdx.x * 64;

    f32x4 acc[8];
#pragma unroll
    for (int i = 0; i < 8; i++) acc[i] = (f32x4){0.f, 0.f, 0.f, 0.f};

    // node GEMM K=256 (cur | inbox)
    for (int s = 0; s < 8; ++s) {
        int k0 = s * 32;
        __syncthreads();
        const float* src = (k0 < 128) ? cur : inbox;
        int kk = (k0 < 128) ? k0 : k0 - 128;
        short8 a = ld_frag(src + (row0 + w * 16 + lm) * 128 + kk + lq * 8);
#pragma unroll
        for (int rr = 0; rr < 2; ++rr) {
            int idx = rr * 256 + tid;
            int nt = idx >> 6, ll = idx & 63;
            *(short8*)&Bs[nt][ll][0] =
                ld_frag(WtNode + (size_t)(nt * 16 + (ll & 15)) * 256 + k0 + (ll >> 4) * 8);
        }
        __syncthreads();
#pragma unroll
        for (int nt = 0; nt < 8; ++nt) {
            short8 b = *(const short8*)&Bs[nt][l][0];
            acc[nt] = __builtin_amdgcn_mfma_f32_16x16x32_bf16(a, b, acc[nt], 0, 0, 0);
        }
    }
    float v[8][4];
#pragma unroll
    for (int nt = 0; nt < 8; ++nt) {
        float bb = b2f(node_b[nt * 16 + lm]);
#pragma unroll
        for (int r = 0; r < 4; ++r) v[nt][r] = acc[nt][r] + bb;
    }
#pragma unroll
    for (int r = 0; r < 4; ++r) {
        float s1 = 0.f, s2 = 0.f;
#pragma unroll
        for (int nt = 0; nt < 8; ++nt) { s1 += v[nt][r]; s2 += v[nt][r] * v[nt][r]; }
#pragma unroll
        for (int m = 1; m < 16; m <<= 1) { s1 += __shfl_xor(s1, m); s2 += __shfl_xor(s2, m); }
        float mu = s1 * (1.f / 128.f);
        float var = s2 * (1.f / 128.f) - mu * mu;
        float rs = rsqrtf(var + 1e-5f);
#pragma unroll
        for (int nt = 0; nt < 8; ++nt) {
            int n = nt * 16 + lm;
            v[nt][r] = (v[nt][r] - mu) * rs * b2f(ln2_g[n]) + b2f(ln2_b[n]);
        }
    }
#pragma unroll
    for (int nt = 0; nt < 8; ++nt)
#pragma unroll
        for (int r = 0; r < 4; ++r) {
            nxt[(row0 + w * 16 + lq * 4 + r) * 128 + nt * 16 + lm] = v[nt][r];
            Act[w * 16 + lq * 4 + r][nt * 16 + lm] = (short)f2bs(v[nt][r]);
        }

    // msg GEMM for next step: two 128-col halves, A from Act (wave-private rows)
    for (int half = 0; half < 2; ++half) {
        const bf16* Wtl = WtMsg + (size_t)half * 128 * 128;
#pragma unroll
        for (int i = 0; i < 8; i++) acc[i] = (f32x4){0.f, 0.f, 0.f, 0.f};
        for (int s = 0; s < 4; ++s) {
            int k0 = s * 32;
            __syncthreads();
#pragma unroll
            for (int rr = 0; rr < 2; ++rr) {
                int idx = rr * 256 + tid;
                int nt = idx >> 6, ll = idx & 63;
                *(short8*)&Bs[nt][ll][0] =
                    ld_frag(Wtl + (size_t)(nt * 16 + (ll & 15)) * 128 + k0 + (ll >> 4) * 8);
            }
            __syncthreads();
            short8 a = *(const short8*)&Act[w * 16 + lm][k0 + lq * 8];
#pragma unroll
            for (int nt = 0; nt < 8; ++nt) {
                short8 b = *(const short8*)&Bs[nt][l][0];
                acc[nt] = __builtin_amdgcn_mfma_f32_16x16x32_bf16(a, b, acc[nt], 0, 0, 0);
            }
        }
#pragma unroll
        for (int nt = 0; nt < 8; ++nt)
#pragma unroll
            for (int r = 0; r < 4; ++r)
                PQ[(row0 + w * 16 + lq * 4 + r) * 256 + half * 128 + nt * 16 + lm] = acc[nt][r];
    }
}

// ---------------------------------------------------------------------------
// FUSED per-row MLP (encoder, 3 layers). Single in-place Act tile.
// ---------------------------------------------------------------------------
template <int K0STEPS, int LAYERS, int RELU_LAST, int TRANS, typename TIN, typename TOUT>
__global__ __launch_bounds__(256) void mlp_k(
    const TIN* __restrict__ Xa, const TIN* __restrict__ Xb, int ldx,
    const bf16* __restrict__ Wt0, const bf16* __restrict__ b0,
    const bf16* __restrict__ Wt1, const bf16* __restrict__ b1,
    const bf16* __restrict__ Wt2, const bf16* __restrict__ b2,
    TOUT* __restrict__ Y, int ldy, int tshift)
{
    constexpr int K0 = K0STEPS * 32;
    __shared__ __align__(16) short Bs[8][64][8];
    __shared__ __align__(16) short Act[64][136];
    int tid = threadIdx.x;
    int w = tid >> 6, l = tid & 63;
    int lm = l & 15, lq = l >> 4;
    size_t row0 = (size_t)blockIdx.x * 64;

    f32x4 acc[8];
#pragma unroll
    for (int i = 0; i < 8; i++) acc[i] = (f32x4){0.f, 0.f, 0.f, 0.f};

    for (int s = 0; s < K0STEPS; ++s) {
        int k0 = s * 32;
        __syncthreads();
        short8 a;
        {
            const TIN* src = Xa; int kk = k0; int ld = ldx;
            if (Xb != nullptr && k0 >= 128) { src = Xb; kk = k0 - 128; ld = 128; }
            a = ld_frag(src + (row0 + w * 16 + lm) * (size_t)ld + kk + lq * 8);
        }
#pragma unroll
        for (int rr = 0; rr < 2; ++rr) {
            int idx = rr * 256 + tid;
            int nt = idx >> 6, ll = idx & 63;
            *(short8*)&Bs[nt][ll][0] =
                ld_frag(Wt0 + (size_t)(nt * 16 + (ll & 15)) * K0 + k0 + (ll >> 4) * 8);
        }
        __syncthreads();
#pragma unroll
        for (int nt = 0; nt < 8; ++nt) {
            short8 b = *(const short8*)&Bs[nt][l][0];
            acc[nt] = __builtin_amdgcn_mfma_f32_16x16x32_bf16(a, b, acc[nt], 0, 0, 0);
        }
    }
#pragma unroll
    for (int nt = 0; nt < 8; ++nt) {
        float bb = b2f(b0[nt * 16 + lm]);
#pragma unroll
        for (int r = 0; r < 4; ++r) {
            float x = fmaxf(acc[nt][r] + bb, 0.f);
            Act[w * 16 + lq * 4 + r][nt * 16 + lm] = (short)f2bs(x);
        }
    }

    for (int L = 1; L < LAYERS; ++L) {
        const bf16* Wt = (L == 1) ? Wt1 : Wt2;
        const bf16* bias = (L == 1) ? b1 : b2;
        bool last = (L == LAYERS - 1);
#pragma unroll
        for (int i = 0; i < 8; i++) acc[i] = (f32x4){0.f, 0.f, 0.f, 0.f};
        for (int s = 0; s < 4; ++s) {
            int k0 = s * 32;
            __syncthreads();
#pragma unroll
            for (int rr = 0; rr < 2; ++rr) {
                int idx = rr * 256 + tid;
                int nt = idx >> 6, ll = idx & 63;
                *(short8*)&Bs[nt][ll][0] =
                    ld_frag(Wt + (size_t)(nt * 16 + (ll & 15)) * 128 + k0 + (ll >> 4) * 8);
            }
            __syncthreads();
            short8 a = *(const short8*)&Act[w * 16 + lm][k0 + lq * 8];
#pragma unroll
            for (int nt = 0; nt < 8; ++nt) {
                short8 b = *(const short8*)&Bs[nt][l][0];
                acc[nt] = __builtin_amdgcn_mfma_f32_16x16x32_bf16(a, b, acc[nt], 0, 0, 0);
            }
        }
        if (!last) {
            __syncthreads();
#pragma unroll
            for (int nt = 0; nt < 8; ++nt) {
                float bb = b2f(bias[nt * 16 + lm]);
#pragma unroll
                for (int r = 0; r < 4; ++r) {
                    float x = fmaxf(acc[nt][r] + bb, 0.f);
                    Act[w * 16 + lq * 4 + r][nt * 16 + lm] = (short)f2bs(x);
                }
            }
        } else {
            float v[8][4];
#pragma unroll
            for (int nt = 0; nt < 8; ++nt) {
                float bb = b2f(bias[nt * 16 + lm]);
#pragma unroll
                for (int r = 0; r < 4; ++r) {
                    float x = acc[nt][r] + bb;
                    if (RELU_LAST) x = fmaxf(x, 0.f);
                    v[nt][r] = x;
                }
            }
            if constexpr (TRANS) {
                size_t grow = row0 + w * 16 + lq * 4;
                int bb2 = (int)(grow >> tshift);
                size_t rloc = grow & (((size_t)1 << tshift) - 1);
                bf16* YT = (bf16*)Y;
#pragma unroll
                for (int nt = 0; nt < 8; ++nt) {
                    int col = nt * 16 + lm;
                    ushort4 u;
                    u.x = f2bs(v[nt][0]); u.y = f2bs(v[nt][1]);
                    u.z = f2bs(v[nt][2]); u.w = f2bs(v[nt][3]);
                    *(ushort4*)(YT + (((size_t)bb2 * 128 + col) << tshift) + rloc) = u;
                }
            } else {
#pragma unroll
                for (int nt = 0; nt < 8; ++nt)
#pragma unroll
                    for (int r = 0; r < 4; ++r)
                        Y[(row0 + w * 16 + lq * 4 + r) * (size_t)ldy + nt * 16 + lm] =
                            Cvt<TOUT>::to(v[nt][r]);
            }
        }
    }
}

// ---------------------------------------------------------------------------
// FUSED tail: qenc (3 layers) -> q in Act; dec L0 (z|q), dec L1, final 128->3.
// ---------------------------------------------------------------------------
__global__ __launch_bounds__(256) void qdec_k(
    const bf16* __restrict__ xt32,
    const bf16* __restrict__ WtQ0, const bf16* __restrict__ qb0,
    const bf16* __restrict__ WtQ1, const bf16* __restrict__ qb1,
    const bf16* __restrict__ WtQ2, const bf16* __restrict__ qb2,
    const bf16* __restrict__ z,
    const bf16* __restrict__ WtDec0, const bf16* __restrict__ db0,
    const bf16* __restrict__ WtDec1, const bf16* __restrict__ db1,
    const bf16* __restrict__ W2, const bf16* __restrict__ b2v,
    const int* __restrict__ flag, void* __restrict__ out)
{
    __shared__ __align__(16) short Bs[8][64][8];
    __shared__ __align__(16) short Act[64][136];
    __shared__ bf16 w2s[384];
    int tid = threadIdx.x;
    int w = tid >> 6, l = tid & 63;
    int lm = l & 15, lq = l >> 4;
    size_t row0 = (size_t)blockIdx.x * 64;
    for (int t = tid; t < 384; t += 256) w2s[t] = W2[t];   // FIX: strided fill (384 > blockDim)

    f32x4 acc[8];
#pragma unroll
    for (int i = 0; i < 8; i++) acc[i] = (f32x4){0.f, 0.f, 0.f, 0.f};

    // qenc L0 (K=32)
    {
        __syncthreads();
#pragma unroll
        for (int rr = 0; rr < 2; ++rr) {
            int idx = rr * 256 + tid;
            int nt = idx >> 6, ll = idx & 63;
            *(short8*)&Bs[nt][ll][0] =
                ld_frag(WtQ0 + (size_t)(nt * 16 + (ll & 15)) * 32 + (ll >> 4) * 8);
        }
        __syncthreads();
        short8 a = ld_frag(xt32 + (row0 + w * 16 + lm) * 32 + lq * 8);
#pragma unroll
        for (int nt = 0; nt < 8; ++nt) {
            short8 b = *(const short8*)&Bs[nt][l][0];
            acc[nt] = __builtin_amdgcn_mfma_f32_16x16x32_bf16(a, b, acc[nt], 0, 0, 0);
        }
#pragma unroll
        for (int nt = 0; nt < 8; ++nt) {
            float bb = b2f(qb0[nt * 16 + lm]);
#pragma unroll
            for (int r = 0; r < 4; ++r)
                Act[w * 16 + lq * 4 + r][nt * 16 + lm] = (short)f2bs(fmaxf(acc[nt][r] + bb, 0.f));
        }
    }
    // qenc L1 (relu) and L2 (no relu) -> Act
    for (int L = 1; L < 3; ++L) {
        const bf16* Wt = (L == 1) ? WtQ1 : WtQ2;
        const bf16* bias = (L == 1) ? qb1 : qb2;
#pragma unroll
        for (int i = 0; i < 8; i++) acc[i] = (f32x4){0.f, 0.f, 0.f, 0.f};
        for (int s = 0; s < 4; ++s) {
            int k0 = s * 32;
            __syncthreads();
#pragma unroll
            for (int rr = 0; rr < 2; ++rr) {
                int idx = rr * 256 + tid;
                int nt = idx >> 6, ll = idx & 63;
                *(short8*)&Bs[nt][ll][0] =
                    ld_frag(Wt + (size_t)(nt * 16 + (ll & 15)) * 128 + k0 + (ll >> 4) * 8);
            }
            __syncthreads();
            short8 a = *(const short8*)&Act[w * 16 + lm][k0 + lq * 8];
#pragma unroll
            for (int nt = 0; nt < 8; ++nt) {
                short8 b = *(const short8*)&Bs[nt][l][0];
                acc[nt] = __builtin_amdgcn_mfma_f32_16x16x32_bf16(a, b, acc[nt], 0, 0, 0);
            }
        }
        __syncthreads();
#pragma unroll
        for (int nt = 0; nt < 8; ++nt) {
            float bb = b2f(bias[nt * 16 + lm]);
#pragma unroll
            for (int r = 0; r < 4; ++r) {
                float x = acc[nt][r] + bb;
                if (L == 1) x = fmaxf(x, 0.f);
                Act[w * 16 + lq * 4 + r][nt * 16 + lm] = (short)f2bs(x);
            }
        }
    }
    // dec L0: K=256 = z (global) | q (Act); relu -> Act
    {
#pragma unroll
        for (int i = 0; i < 8; i++) acc[i] = (f32x4){0.f, 0.f, 0.f, 0.f};
        for (int s = 0; s < 8; ++s) {
            int k0 = s * 32;
            __syncthreads();
#pragma unroll
            for (int rr = 0; rr < 2; ++rr) {
                int idx = rr * 256 + tid;
                int nt = idx >> 6, ll = idx & 63;
                *(short8*)&Bs[nt][ll][0] =
                    ld_frag(WtDec0 + (size_t)(nt * 16 + (ll & 15)) * 256 + k0 + (ll >> 4) * 8);
            }
            __syncthreads();
            short8 a;
            if (k0 < 128) a = ld_frag(z + (row0 + w * 16 + lm) * (size_t)128 + k0 + lq * 8);
            else          a = *(const short8*)&Act[w * 16 + lm][(k0 - 128) + lq * 8];
#pragma unroll
            for (int nt = 0; nt < 8; ++nt) {
                short8 b = *(const short8*)&Bs[nt][l][0];
                acc[nt] = __builtin_amdgcn_mfma_f32_16x16x32_bf16(a, b, acc[nt], 0, 0, 0);
            }
        }
        __syncthreads();
#pragma unroll
        for (int nt = 0; nt < 8; ++nt) {
            float bb = b2f(db0[nt * 16 + lm]);
#pragma unroll
            for (int r = 0; r < 4; ++r)
                Act[w * 16 + lq * 4 + r][nt * 16 + lm] = (short)f2bs(fmaxf(acc[nt][r] + bb, 0.f));
        }
    }
    // dec L1: K=128 from Act; relu -> Act
    {
#pragma unroll
        for (int i = 0; i < 8; i++) acc[i] = (f32x4){0.f, 0.f, 0.f, 0.f};
        for (int s = 0; s < 4; ++s) {
            int k0 = s * 32;
            __syncthreads();
#pragma unroll
            for (int rr = 0; rr < 2; ++rr) {
                int idx = rr * 256 + tid;
                int nt = idx >> 6, ll = idx & 63;
                *(short8*)&Bs[nt][ll][0] =
                    ld_frag(WtDec1 + (size_t)(nt * 16 + (ll & 15)) * 128 + k0 + (ll >> 4) * 8);
            }
            __syncthreads();
            short8 a = *(const short8*)&Act[w * 16 + lm][k0 + lq * 8];
#pragma unroll
            for (int nt = 0; nt < 8; ++nt) {
                short8 b = *(const short8*)&Bs[nt][l][0];
                acc[nt] = __builtin_amdgcn_mfma_f32_16x16x32_bf16(a, b, acc[nt], 0, 0, 0);
            }
        }
        __syncthreads();
#pragma unroll
        for (int nt = 0; nt < 8; ++nt) {
            float bb = b2f(db1[nt * 16 + lm]);
#pragma unroll
            for (int r = 0; r < 4; ++r)
                Act[w * 16 + lq * 4 + r][nt * 16 + lm] = (short)f2bs(fmaxf(acc[nt][r] + bb, 0.f));
        }
    }
    __syncthreads();
    // final 128 -> 3
    if (tid < 192) {
        int row = tid / 3, col = tid - (tid / 3) * 3;
        float a = b2f(b2v[col]);
        for (int k8 = 0; k8 < 16; ++k8) {
            short8 av = *(const short8*)&Act[row][k8 * 8];
#pragma unroll
            for (int j = 0; j < 8; ++j)
                a += bs2f(av[j]) * b2f(w2s[(k8 * 8 + j) * 3 + col]);
        }
        size_t o = (row0 + row) * 3 + col;
        if (*flag) ((float*)out)[o] = a;
        else       ((bf16*)out)[o] = __float2bfloat16(a);
    }
}

// ---------------------------------------------------------------------------
// fused softmax stats for xc (blocks <8192) and xt
// ---------------------------------------------------------------------------
__global__ __launch_bounds__(256) void stats2_k(const bf16* __restrict__ xcp,
                                                const bf16* __restrict__ xtp,
                                                const bf16* __restrict__ pos,
                                                float4* __restrict__ cstC4,
                                                float4* __restrict__ cstT4) {
    __shared__ float px[NNODE], py[NNODE];
    int tid = threadIdx.x;
    for (int t = tid; t < NNODE; t += 256) {
        px[t] = b2f(pos[2 * t]);
        py[t] = b2f(pos[2 * t + 1]);
    }
    __syncthreads();
    const bf16* xp = (blockIdx.x < 8192) ? xcp : xtp;
    float4* st4 = (blockIdx.x < 8192) ? cstC4 : cstT4;
    int pb = blockIdx.x & 8191;
    int w = tid >> 6, l = tid & 63;
    int p = pb * 4 + w;
    float x = b2f(xp[2 * p]), y = b2f(xp[2 * p + 1]);
    float vals[16];
    float m = -3.4e38f;
#pragma unroll
    for (int k = 0; k < 16; k++) {
        int n = k * 64 + l;
        float dx = x - px[n], dy = y - py[n];
        float v = -(dx * dx + dy * dy);
        vals[k] = v;
        m = fmaxf(m, v);
    }
#pragma unroll
    for (int off = 32; off; off >>= 1) m = fmaxf(m, __shfl_xor(m, off));
    float s = 0.f;
#pragma unroll
    for (int k = 0; k < 16; k++) s += __expf(vals[k] - m);
#pragma unroll
    for (int off = 32; off; off >>= 1) s += __shfl_xor(s, off);
    if (l == 0) st4[p] = make_float4(x, y, m, 1.f / s);
}

struct P8 { float* p[8]; };

// ---------------------------------------------------------------------------
// lat partials via MFMA, XCD-affine, K-split; conflict-free red layout.
// ---------------------------------------------------------------------------
__global__ __launch_bounds__(512, 4) void lat_mfma_k(const bf16* __restrict__ embT,
                                                     const float2* __restrict__ posf2,
                                                     const float4* __restrict__ cstC4,
                                                     P8 parts) {
    int i = blockIdx.x;
    int b = i & 7, r = i >> 3;
    int cs = r >> 4, nt = r & 15;
    int n0 = nt * 64;
    __shared__ __align__(16) float4 csh[512];
    __shared__ __align__(16) float4 red[4][8][64];
    int tid = threadIdx.x;
    int w = tid >> 6, l = tid & 63;
    int wl = w & 3, up = w >> 2;
    int lm = l & 15, lq = l >> 4;
    int node = n0 + wl * 16 + lm;
    float2 pn = posf2[node];
    const bf16* ebase = embT + ((size_t)b << 19) + cs * 512;
    const float4* cbase = cstC4 + b * NC + cs * 512;
    for (int t = tid; t < 512; t += 512) csh[t] = cbase[t];
    __syncthreads();

    f32x4 acc[8];
#pragma unroll
    for (int q = 0; q < 8; q++) acc[q] = (f32x4){0.f, 0.f, 0.f, 0.f};

    union AF { short8 s; u16 u[8]; };
    AF cw, nw;
    short8 bc[8], bn[8];
    int chb = up * 8;
    int c00 = chb * 32;
#pragma unroll
    for (int j = 0; j < 8; ++j) {
        float4 cc = csh[c00 + lq * 8 + j];
        float dx = cc.x - pn.x, dy = cc.y - pn.y;
        cw.u[j] = f2bs(__expf(-(dx * dx + dy * dy) - cc.z) * cc.w);
    }
#pragma unroll
    for (int t2 = 0; t2 < 8; ++t2)
        bc[t2] = ld_frag(ebase + ((size_t)(t2 * 16 + lm) << 12) + c00 + lq * 8);

    for (int ch = 0; ch < 8; ++ch) {
        int c0n = (chb + ((ch + 1) & 7)) * 32;
#pragma unroll
        for (int t2 = 0; t2 < 8; ++t2)
            bn[t2] = ld_frag(ebase + ((size_t)(t2 * 16 + lm) << 12) + c0n + lq * 8);
#pragma unroll
        for (int j = 0; j < 8; ++j) {
            float4 cc = csh[c0n + lq * 8 + j];
            float dx = cc.x - pn.x, dy = cc.y - pn.y;
            nw.u[j] = f2bs(__expf(-(dx * dx + dy * dy) - cc.z) * cc.w);
        }
#pragma unroll
        for (int t2 = 0; t2 < 8; ++t2)
            acc[t2] = __builtin_amdgcn_mfma_f32_16x16x32_bf16(cw.s, bc[t2], acc[t2], 0, 0, 0);
        cw = nw;
#pragma unroll
        for (int t2 = 0; t2 < 8; ++t2) bc[t2] = bn[t2];
    }
    if (up) {
#pragma unroll
        for (int t2 = 0; t2 < 8; ++t2)
            red[wl][t2][l] = make_float4(acc[t2][0], acc[t2][1], acc[t2][2], acc[t2][3]);
    }
    __syncthreads();
    if (!up) {
        float* part = parts.p[cs] + (((size_t)(b * NNODE + n0 + wl * 16 + lq * 4)) << 7) + lm;
#pragma unroll
        for (int t2 = 0; t2 < 8; ++t2) {
            float4 o = red[wl][t2][l];
#pragma unroll
            for (int r2 = 0; r2 < 4; ++r2)
                part[(r2 << 7) + t2 * 16] = acc[t2][r2] + ((const float*)&o)[r2];
        }
    }
}

__global__ __launch_bounds__(256) void reduce8_k(float* __restrict__ dst, P8 parts) {
    int i = blockIdx.x * 256 + threadIdx.x;
    float4 s = ((const float4*)parts.p[0])[i];
#pragma unroll
    for (int k = 1; k < 8; ++k) {
        float4 v = ((const float4*)parts.p[k])[i];
        s.x += v.x; s.y += v.y; s.z += v.z; s.w += v.w;
    }
    ((float4*)dst)[i] = s;
}

// ---------------------------------------------------------------------------
// z via MFMA, XCD-affine, K-split; conflict-free red layout.
// ---------------------------------------------------------------------------
__global__ __launch_bounds__(512, 4) void z_mfma_k(const bf16* __restrict__ latT,
                                                   const float2* __restrict__ posf2,
                                                   const float4* __restrict__ cstT4,
                                                   bf16* __restrict__ z) {
    int i = blockIdx.x;
    int b = i & 7, tt = i >> 3;
    int t0 = tt * 64;
    __shared__ __align__(8) float2 posh[1024];
    __shared__ __align__(16) float4 red[4][8][64];
    int tid = threadIdx.x;
    int w = tid >> 6, l = tid & 63;
    int wl = w & 3, up = w >> 2;
    int lm = l & 15, lq = l >> 4;
    int t = t0 + wl * 16 + lm;
    float4 qs = cstT4[b * NTT + t];
    const bf16* lbase = latT + ((size_t)b << 17);
    for (int k = tid; k < 1024; k += 512) posh[k] = posf2[k];
    __syncthreads();

    f32x4 acc[8];
#pragma unroll
    for (int q = 0; q < 8; q++) acc[q] = (f32x4){0.f, 0.f, 0.f, 0.f};

    union AF { short8 s; u16 u[8]; };
    AF cw, nw;
    short8 bc[8], bn[8];
    int chb = up * 16;
    int nb0 = chb * 32;
#pragma unroll
    for (int j = 0; j < 8; ++j) {
        float2 pn = posh[nb0 + lq * 8 + j];
        float dx = qs.x - pn.x, dy = qs.y - pn.y;
        cw.u[j] = f2bs(__expf(-(dx * dx + dy * dy) - qs.z) * qs.w);
    }
#pragma unroll
    for (int t2 = 0; t2 < 8; ++t2)
        bc[t2] = ld_frag(lbase + ((size_t)(t2 * 16 + lm) << 10) + nb0 + lq * 8);

    for (int ch = 0; ch < 16; ++ch) {
        int nbn = (chb + ((ch + 1) & 15)) * 32;
#pragma unroll
        for (int t2 = 0; t2 < 8; ++t2)
            bn[t2] = ld_frag(lbase + ((size_t)(t2 * 16 + lm) << 10) + nbn + lq * 8);
#pragma unroll
        for (int j = 0; j < 8; ++j) {
            float2 pn = posh[nbn + lq * 8 + j];
            float dx = qs.x - pn.x, dy = qs.y - pn.y;
            nw.u[j] = f2bs(__expf(-(dx * dx + dy * dy) - qs.z) * qs.w);
        }
#pragma unroll
        for (int t2 = 0; t2 < 8; ++t2)
            acc[t2] = __builtin_amdgcn_mfma_f32_16x16x32_bf16(cw.s, bc[t2], acc[t2], 0, 0, 0);
        cw = nw;
#pragma unroll
        for (int t2 = 0; t2 < 8; ++t2) bc[t2] = bn[t2];
    }
    if (up) {
#pragma unroll
        for (int t2 = 0; t2 < 8; ++t2)
            red[wl][t2][l] = make_float4(acc[t2][0], acc[t2][1], acc[t2][2], acc[t2][3]);
    }
    __syncthreads();
    if (!up) {
        bf16* zp = z + (((size_t)(b * NTT + t0 + wl * 16 + lq * 4)) << 7) + lm;
#pragma unroll
        for (int t2 = 0; t2 < 8; ++t2) {
            float4 o = red[wl][t2][l];
#pragma unroll
            for (int r2 = 0; r2 < 4; ++r2)
                zp[(r2 << 7) + t2 * 16] = __float2bfloat16(acc[t2][r2] + ((const float*)&o)[r2]);
        }
    }
}

// ---------------------------------------------------------------------------
// edge gather: one wave per (b, node). No atomics.
// ---------------------------------------------------------------------------
__global__ __launch_bounds__(256) void edge_gather_k(const float* __restrict__ PQ,
                                                     const int* __restrict__ rowptr,
                                                     const int* __restrict__ csr_send,
                                                     const bf16* __restrict__ mb,
                                                     const bf16* __restrict__ g1,
                                                     const bf16* __restrict__ b1,
                                                     float* __restrict__ inbox) {
    int tid = threadIdx.x;
    int w = tid >> 6, l = tid & 63;
    int gw = blockIdx.x * 4 + w;
    int b = gw >> 10, n = gw & 1023;
    const float* pqb = PQ + ((size_t)b << 18);
    float p0 = pqb[(n << 8) + l];
    float p1 = pqb[(n << 8) + l + 64];
    float mb0 = b2f(mb[l]), mb1 = b2f(mb[l + 64]);
    float g0 = b2f(g1[l]), g1v = b2f(g1[l + 64]);
    float bb0 = b2f(b1[l]), bb1 = b2f(b1[l + 64]);
    int beg = rowptr[n], end = rowptr[n + 1];
    float a0 = 0.f, a1 = 0.f;
    for (int i = beg; i < end; ++i) {
        int s = csr_send[i];
        const float* q = pqb + (s << 8) + 128;
        float m0 = p0 + q[l] + mb0;
        float m1 = p1 + q[l + 64] + mb1;
        float s1 = m0 + m1, s2 = m0 * m0 + m1 * m1;
#pragma unroll
        for (int off = 32; off; off >>= 1) {
            s1 += __shfl_xor(s1, off);
            s2 += __shfl_xor(s2, off);
        }
        float mu = s1 * (1.f / 128.f);
        float var = s2 * (1.f / 128.f) - mu * mu;
        float rs = rsqrtf(var + 1e-5f);
        a0 += (m0 - mu) * rs * g0 + bb0;
        a1 += (m1 - mu) * rs * g1v + bb1;
    }
    float* inb = inbox + ((size_t)b << 17) + (n << 7);
    inb[l] = a0;
    inb[l + 64] = a1;
}

// ---------------------------------------------------------------------------
extern "C" void kernel_launch(void* const* d_in, const int* in_sizes, int n_in,
                              void* d_out, int out_size, void* d_ws, size_t ws_size,
                              hipStream_t stream) {
    const int* senders = (const int*)d_in[30];
    const int* receivers = (const int*)d_in[31];

    char* base = (char*)d_ws;
    size_t off = 0;
    auto alloc = [&](size_t bytes) { char* p = base + off; off += (bytes + 255) & ~(size_t)255; return p; };

    int* flag = (int*)alloc(256);

    Tab tab;
    int pref = 0;
    for (int i = 0; i < 30; ++i) { tab.src[i] = d_in[i]; tab.pref[i] = pref; pref += in_sizes[i]; }
    tab.pref[30] = pref;
    bf16* arena = (bf16*)alloc((size_t)pref * 2);
    auto C = [&](int i) { return arena + tab.pref[i]; };

    float4* cstC4 = (float4*)alloc(32768 * sizeof(float4));
    float4* cstT4 = (float4*)alloc(32768 * sizeof(float4));
    float* lat0  = (float*)alloc(8192 * 128 * 4);
    float* lat1  = (float*)alloc(8192 * 128 * 4);
    float* inbox = (float*)alloc(8192 * 128 * 4);
    bf16* T1     = (bf16*)alloc((size_t)32768 * 128 * 2);
    bf16* T2     = (bf16*)alloc((size_t)32768 * 128 * 2);
    bf16* T3     = (bf16*)alloc((size_t)32768 * 128 * 2);
    bf16* embT   = (bf16*)alloc((size_t)8 * 128 * 4096 * 2);
    bf16* latT   = (bf16*)alloc((size_t)8 * 128 * 1024 * 2);
    bf16* xin32  = (bf16*)alloc((size_t)32768 * 32 * 2);
    bf16* xt32   = (bf16*)alloc((size_t)32768 * 32 * 2);
    float2* posf2 = (float2*)alloc(1024 * sizeof(float2));
    int* rowptr  = (int*)alloc(1025 * 4);
    int* csr_send = (int*)alloc(NEDGE * 4);
    bf16* WtEnc0 = (bf16*)alloc(128 * 32 * 2);
    bf16* WtQ0   = (bf16*)alloc(128 * 32 * 2);
    bf16* WtEnc1 = (bf16*)alloc(16384 * 2);
    bf16* WtEnc2 = (bf16*)alloc(16384 * 2);
    bf16* WtQ1   = (bf16*)alloc(16384 * 2);
    bf16* WtQ2   = (bf16*)alloc(16384 * 2);
    bf16* WtDec0 = (bf16*)alloc(32768 * 2);
    bf16* WtDec1 = (bf16*)alloc(16384 * 2);
    bf16* WtMsg  = (bf16*)alloc(32768 * 2);
    bf16* WtNode = (bf16*)alloc(32768 * 2);
    float* PQ    = (float*)T3;
    (void)ws_size; (void)n_in; (void)out_size;

    detect_k<<<1, 256, 0, stream>>>((const u16*)d_in[3], flag);
    ingest_k<<<(pref + 255) / 256, 256, 0, stream>>>(tab, flag, arena);

    const bf16 *xc = C(0), *yc = C(1), *xt = C(2), *pos = C(3);
    const bf16 *enc_W0 = C(4), *enc_b0 = C(5), *enc_W1 = C(6), *enc_b1 = C(7), *enc_W2 = C(8), *enc_b2 = C(9);
    const bf16 *qenc_W0 = C(10), *qenc_b0 = C(11), *qenc_W1 = C(12), *qenc_b1 = C(13), *qenc_W2 = C(14), *qenc_b2 = C(15);
    const bf16 *dec_W0 = C(16), *dec_b0 = C(17), *dec_W1 = C(18), *dec_b1 = C(19), *dec_W2 = C(20), *dec_b2 = C(21);
    const bf16 *msg_W = C(22), *msg_b = C(23), *ln1_g = C(24), *ln1_b = C(25);
    const bf16 *node_W = C(26), *node_b = C(27), *ln2_g = C(28), *ln2_b = C(29);

    TT tt;
    const bf16* s11[11] = { enc_W1, enc_W2, qenc_W1, qenc_W2, dec_W1, dec_W0, msg_W, msg_W + 16384, node_W, enc_W0, qenc_W0 };
    bf16* d11[11]       = { WtEnc1, WtEnc2, WtQ1,    WtQ2,    WtDec1, WtDec0, WtMsg, WtMsg + 16384, WtNode, WtEnc0, WtQ0   };
    int sk11[11] = { 128, 128, 128, 128, 128, 256, 128, 128, 256, 5, 2 };
    int dk11[11] = { 128, 128, 128, 128, 128, 256, 128, 128, 256, 32, 32 };
    int tp = 0;
    for (int i = 0; i < 11; ++i) {
        tt.src[i] = s11[i]; tt.dst[i] = d11[i]; tt.srcK[i] = sk11[i]; tt.dK[i] = dk11[i];
        tt.pref[i] = tp; tp += dk11[i] * 128;
    }
    tt.pref[11] = tp;

    prep_trans_k<<<128 + (tp + 255) / 256, 256, 0, stream>>>(tt, xc, yc, xt, pos, xin32, xt32, posf2);
    build_csr_k<<<1, 1024, 0, stream>>>(receivers, senders, rowptr, csr_send);

    // encoder (fused 3-layer MLP): xin32 -> embT (transposed)
    mlp_k<1, 3, 0, 1, bf16, bf16><<<512, 256, 0, stream>>>(
        xin32, nullptr, 32, WtEnc0, enc_b0, WtEnc1, enc_b1, WtEnc2, enc_b2, embT, 128, 12);

    stats2_k<<<16384, 256, 0, stream>>>(xc, xt, pos, cstC4, cstT4);

    P8 parts;
    parts.p[0] = lat1;
    parts.p[1] = inbox;
    parts.p[2] = (float*)T1;
    parts.p[3] = (float*)T1 + 1048576;
    parts.p[4] = (float*)T2;
    parts.p[5] = (float*)T2 + 1048576;
    parts.p[6] = (float*)T3;
    parts.p[7] = (float*)T3 + 1048576;
    lat_mfma_k<<<1024, 512, 0, stream>>>(embT, posf2, cstC4, parts);
    reduce8_k<<<1024, 256, 0, stream>>>(lat0, parts);

    // 4-step recurrence, node+msg fused (multi-launch; stream-ordered launches
    // are the cheap grid barrier on MI355X)
    mfma_gemm_k<4, 0, 0, 0, 2, float, float><<<256, 256, 0, stream>>>(lat0, nullptr, 128, WtMsg, nullptr, nullptr, nullptr, PQ, 256, 0);
    edge_gather_k<<<2048, 256, 0, stream>>>(PQ, rowptr, csr_send, msg_b, ln1_g, ln1_b, inbox);
    node_msg_k<<<128, 256, 0, stream>>>(lat0, inbox, WtNode, node_b, ln2_g, ln2_b, WtMsg, lat1, PQ);
    edge_gather_k<<<2048, 256, 0, stream>>>(PQ, rowptr, csr_send, msg_b, ln1_g, ln1_b, inbox);
    node_msg_k<<<128, 256, 0, stream>>>(lat1, inbox, WtNode, node_b, ln2_g, ln2_b, WtMsg, lat0, PQ);
    edge_gather_k<<<2048, 256, 0, stream>>>(PQ, rowptr, csr_send, msg_b, ln1_g, ln1_b, inbox);
    node_msg_k<<<128, 256, 0, stream>>>(lat0, inbox, WtNode, node_b, ln2_g, ln2_b, WtMsg, lat1, PQ);
    edge_gather_k<<<2048, 256, 0, stream>>>(PQ, rowptr, csr_send, msg_b, ln1_g, ln1_b, inbox);
    mfma_gemm_k<8, 1, 0, 1, 1, float, bf16><<<128, 256, 0, stream>>>(lat1, inbox, 128, WtNode, node_b, ln2_g, ln2_b, latT, 128, 10);

    // z -> T2 (bf16)
    z_mfma_k<<<512, 512, 0, stream>>>(latT, posf2, cstT4, T2);

    // fused tail: qenc(xt32) + dec(z|q) + final -> out
    qdec_k<<<512, 256, 0, stream>>>(xt32,
                                    WtQ0, qenc_b0, WtQ1, qenc_b1, WtQ2, qenc_b2,
                                    T2,
                                    WtDec0, dec_b0, WtDec1, dec_b1,
                                    dec_W2, dec_b2, flag, d_out);
}

// Round 18
// 531.804 us; speedup vs baseline: 3.7666x; 1.0163x over previous
//
#include <hip/hip_runtime.h>
#include <hip/hip_bf16.h>
#include <string.h>

#define BB 8
#define NC 4096
#define NTT 4096
#define NNODE 1024
#define NEDGE 16384

typedef __hip_bfloat16 bf16;
typedef unsigned short u16;
typedef __attribute__((ext_vector_type(8))) short short8;
typedef __attribute__((ext_vector_type(4))) float f32x4;

__device__ __forceinline__ float b2f(bf16 x) { return __bfloat162float(x); }
__device__ __forceinline__ float bs2f(short s) { return __uint_as_float(((unsigned)(unsigned short)s) << 16); }

template <typename T> struct Cvt;
template <> struct Cvt<float> { static __device__ __forceinline__ float to(float v) { return v; } };
template <> struct Cvt<bf16>  { static __device__ __forceinline__ bf16  to(float v) { return __float2bfloat16(v); } };

__device__ __forceinline__ unsigned short f2bs(float x) {
    unsigned u = __float_as_uint(x);
    return (unsigned short)((u + 0x7FFFu + ((u >> 16) & 1u)) >> 16);
}

__device__ __forceinline__ short8 ld_frag(const bf16* g) {
    union { uint4 u4; short8 s8; } cv;
    cv.u4 = *(const uint4*)g;
    return cv.s8;
}
__device__ __forceinline__ short8 ld_frag(const float* g) {
    float4 f0 = *(const float4*)g;
    float4 f1 = *(const float4*)(g + 4);
    short8 r;
    r[0] = (short)f2bs(f0.x); r[1] = (short)f2bs(f0.y);
    r[2] = (short)f2bs(f0.z); r[3] = (short)f2bs(f0.w);
    r[4] = (short)f2bs(f1.x); r[5] = (short)f2bs(f1.y);
    r[6] = (short)f2bs(f1.z); r[7] = (short)f2bs(f1.w);
    return r;
}

// ---------------------------------------------------------------------------
__global__ void detect_k(const u16* __restrict__ posu, int* __restrict__ flag) {
    __shared__ int cnt;
    if (threadIdx.x == 0) cnt = 0;
    __syncthreads();
    int wild = 0;
    for (int i = threadIdx.x; i < 1024; i += 256) {
        u16 u = posu[2 * i];
        int ex = (u >> 7) & 0xFF;
        if (ex == 0 || ex == 0xFF || ex > 137 || ex < 107) wild++;
    }
    atomicAdd(&cnt, wild);
    __syncthreads();
    if (threadIdx.x == 0) *flag = (cnt > 50) ? 1 : 0;
}

// ---------------------------------------------------------------------------
struct Tab { const void* src[30]; int pref[31]; };

__global__ __launch_bounds__(256) void ingest_k(Tab tab, const int* __restrict__ flag,
                                                bf16* __restrict__ dst) {
    int idx = blockIdx.x * 256 + threadIdx.x;
    if (idx >= tab.pref[30]) return;
    int t = 0;
    while (tab.pref[t + 1] <= idx) t++;
    int e = idx - tab.pref[t];
    float v;
    if (*flag) v = ((const float*)tab.src[t])[e];
    else       v = b2f(((const bf16*)tab.src[t])[e]);
    dst[idx] = __float2bfloat16(v);
}

// ---------------------------------------------------------------------------
// fused prep (blocks 0..127) + zero-padding weight transpose (blocks 128..)
// ---------------------------------------------------------------------------
struct TT { const bf16* src[11]; bf16* dst[11]; int srcK[11]; int dK[11]; int pref[12]; };

__global__ __launch_bounds__(256) void prep_trans_k(
    TT tt,
    const bf16* __restrict__ xc, const bf16* __restrict__ yc,
    const bf16* __restrict__ xt,
    const bf16* __restrict__ pos,
    bf16* __restrict__ xin32, bf16* __restrict__ xt32,
    float2* __restrict__ posf2) {
    if (blockIdx.x < 128) {
        int row = blockIdx.x * 256 + threadIdx.x;
        bf16 z = __float2bfloat16(0.f);
        bf16* xr = xin32 + row * 32;
        xr[0] = xc[row * 2 + 0];
        xr[1] = xc[row * 2 + 1];
        xr[2] = yc[row * 3 + 0];
        xr[3] = yc[row * 3 + 1];
        xr[4] = yc[row * 3 + 2];
#pragma unroll
        for (int k = 5; k < 32; ++k) xr[k] = z;
        bf16* tr = xt32 + row * 32;
        tr[0] = xt[row * 2 + 0];
        tr[1] = xt[row * 2 + 1];
#pragma unroll
        for (int k = 2; k < 32; ++k) tr[k] = z;
        if (row < NNODE) posf2[row] = make_float2(b2f(pos[2 * row]), b2f(pos[2 * row + 1]));
        return;
    }
    int idx = (blockIdx.x - 128) * 256 + threadIdx.x;
    if (idx >= tt.pref[11]) return;
    int t = 0;
    while (tt.pref[t + 1] <= idx) t++;
    int e = idx - tt.pref[t];
    int k = e >> 7, n = e & 127;
    bf16 v = (k < tt.srcK[t]) ? tt.src[t][k * 128 + n] : __float2bfloat16(0.f);
    tt.dst[t][n * tt.dK[t] + k] = v;
}

// ---------------------------------------------------------------------------
__global__ __launch_bounds__(1024) void build_csr_k(const int* __restrict__ recv,
                                                    const int* __restrict__ send,
                                                    int* __restrict__ rowptr,
                                                    int* __restrict__ csr_send) {
    __shared__ int cnt[1024];
    __shared__ int wt[16], wt2[16];
    __shared__ int cur[1024];
    int t = threadIdx.x;
    cnt[t] = 0;
    __syncthreads();
    for (int e = t; e < NEDGE; e += 1024) atomicAdd(&cnt[recv[e]], 1);
    __syncthreads();
    int v = cnt[t];
    int lane = t & 63, w = t >> 6;
#pragma unroll
    for (int off = 1; off < 64; off <<= 1) {
        int u = __shfl_up(v, off);
        if (lane >= off) v += u;
    }
    if (lane == 63) wt[w] = v;
    __syncthreads();
    if (t < 16) {
        int x = wt[t];
#pragma unroll
        for (int off = 1; off < 16; off <<= 1) {
            int u = __shfl_up(x, off);
            if (t >= off) x += u;
        }
        wt2[t] = x;
    }
    __syncthreads();
    int excl = v - cnt[t] + (w ? wt2[w - 1] : 0);
    rowptr[t] = excl;
    cur[t] = excl;
    if (t == 0) rowptr[1024] = NEDGE;
    __syncthreads();
    for (int e = t; e < NEDGE; e += 1024) {
        int pos = atomicAdd(&cur[recv[e]], 1);
        csr_send[pos] = send[e];
    }
}

// ---------------------------------------------------------------------------
// MFMA GEMM (first msg + final node). A-frags direct from global.
// TINA = type of Xa (k<128), TINB = type of Xb (k>=128).
// ---------------------------------------------------------------------------
template <int KSTEPS, int EPI, int RELU, int TRANS, int NSPLIT,
          typename TINA, typename TINB, typename TOUT>
__global__ __launch_bounds__(256) void mfma_gemm_k(
    const TINA* __restrict__ Xa, const TINB* __restrict__ Xb, int ldx,
    const bf16* __restrict__ Wt,
    const bf16* __restrict__ bias,
    const bf16* __restrict__ lng, const bf16* __restrict__ lnb,
    TOUT* __restrict__ Y, int ldy, int tshift)
{
    constexpr int K = KSTEPS * 32;
    __shared__ __align__(16) short Bs[8][64][8];
    int tid = threadIdx.x;
    int w = tid >> 6, l = tid & 63;
    int lm = l & 15, lq = l >> 4;
    int blk = blockIdx.x;
    int half = 0;
    if (NSPLIT == 2) { half = blk & 1; blk >>= 1; }
    const bf16* Wtl = Wt + (size_t)half * 128 * K;
    int colbase = half * 128;
    size_t row0 = (size_t)blk * 64;

    f32x4 acc[8];
#pragma unroll
    for (int i = 0; i < 8; i++) acc[i] = (f32x4){0.f, 0.f, 0.f, 0.f};

    for (int s = 0; s < KSTEPS; ++s) {
        int k0 = s * 32;
        __syncthreads();
        short8 a;
        if (Xb != nullptr && k0 >= 128)
            a = ld_frag(Xb + (row0 + w * 16 + lm) * (size_t)128 + (k0 - 128) + lq * 8);
        else
            a = ld_frag(Xa + (row0 + w * 16 + lm) * (size_t)ldx + k0 + lq * 8);
#pragma unroll
        for (int rr = 0; rr < 2; ++rr) {
            int idx = rr * 256 + tid;
            int nt = idx >> 6, ll = idx & 63;
            *(short8*)&Bs[nt][ll][0] =
                ld_frag(Wtl + (size_t)(nt * 16 + (ll & 15)) * K + k0 + (ll >> 4) * 8);
        }
        __syncthreads();
#pragma unroll
        for (int nt = 0; nt < 8; ++nt) {
            short8 b = *(const short8*)&Bs[nt][l][0];
            acc[nt] = __builtin_amdgcn_mfma_f32_16x16x32_bf16(a, b, acc[nt], 0, 0, 0);
        }
    }

    float v[8][4];
#pragma unroll
    for (int nt = 0; nt < 8; ++nt) {
        float bb = bias ? b2f(bias[colbase + nt * 16 + lm]) : 0.f;
#pragma unroll
        for (int r = 0; r < 4; ++r) v[nt][r] = acc[nt][r] + bb;
    }
    if constexpr (EPI == 1) {
#pragma unroll
        for (int r = 0; r < 4; ++r) {
            float s1 = 0.f, s2 = 0.f;
#pragma unroll
            for (int nt = 0; nt < 8; ++nt) { s1 += v[nt][r]; s2 += v[nt][r] * v[nt][r]; }
#pragma unroll
            for (int m = 1; m < 16; m <<= 1) { s1 += __shfl_xor(s1, m); s2 += __shfl_xor(s2, m); }
            float mu = s1 * (1.f / 128.f);
            float var = s2 * (1.f / 128.f) - mu * mu;
            float rs = rsqrtf(var + 1e-5f);
#pragma unroll
            for (int nt = 0; nt < 8; ++nt) {
                int n = nt * 16 + lm;
                v[nt][r] = (v[nt][r] - mu) * rs * b2f(lng[n]) + b2f(lnb[n]);
            }
        }
    }
    if constexpr (TRANS) {
        size_t grow = row0 + w * 16 + lq * 4;
        int bb2 = (int)(grow >> tshift);
        size_t rloc = grow & (((size_t)1 << tshift) - 1);
        bf16* YT = (bf16*)Y;
#pragma unroll
        for (int nt = 0; nt < 8; ++nt) {
            int col = colbase + nt * 16 + lm;
            ushort4 u;
            float x0 = v[nt][0], x1 = v[nt][1], x2 = v[nt][2], x3 = v[nt][3];
            if (RELU) { x0 = fmaxf(x0, 0.f); x1 = fmaxf(x1, 0.f); x2 = fmaxf(x2, 0.f); x3 = fmaxf(x3, 0.f); }
            u.x = f2bs(x0); u.y = f2bs(x1); u.z = f2bs(x2); u.w = f2bs(x3);
            *(ushort4*)(YT + (((size_t)bb2 * 128 + col) << tshift) + rloc) = u;
        }
    } else {
#pragma unroll
        for (int nt = 0; nt < 8; ++nt)
#pragma unroll
            for (int r = 0; r < 4; ++r) {
                float x = v[nt][r];
                if (RELU) x = fmaxf(x, 0.f);
                Y[(row0 + w * 16 + lq * 4 + r) * (size_t)ldy + colbase + nt * 16 + lm] = Cvt<TOUT>::to(x);
            }
    }
}

// ---------------------------------------------------------------------------
// FUSED node-GEMM+LN then msg-GEMM for the NEXT step (row-local chain).
// cur: f32 latents; inbox: bf16; writes nxt (f32) and PQ (bf16 [row][256]).
// ---------------------------------------------------------------------------
__global__ __launch_bounds__(256) void node_msg_k(
    const float* __restrict__ cur, const bf16* __restrict__ inbox,
    const bf16* __restrict__ WtNode, const bf16* __restrict__ node_b,
    const bf16* __restrict__ ln2_g, const bf16* __restrict__ ln2_b,
    const bf16* __restrict__ WtMsg,
    float* __restrict__ nxt, bf16* __restrict__ PQ)
{
    __shared__ __align__(16) short Bs[8][64][8];
    __shared__ __align__(16) short Act[64][136];
    int tid = threadIdx.x;
    int w = tid >> 6, l = tid & 63;
    int lm = l & 15, lq = l >> 4;
    size_t row0 = (size_t)blockIdx.x * 64;

    f32x4 acc[8];
#pragma unroll
    for (int i = 0; i < 8; i++) acc[i] = (f32x4){0.f, 0.f, 0.f, 0.f};

    // node GEMM K=256 (cur f32 | inbox bf16)
    for (int s = 0; s < 8; ++s) {
        int k0 = s * 32;
        __syncthreads();
        short8 a;
        if (k0 < 128) a = ld_frag(cur + (row0 + w * 16 + lm) * 128 + k0 + lq * 8);
        else          a = ld_frag(inbox + (row0 + w * 16 + lm) * 128 + (k0 - 128) + lq * 8);
#pragma unroll
        for (int rr = 0; rr < 2; ++rr) {
            int idx = rr * 256 + tid;
            int nt = idx >> 6, ll = idx & 63;
            *(short8*)&Bs[nt][ll][0] =
                ld_frag(WtNode + (size_t)(nt * 16 + (ll & 15)) * 256 + k0 + (ll >> 4) * 8);
        }
        __syncthreads();
#pragma unroll
        for (int nt = 0; nt < 8; ++nt) {
            short8 b = *(const short8*)&Bs[nt][l][0];
            acc[nt] = __builtin_amdgcn_mfma_f32_16x16x32_bf16(a, b, acc[nt], 0, 0, 0);
        }
    }
    float v[8][4];
#pragma unroll
    for (int nt = 0; nt < 8; ++nt) {
        float bb = b2f(node_b[nt * 16 + lm]);
#pragma unroll
        for (int r = 0; r < 4; ++r) v[nt][r] = acc[nt][r] + bb;
    }
#pragma unroll
    for (int r = 0; r < 4; ++r) {
        float s1 = 0.f, s2 = 0.f;
#pragma unroll
        for (int nt = 0; nt < 8; ++nt) { s1 += v[nt][r]; s2 += v[nt][r] * v[nt][r]; }
#pragma unroll
        for (int m = 1; m < 16; m <<= 1) { s1 += __shfl_xor(s1, m); s2 += __shfl_xor(s2, m); }
        float mu = s1 * (1.f / 128.f);
        float var = s2 * (1.f / 128.f) - mu * mu;
        float rs = rsqrtf(var + 1e-5f);
#pragma unroll
        for (int nt = 0; nt < 8; ++nt) {
            int n = nt * 16 + lm;
            v[nt][r] = (v[nt][r] - mu) * rs * b2f(ln2_g[n]) + b2f(ln2_b[n]);
        }
    }
#pragma unroll
    for (int nt = 0; nt < 8; ++nt)
#pragma unroll
        for (int r = 0; r < 4; ++r) {
            nxt[(row0 + w * 16 + lq * 4 + r) * 128 + nt * 16 + lm] = v[nt][r];
            Act[w * 16 + lq * 4 + r][nt * 16 + lm] = (short)f2bs(v[nt][r]);
        }

    // msg GEMM for next step: two 128-col halves, A from Act
    for (int half = 0; half < 2; ++half) {
        const bf16* Wtl = WtMsg + (size_t)half * 128 * 128;
#pragma unroll
        for (int i = 0; i < 8; i++) acc[i] = (f32x4){0.f, 0.f, 0.f, 0.f};
        for (int s = 0; s < 4; ++s) {
            int k0 = s * 32;
            __syncthreads();
#pragma unroll
            for (int rr = 0; rr < 2; ++rr) {
                int idx = rr * 256 + tid;
                int nt = idx >> 6, ll = idx & 63;
                *(short8*)&Bs[nt][ll][0] =
                    ld_frag(Wtl + (size_t)(nt * 16 + (ll & 15)) * 128 + k0 + (ll >> 4) * 8);
            }
            __syncthreads();
            short8 a = *(const short8*)&Act[w * 16 + lm][k0 + lq * 8];
#pragma unroll
            for (int nt = 0; nt < 8; ++nt) {
                short8 b = *(const short8*)&Bs[nt][l][0];
                acc[nt] = __builtin_amdgcn_mfma_f32_16x16x32_bf16(a, b, acc[nt], 0, 0, 0);
            }
        }
#pragma unroll
        for (int nt = 0; nt < 8; ++nt)
#pragma unroll
            for (int r = 0; r < 4; ++r)
                PQ[(row0 + w * 16 + lq * 4 + r) * 256 + half * 128 + nt * 16 + lm] =
                    __float2bfloat16(acc[nt][r]);
    }
}

// ---------------------------------------------------------------------------
// FUSED per-row MLP (encoder, 3 layers). Single in-place Act tile.
// ---------------------------------------------------------------------------
template <int K0STEPS, int LAYERS, int RELU_LAST, int TRANS, typename TIN, typename TOUT>
__global__ __launch_bounds__(256) void mlp_k(
    const TIN* __restrict__ Xa, const TIN* __restrict__ Xb, int ldx,
    const bf16* __restrict__ Wt0, const bf16* __restrict__ b0,
    const bf16* __restrict__ Wt1, const bf16* __restrict__ b1,
    const bf16* __restrict__ Wt2, const bf16* __restrict__ b2,
    TOUT* __restrict__ Y, int ldy, int tshift)
{
    constexpr int K0 = K0STEPS * 32;
    __shared__ __align__(16) short Bs[8][64][8];
    __shared__ __align__(16) short Act[64][136];
    int tid = threadIdx.x;
    int w = tid >> 6, l = tid & 63;
    int lm = l & 15, lq = l >> 4;
    size_t row0 = (size_t)blockIdx.x * 64;

    f32x4 acc[8];
#pragma unroll
    for (int i = 0; i < 8; i++) acc[i] = (f32x4){0.f, 0.f, 0.f, 0.f};

    for (int s = 0; s < K0STEPS; ++s) {
        int k0 = s * 32;
        __syncthreads();
        short8 a;
        {
            const TIN* src = Xa; int kk = k0; int ld = ldx;
            if (Xb != nullptr && k0 >= 128) { src = Xb; kk = k0 - 128; ld = 128; }
            a = ld_frag(src + (row0 + w * 16 + lm) * (size_t)ld + kk + lq * 8);
        }
#pragma unroll
        for (int rr = 0; rr < 2; ++rr) {
            int idx = rr * 256 + tid;
            int nt = idx >> 6, ll = idx & 63;
            *(short8*)&Bs[nt][ll][0] =
                ld_frag(Wt0 + (size_t)(nt * 16 + (ll & 15)) * K0 + k0 + (ll >> 4) * 8);
        }
        __syncthreads();
#pragma unroll
        for (int nt = 0; nt < 8; ++nt) {
            short8 b = *(const short8*)&Bs[nt][l][0];
            acc[nt] = __builtin_amdgcn_mfma_f32_16x16x32_bf16(a, b, acc[nt], 0, 0, 0);
        }
    }
#pragma unroll
    for (int nt = 0; nt < 8; ++nt) {
        float bb = b2f(b0[nt * 16 + lm]);
#pragma unroll
        for (int r = 0; r < 4; ++r) {
            float x = fmaxf(acc[nt][r] + bb, 0.f);
            Act[w * 16 + lq * 4 + r][nt * 16 + lm] = (short)f2bs(x);
        }
    }

    for (int L = 1; L < LAYERS; ++L) {
        const bf16* Wt = (L == 1) ? Wt1 : Wt2;
        const bf16* bias = (L == 1) ? b1 : b2;
        bool last = (L == LAYERS - 1);
#pragma unroll
        for (int i = 0; i < 8; i++) acc[i] = (f32x4){0.f, 0.f, 0.f, 0.f};
        for (int s = 0; s < 4; ++s) {
            int k0 = s * 32;
            __syncthreads();
#pragma unroll
            for (int rr = 0; rr < 2; ++rr) {
                int idx = rr * 256 + tid;
                int nt = idx >> 6, ll = idx & 63;
                *(short8*)&Bs[nt][ll][0] =
                    ld_frag(Wt + (size_t)(nt * 16 + (ll & 15)) * 128 + k0 + (ll >> 4) * 8);
            }
            __syncthreads();
            short8 a = *(const short8*)&Act[w * 16 + lm][k0 + lq * 8];
#pragma unroll
            for (int nt = 0; nt < 8; ++nt) {
                short8 b = *(const short8*)&Bs[nt][l][0];
                acc[nt] = __builtin_amdgcn_mfma_f32_16x16x32_bf16(a, b, acc[nt], 0, 0, 0);
            }
        }
        if (!last) {
            __syncthreads();
#pragma unroll
            for (int nt = 0; nt < 8; ++nt) {
                float bb = b2f(bias[nt * 16 + lm]);
#pragma unroll
                for (int r = 0; r < 4; ++r) {
                    float x = fmaxf(acc[nt][r] + bb, 0.f);
                    Act[w * 16 + lq * 4 + r][nt * 16 + lm] = (short)f2bs(x);
                }
            }
        } else {
            float v[8][4];
#pragma unroll
            for (int nt = 0; nt < 8; ++nt) {
                float bb = b2f(bias[nt * 16 + lm]);
#pragma unroll
                for (int r = 0; r < 4; ++r) {
                    float x = acc[nt][r] + bb;
                    if (RELU_LAST) x = fmaxf(x, 0.f);
                    v[nt][r] = x;
                }
            }
            if constexpr (TRANS) {
                size_t grow = row0 + w * 16 + lq * 4;
                int bb2 = (int)(grow >> tshift);
                size_t rloc = grow & (((size_t)1 << tshift) - 1);
                bf16* YT = (bf16*)Y;
#pragma unroll
                for (int nt = 0; nt < 8; ++nt) {
                    int col = nt * 16 + lm;
                    ushort4 u;
                    u.x = f2bs(v[nt][0]); u.y = f2bs(v[nt][1]);
                    u.z = f2bs(v[nt][2]); u.w = f2bs(v[nt][3]);
                    *(ushort4*)(YT + (((size_t)bb2 * 128 + col) << tshift) + rloc) = u;
                }
            } else {
#pragma unroll
                for (int nt = 0; nt < 8; ++nt)
#pragma unroll
                    for (int r = 0; r < 4; ++r)
                        Y[(row0 + w * 16 + lq * 4 + r) * (size_t)ldy + nt * 16 + lm] =
                            Cvt<TOUT>::to(v[nt][r]);
            }
        }
    }
}

// ---------------------------------------------------------------------------
// FUSED tail: qenc (3 layers) -> q in Act; dec L0 (z|q), dec L1, final 128->3.
// ---------------------------------------------------------------------------
__global__ __launch_bounds__(256) void qdec_k(
    const bf16* __restrict__ xt32,
    const bf16* __restrict__ WtQ0, const bf16* __restrict__ qb0,
    const bf16* __restrict__ WtQ1, const bf16* __restrict__ qb1,
    const bf16* __restrict__ WtQ2, const bf16* __restrict__ qb2,
    const bf16* __restrict__ z,
    const bf16* __restrict__ WtDec0, const bf16* __restrict__ db0,
    const bf16* __restrict__ WtDec1, const bf16* __restrict__ db1,
    const bf16* __restrict__ W2, const bf16* __restrict__ b2v,
    const int* __restrict__ flag, void* __restrict__ out)
{
    __shared__ __align__(16) short Bs[8][64][8];
    __shared__ __align__(16) short Act[64][136];
    __shared__ bf16 w2s[384];
    int tid = threadIdx.x;
    int w = tid >> 6, l = tid & 63;
    int lm = l & 15, lq = l >> 4;
    size_t row0 = (size_t)blockIdx.x * 64;
    for (int t = tid; t < 384; t += 256) w2s[t] = W2[t];

    f32x4 acc[8];
#pragma unroll
    for (int i = 0; i < 8; i++) acc[i] = (f32x4){0.f, 0.f, 0.f, 0.f};

    // qenc L0 (K=32)
    {
        __syncthreads();
#pragma unroll
        for (int rr = 0; rr < 2; ++rr) {
            int idx = rr * 256 + tid;
            int nt = idx >> 6, ll = idx & 63;
            *(short8*)&Bs[nt][ll][0] =
                ld_frag(WtQ0 + (size_t)(nt * 16 + (ll & 15)) * 32 + (ll >> 4) * 8);
        }
        __syncthreads();
        short8 a = ld_frag(xt32 + (row0 + w * 16 + lm) * 32 + lq * 8);
#pragma unroll
        for (int nt = 0; nt < 8; ++nt) {
            short8 b = *(const short8*)&Bs[nt][l][0];
            acc[nt] = __builtin_amdgcn_mfma_f32_16x16x32_bf16(a, b, acc[nt], 0, 0, 0);
        }
#pragma unroll
        for (int nt = 0; nt < 8; ++nt) {
            float bb = b2f(qb0[nt * 16 + lm]);
#pragma unroll
            for (int r = 0; r < 4; ++r)
                Act[w * 16 + lq * 4 + r][nt * 16 + lm] = (short)f2bs(fmaxf(acc[nt][r] + bb, 0.f));
        }
    }
    // qenc L1 (relu) and L2 (no relu) -> Act
    for (int L = 1; L < 3; ++L) {
        const bf16* Wt = (L == 1) ? WtQ1 : WtQ2;
        const bf16* bias = (L == 1) ? qb1 : qb2;
#pragma unroll
        for (int i = 0; i < 8; i++) acc[i] = (f32x4){0.f, 0.f, 0.f, 0.f};
        for (int s = 0; s < 4; ++s) {
            int k0 = s * 32;
            __syncthreads();
#pragma unroll
            for (int rr = 0; rr < 2; ++rr) {
                int idx = rr * 256 + tid;
                int nt = idx >> 6, ll = idx & 63;
                *(short8*)&Bs[nt][ll][0] =
                    ld_frag(Wt + (size_t)(nt * 16 + (ll & 15)) * 128 + k0 + (ll >> 4) * 8);
            }
            __syncthreads();
            short8 a = *(const short8*)&Act[w * 16 + lm][k0 + lq * 8];
#pragma unroll
            for (int nt = 0; nt < 8; ++nt) {
                short8 b = *(const short8*)&Bs[nt][l][0];
                acc[nt] = __builtin_amdgcn_mfma_f32_16x16x32_bf16(a, b, acc[nt], 0, 0, 0);
            }
        }
        __syncthreads();
#pragma unroll
        for (int nt = 0; nt < 8; ++nt) {
            float bb = b2f(bias[nt * 16 + lm]);
#pragma unroll
            for (int r = 0; r < 4; ++r) {
                float x = acc[nt][r] + bb;
                if (L == 1) x = fmaxf(x, 0.f);
                Act[w * 16 + lq * 4 + r][nt * 16 + lm] = (short)f2bs(x);
            }
        }
    }
    // dec L0: K=256 = z (global) | q (Act); relu -> Act
    {
#pragma unroll
        for (int i = 0; i < 8; i++) acc[i] = (f32x4){0.f, 0.f, 0.f, 0.f};
        for (int s = 0; s < 8; ++s) {
            int k0 = s * 32;
            __syncthreads();
#pragma unroll
            for (int rr = 0; rr < 2; ++rr) {
                int idx = rr * 256 + tid;
                int nt = idx >> 6, ll = idx & 63;
                *(short8*)&Bs[nt][ll][0] =
                    ld_frag(WtDec0 + (size_t)(nt * 16 + (ll & 15)) * 256 + k0 + (ll >> 4) * 8);
            }
            __syncthreads();
            short8 a;
            if (k0 < 128) a = ld_frag(z + (row0 + w * 16 + lm) * (size_t)128 + k0 + lq * 8);
            else          a = *(const short8*)&Act[w * 16 + lm][(k0 - 128) + lq * 8];
#pragma unroll
            for (int nt = 0; nt < 8; ++nt) {
                short8 b = *(const short8*)&Bs[nt][l][0];
                acc[nt] = __builtin_amdgcn_mfma_f32_16x16x32_bf16(a, b, acc[nt], 0, 0, 0);
            }
        }
        __syncthreads();
#pragma unroll
        for (int nt = 0; nt < 8; ++nt) {
            float bb = b2f(db0[nt * 16 + lm]);
#pragma unroll
            for (int r = 0; r < 4; ++r)
                Act[w * 16 + lq * 4 + r][nt * 16 + lm] = (short)f2bs(fmaxf(acc[nt][r] + bb, 0.f));
        }
    }
    // dec L1: K=128 from Act; relu -> Act
    {
#pragma unroll
        for (int i = 0; i < 8; i++) acc[i] = (f32x4){0.f, 0.f, 0.f, 0.f};
        for (int s = 0; s < 4; ++s) {
            int k0 = s * 32;
            __syncthreads();
#pragma unroll
            for (int rr = 0; rr < 2; ++rr) {
                int idx = rr * 256 + tid;
                int nt = idx >> 6, ll = idx & 63;
                *(short8*)&Bs[nt][ll][0] =
                    ld_frag(WtDec1 + (size_t)(nt * 16 + (ll & 15)) * 128 + k0 + (ll >> 4) * 8);
            }
            __syncthreads();
            short8 a = *(const short8*)&Act[w * 16 + lm][k0 + lq * 8];
#pragma unroll
            for (int nt = 0; nt < 8; ++nt) {
                short8 b = *(const short8*)&Bs[nt][l][0];
                acc[nt] = __builtin_amdgcn_mfma_f32_16x16x32_bf16(a, b, acc[nt], 0, 0, 0);
            }
        }
        __syncthreads();
#pragma unroll
        for (int nt = 0; nt < 8; ++nt) {
            float bb = b2f(db1[nt * 16 + lm]);
#pragma unroll
            for (int r = 0; r < 4; ++r)
                Act[w * 16 + lq * 4 + r][nt * 16 + lm] = (short)f2bs(fmaxf(acc[nt][r] + bb, 0.f));
        }
    }
    __syncthreads();
    // final 128 -> 3
    if (tid < 192) {
        int row = tid / 3, col = tid - (tid / 3) * 3;
        float a = b2f(b2v[col]);
        for (int k8 = 0; k8 < 16; ++k8) {
            short8 av = *(const short8*)&Act[row][k8 * 8];
#pragma unroll
            for (int j = 0; j < 8; ++j)
                a += bs2f(av[j]) * b2f(w2s[(k8 * 8 + j) * 3 + col]);
        }
        size_t o = (row0 + row) * 3 + col;
        if (*flag) ((float*)out)[o] = a;
        else       ((bf16*)out)[o] = __float2bfloat16(a);
    }
}

// ---------------------------------------------------------------------------
// fused softmax stats for xc (blocks <8192) and xt
// ---------------------------------------------------------------------------
__global__ __launch_bounds__(256) void stats2_k(const bf16* __restrict__ xcp,
                                                const bf16* __restrict__ xtp,
                                                const bf16* __restrict__ pos,
                                                float4* __restrict__ cstC4,
                                                float4* __restrict__ cstT4) {
    __shared__ float px[NNODE], py[NNODE];
    int tid = threadIdx.x;
    for (int t = tid; t < NNODE; t += 256) {
        px[t] = b2f(pos[2 * t]);
        py[t] = b2f(pos[2 * t + 1]);
    }
    __syncthreads();
    const bf16* xp = (blockIdx.x < 8192) ? xcp : xtp;
    float4* st4 = (blockIdx.x < 8192) ? cstC4 : cstT4;
    int pb = blockIdx.x & 8191;
    int w = tid >> 6, l = tid & 63;
    int p = pb * 4 + w;
    float x = b2f(xp[2 * p]), y = b2f(xp[2 * p + 1]);
    float vals[16];
    float m = -3.4e38f;
#pragma unroll
    for (int k = 0; k < 16; k++) {
        int n = k * 64 + l;
        float dx = x - px[n], dy = y - py[n];
        float v = -(dx * dx + dy * dy);
        vals[k] = v;
        m = fmaxf(m, v);
    }
#pragma unroll
    for (int off = 32; off; off >>= 1) m = fmaxf(m, __shfl_xor(m, off));
    float s = 0.f;
#pragma unroll
    for (int k = 0; k < 16; k++) s += __expf(vals[k] - m);
#pragma unroll
    for (int off = 32; off; off >>= 1) s += __shfl_xor(s, off);
    if (l == 0) st4[p] = make_float4(x, y, m, 1.f / s);
}

struct P8 { float* p[8]; };

// ---------------------------------------------------------------------------
// lat partials via MFMA, XCD-affine, K-split; conflict-free red layout.
// ---------------------------------------------------------------------------
__global__ __launch_bounds__(512, 4) void lat_mfma_k(const bf16* __restrict__ embT,
                                                     const float2* __restrict__ posf2,
                                                     const float4* __restrict__ cstC4,
                                                     P8 parts) {
    int i = blockIdx.x;
    int b = i & 7, r = i >> 3;
    int cs = r >> 4, nt = r & 15;
    int n0 = nt * 64;
    __shared__ __align__(16) float4 csh[512];
    __shared__ __align__(16) float4 red[4][8][64];
    int tid = threadIdx.x;
    int w = tid >> 6, l = tid & 63;
    int wl = w & 3, up = w >> 2;
    int lm = l & 15, lq = l >> 4;
    int node = n0 + wl * 16 + lm;
    float2 pn = posf2[node];
    const bf16* ebase = embT + ((size_t)b << 19) + cs * 512;
    const float4* cbase = cstC4 + b * NC + cs * 512;
    for (int t = tid; t < 512; t += 512) csh[t] = cbase[t];
    __syncthreads();

    f32x4 acc[8];
#pragma unroll
    for (int q = 0; q < 8; q++) acc[q] = (f32x4){0.f, 0.f, 0.f, 0.f};

    union AF { short8 s; u16 u[8]; };
    AF cw, nw;
    short8 bc[8], bn[8];
    int chb = up * 8;
    int c00 = chb * 32;
#pragma unroll
    for (int j = 0; j < 8; ++j) {
        float4 cc = csh[c00 + lq * 8 + j];
        float dx = cc.x - pn.x, dy = cc.y - pn.y;
        cw.u[j] = f2bs(__expf(-(dx * dx + dy * dy) - cc.z) * cc.w);
    }
#pragma unroll
    for (int t2 = 0; t2 < 8; ++t2)
        bc[t2] = ld_frag(ebase + ((size_t)(t2 * 16 + lm) << 12) + c00 + lq * 8);

    for (int ch = 0; ch < 8; ++ch) {
        int c0n = (chb + ((ch + 1) & 7)) * 32;
#pragma unroll
        for (int t2 = 0; t2 < 8; ++t2)
            bn[t2] = ld_frag(ebase + ((size_t)(t2 * 16 + lm) << 12) + c0n + lq * 8);
#pragma unroll
        for (int j = 0; j < 8; ++j) {
            float4 cc = csh[c0n + lq * 8 + j];
            float dx = cc.x - pn.x, dy = cc.y - pn.y;
            nw.u[j] = f2bs(__expf(-(dx * dx + dy * dy) - cc.z) * cc.w);
        }
#pragma unroll
        for (int t2 = 0; t2 < 8; ++t2)
            acc[t2] = __builtin_amdgcn_mfma_f32_16x16x32_bf16(cw.s, bc[t2], acc[t2], 0, 0, 0);
        cw = nw;
#pragma unroll
        for (int t2 = 0; t2 < 8; ++t2) bc[t2] = bn[t2];
    }
    if (up) {
#pragma unroll
        for (int t2 = 0; t2 < 8; ++t2)
            red[wl][t2][l] = make_float4(acc[t2][0], acc[t2][1], acc[t2][2], acc[t2][3]);
    }
    __syncthreads();
    if (!up) {
        float* part = parts.p[cs] + (((size_t)(b * NNODE + n0 + wl * 16 + lq * 4)) << 7) + lm;
#pragma unroll
        for (int t2 = 0; t2 < 8; ++t2) {
            float4 o = red[wl][t2][l];
#pragma unroll
            for (int r2 = 0; r2 < 4; ++r2)
                part[(r2 << 7) + t2 * 16] = acc[t2][r2] + ((const float*)&o)[r2];
        }
    }
}

__global__ __launch_bounds__(256) void reduce8_k(float* __restrict__ dst, P8 parts) {
    int i = blockIdx.x * 256 + threadIdx.x;
    float4 s = ((const float4*)parts.p[0])[i];
#pragma unroll
    for (int k = 1; k < 8; ++k) {
        float4 v = ((const float4*)parts.p[k])[i];
        s.x += v.x; s.y += v.y; s.z += v.z; s.w += v.w;
    }
    ((float4*)dst)[i] = s;
}

// ---------------------------------------------------------------------------
// z via MFMA, XCD-affine, K-split; conflict-free red layout.
// ---------------------------------------------------------------------------
__global__ __launch_bounds__(512, 4) void z_mfma_k(const bf16* __restrict__ latT,
                                                   const float2* __restrict__ posf2,
                                                   const float4* __restrict__ cstT4,
                                                   bf16* __restrict__ z) {
    int i = blockIdx.x;
    int b = i & 7, tt = i >> 3;
    int t0 = tt * 64;
    __shared__ __align__(8) float2 posh[1024];
    __shared__ __align__(16) float4 red[4][8][64];
    int tid = threadIdx.x;
    int w = tid >> 6, l = tid & 63;
    int wl = w & 3, up = w >> 2;
    int lm = l & 15, lq = l >> 4;
    int t = t0 + wl * 16 + lm;
    float4 qs = cstT4[b * NTT + t];
    const bf16* lbase = latT + ((size_t)b << 17);
    for (int k = tid; k < 1024; k += 512) posh[k] = posf2[k];
    __syncthreads();

    f32x4 acc[8];
#pragma unroll
    for (int q = 0; q < 8; q++) acc[q] = (f32x4){0.f, 0.f, 0.f, 0.f};

    union AF { short8 s; u16 u[8]; };
    AF cw, nw;
    short8 bc[8], bn[8];
    int chb = up * 16;
    int nb0 = chb * 32;
#pragma unroll
    for (int j = 0; j < 8; ++j) {
        float2 pn = posh[nb0 + lq * 8 + j];
        float dx = qs.x - pn.x, dy = qs.y - pn.y;
        cw.u[j] = f2bs(__expf(-(dx * dx + dy * dy) - qs.z) * qs.w);
    }
#pragma unroll
    for (int t2 = 0; t2 < 8; ++t2)
        bc[t2] = ld_frag(lbase + ((size_t)(t2 * 16 + lm) << 10) + nb0 + lq * 8);

    for (int ch = 0; ch < 16; ++ch) {
        int nbn = (chb + ((ch + 1) & 15)) * 32;
#pragma unroll
        for (int t2 = 0; t2 < 8; ++t2)
            bn[t2] = ld_frag(lbase + ((size_t)(t2 * 16 + lm) << 10) + nbn + lq * 8);
#pragma unroll
        for (int j = 0; j < 8; ++j) {
            float2 pn = posh[nbn + lq * 8 + j];
            float dx = qs.x - pn.x, dy = qs.y - pn.y;
            nw.u[j] = f2bs(__expf(-(dx * dx + dy * dy) - qs.z) * qs.w);
        }
#pragma unroll
        for (int t2 = 0; t2 < 8; ++t2)
            acc[t2] = __builtin_amdgcn_mfma_f32_16x16x32_bf16(cw.s, bc[t2], acc[t2], 0, 0, 0);
        cw = nw;
#pragma unroll
        for (int t2 = 0; t2 < 8; ++t2) bc[t2] = bn[t2];
    }
    if (up) {
#pragma unroll
        for (int t2 = 0; t2 < 8; ++t2)
            red[wl][t2][l] = make_float4(acc[t2][0], acc[t2][1], acc[t2][2], acc[t2][3]);
    }
    __syncthreads();
    if (!up) {
        bf16* zp = z + (((size_t)(b * NTT + t0 + wl * 16 + lq * 4)) << 7) + lm;
#pragma unroll
        for (int t2 = 0; t2 < 8; ++t2) {
            float4 o = red[wl][t2][l];
#pragma unroll
            for (int r2 = 0; r2 < 4; ++r2)
                zp[(r2 << 7) + t2 * 16] = __float2bfloat16(acc[t2][r2] + ((const float*)&o)[r2]);
        }
    }
}

// ---------------------------------------------------------------------------
// edge gather: one wave per (b, node). PQ + inbox in bf16.
// ---------------------------------------------------------------------------
__global__ __launch_bounds__(256) void edge_gather_k(const bf16* __restrict__ PQ,
                                                     const int* __restrict__ rowptr,
                                                     const int* __restrict__ csr_send,
                                                     const bf16* __restrict__ mb,
                                                     const bf16* __restrict__ g1,
                                                     const bf16* __restrict__ b1,
                                                     bf16* __restrict__ inbox) {
    int tid = threadIdx.x;
    int w = tid >> 6, l = tid & 63;
    int gw = blockIdx.x * 4 + w;
    int b = gw >> 10, n = gw & 1023;
    const bf16* pqb = PQ + ((size_t)b << 18);
    float p0 = b2f(pqb[(n << 8) + l]);
    float p1 = b2f(pqb[(n << 8) + l + 64]);
    float mb0 = b2f(mb[l]), mb1 = b2f(mb[l + 64]);
    float g0 = b2f(g1[l]), g1v = b2f(g1[l + 64]);
    float bb0 = b2f(b1[l]), bb1 = b2f(b1[l + 64]);
    int beg = rowptr[n], end = rowptr[n + 1];
    float a0 = 0.f, a1 = 0.f;
    for (int i = beg; i < end; ++i) {
        int s = csr_send[i];
        const bf16* q = pqb + (s << 8) + 128;
        float m0 = p0 + b2f(q[l]) + mb0;
        float m1 = p1 + b2f(q[l + 64]) + mb1;
        float s1 = m0 + m1, s2 = m0 * m0 + m1 * m1;
#pragma unroll
        for (int off = 32; off; off >>= 1) {
            s1 += __shfl_xor(s1, off);
            s2 += __shfl_xor(s2, off);
        }
        float mu = s1 * (1.f / 128.f);
        float var = s2 * (1.f / 128.f) - mu * mu;
        float rs = rsqrtf(var + 1e-5f);
        a0 += (m0 - mu) * rs * g0 + bb0;
        a1 += (m1 - mu) * rs * g1v + bb1;
    }
    bf16* inb = inbox + ((size_t)b << 17) + (n << 7);
    inb[l] = __float2bfloat16(a0);
    inb[l + 64] = __float2bfloat16(a1);
}

// ---------------------------------------------------------------------------
extern "C" void kernel_launch(void* const* d_in, const int* in_sizes, int n_in,
                              void* d_out, int out_size, void* d_ws, size_t ws_size,
                              hipStream_t stream) {
    const int* senders = (const int*)d_in[30];
    const int* receivers = (const int*)d_in[31];

    char* base = (char*)d_ws;
    size_t off = 0;
    auto alloc = [&](size_t bytes) { char* p = base + off; off += (bytes + 255) & ~(size_t)255; return p; };

    int* flag = (int*)alloc(256);

    Tab tab;
    int pref = 0;
    for (int i = 0; i < 30; ++i) { tab.src[i] = d_in[i]; tab.pref[i] = pref; pref += in_sizes[i]; }
    tab.pref[30] = pref;
    bf16* arena = (bf16*)alloc((size_t)pref * 2);
    auto C = [&](int i) { return arena + tab.pref[i]; };

    float4* cstC4 = (float4*)alloc(32768 * sizeof(float4));
    float4* cstT4 = (float4*)alloc(32768 * sizeof(float4));
    float* lat0  = (float*)alloc(8192 * 128 * 4);
    float* lat1  = (float*)alloc(8192 * 128 * 4);
    float* inboxf = (float*)alloc(8192 * 128 * 4);          // lat partials only
    bf16* inbox  = (bf16*)alloc(8192 * 128 * 2);            // bf16 inbox
    bf16* T1     = (bf16*)alloc((size_t)32768 * 128 * 2);
    bf16* T2     = (bf16*)alloc((size_t)32768 * 128 * 2);
    bf16* T3     = (bf16*)alloc((size_t)32768 * 128 * 2);
    bf16* embT   = (bf16*)alloc((size_t)8 * 128 * 4096 * 2);
    bf16* latT   = (bf16*)alloc((size_t)8 * 128 * 1024 * 2);
    bf16* xin32  = (bf16*)alloc((size_t)32768 * 32 * 2);
    bf16* xt32   = (bf16*)alloc((size_t)32768 * 32 * 2);
    float2* posf2 = (float2*)alloc(1024 * sizeof(float2));
    int* rowptr  = (int*)alloc(1025 * 4);
    int* csr_send = (int*)alloc(NEDGE * 4);
    bf16* WtEnc0 = (bf16*)alloc(128 * 32 * 2);
    bf16* WtQ0   = (bf16*)alloc(128 * 32 * 2);
    bf16* WtEnc1 = (bf16*)alloc(16384 * 2);
    bf16* WtEnc2 = (bf16*)alloc(16384 * 2);
    bf16* WtQ1   = (bf16*)alloc(16384 * 2);
    bf16* WtQ2   = (bf16*)alloc(16384 * 2);
    bf16* WtDec0 = (bf16*)alloc(32768 * 2);
    bf16* WtDec1 = (bf16*)alloc(16384 * 2);
    bf16* WtMsg  = (bf16*)alloc(32768 * 2);
    bf16* WtNode = (bf16*)alloc(32768 * 2);
    bf16* PQ     = T3;   // overlay: bf16 PQ (4 MB) in T3's region; disjoint lifetime
    (void)ws_size; (void)n_in; (void)out_size;

    detect_k<<<1, 256, 0, stream>>>((const u16*)d_in[3], flag);
    ingest_k<<<(pref + 255) / 256, 256, 0, stream>>>(tab, flag, arena);

    const bf16 *xc = C(0), *yc = C(1), *xt = C(2), *pos = C(3);
    const bf16 *enc_W0 = C(4), *enc_b0 = C(5), *enc_W1 = C(6), *enc_b1 = C(7), *enc_W2 = C(8), *enc_b2 = C(9);
    const bf16 *qenc_W0 = C(10), *qenc_b0 = C(11), *qenc_W1 = C(12), *qenc_b1 = C(13), *qenc_W2 = C(14), *qenc_b2 = C(15);
    const bf16 *dec_W0 = C(16), *dec_b0 = C(17), *dec_W1 = C(18), *dec_b1 = C(19), *dec_W2 = C(20), *dec_b2 = C(21);
    const bf16 *msg_W = C(22), *msg_b = C(23), *ln1_g = C(24), *ln1_b = C(25);
    const bf16 *node_W = C(26), *node_b = C(27), *ln2_g = C(28), *ln2_b = C(29);

    TT tt;
    const bf16* s11[11] = { enc_W1, enc_W2, qenc_W1, qenc_W2, dec_W1, dec_W0, msg_W, msg_W + 16384, node_W, enc_W0, qenc_W0 };
    bf16* d11[11]       = { WtEnc1, WtEnc2, WtQ1,    WtQ2,    WtDec1, WtDec0, WtMsg, WtMsg + 16384, WtNode, WtEnc0, WtQ0   };
    int sk11[11] = { 128, 128, 128, 128, 128, 256, 128, 128, 256, 5, 2 };
    int dk11[11] = { 128, 128, 128, 128, 128, 256, 128, 128, 256, 32, 32 };
    int tp = 0;
    for (int i = 0; i < 11; ++i) {
        tt.src[i] = s11[i]; tt.dst[i] = d11[i]; tt.srcK[i] = sk11[i]; tt.dK[i] = dk11[i];
        tt.pref[i] = tp; tp += dk11[i] * 128;
    }
    tt.pref[11] = tp;

    prep_trans_k<<<128 + (tp + 255) / 256, 256, 0, stream>>>(tt, xc, yc, xt, pos, xin32, xt32, posf2);
    build_csr_k<<<1, 1024, 0, stream>>>(receivers, senders, rowptr, csr_send);

    // encoder (fused 3-layer MLP): xin32 -> embT (transposed)
    mlp_k<1, 3, 0, 1, bf16, bf16><<<512, 256, 0, stream>>>(
        xin32, nullptr, 32, WtEnc0, enc_b0, WtEnc1, enc_b1, WtEnc2, enc_b2, embT, 128, 12);

    stats2_k<<<16384, 256, 0, stream>>>(xc, xt, pos, cstC4, cstT4);

    P8 parts;
    parts.p[0] = lat1;
    parts.p[1] = inboxf;
    parts.p[2] = (float*)T1;
    parts.p[3] = (float*)T1 + 1048576;
    parts.p[4] = (float*)T2;
    parts.p[5] = (float*)T2 + 1048576;
    parts.p[6] = (float*)T3;
    parts.p[7] = (float*)T3 + 1048576;
    lat_mfma_k<<<1024, 512, 0, stream>>>(embT, posf2, cstC4, parts);
    reduce8_k<<<1024, 256, 0, stream>>>(lat0, parts);

    // 4-step recurrence, node+msg fused; PQ/inbox in bf16
    mfma_gemm_k<4, 0, 0, 0, 2, float, float, bf16><<<256, 256, 0, stream>>>(lat0, nullptr, 128, WtMsg, nullptr, nullptr, nullptr, PQ, 256, 0);
    edge_gather_k<<<2048, 256, 0, stream>>>(PQ, rowptr, csr_send, msg_b, ln1_g, ln1_b, inbox);
    node_msg_k<<<128, 256, 0, stream>>>(lat0, inbox, WtNode, node_b, ln2_g, ln2_b, WtMsg, lat1, PQ);
    edge_gather_k<<<2048, 256, 0, stream>>>(PQ, rowptr, csr_send, msg_b, ln1_g, ln1_b, inbox);
    node_msg_k<<<128, 256, 0, stream>>>(lat1, inbox, WtNode, node_b, ln2_g, ln2_b, WtMsg, lat0, PQ);
    edge_gather_k<<<2048, 256, 0, stream>>>(PQ, rowptr, csr_send, msg_b, ln1_g, ln1_b, inbox);
    node_msg_k<<<128, 256, 0, stream>>>(lat0, inbox, WtNode, node_b, ln2_g, ln2_b, WtMsg, lat1, PQ);
    edge_gather_k<<<2048, 256, 0, stream>>>(PQ, rowptr, csr_send, msg_b, ln1_g, ln1_b, inbox);
    mfma_gemm_k<8, 1, 0, 1, 1, float, bf16, bf16><<<128, 256, 0, stream>>>(lat1, inbox, 128, WtNode, node_b, ln2_g, ln2_b, latT, 128, 10);

    // z -> T2 (bf16)
    z_mfma_k<<<512, 512, 0, stream>>>(latT, posf2, cstT4, T2);

    // fused tail: qenc(xt32) + dec(z|q) + final -> out
    qdec_k<<<512, 256, 0, stream>>>(xt32,
                                    WtQ0, qenc_b0, WtQ1, qenc_b1, WtQ2, qenc_b2,
                                    T2,
                                    WtDec0, dec_b0, WtDec1, dec_b1,
                                    dec_W2, dec_b2, flag, d_out);
}